// Round 11
// baseline (1237.515 us; speedup 1.0000x reference)
//
#include <hip/hip_runtime.h>
#include <hip/hip_bf16.h>
#include <math.h>

#define CC_COST 0.25

typedef __attribute__((ext_vector_type(8))) short short8v;
typedef __attribute__((ext_vector_type(16))) float f32x16;

__device__ __forceinline__ unsigned short f2bf(float f) {
    unsigned u = __float_as_uint(f);
    unsigned r = (u + 0x7FFFu + ((u >> 16) & 1u)) >> 16;
    return (unsigned short)r;
}
__device__ __forceinline__ float bf2f(unsigned short h) {
    return __uint_as_float(((unsigned)h) << 16);
}

// ===========================================================================
// VQ-VAE forward. Big 3x3 convs on MFMA (bf16 hi/lo 3-product ~ fp32 exact),
// rest fp32 vector. d_out[0]=loss, [1..1572864]=recon, [1572865]=perplexity
// ===========================================================================

// ---------------- batched weight transforms (fp32 vector kernels) ----------
struct WtJobs {
    const float* src[15];
    float* dst[15];
    int cout[15], cin[15], kk[15], kind[15];
    int blk0[16];
};

__global__ void wt_batch_k(WtJobs J)
{
    int blk = blockIdx.x;
    int j = 0;
    while (j < 14 && blk >= J.blk0[j + 1]) ++j;
    int i = (blk - J.blk0[j]) * 256 + threadIdx.x;
    int total = J.cout[j] * J.cin[j] * J.kk[j];
    if (i >= total) return;
    const float* src = J.src[j];
    float* dst = J.dst[j];
    int kind = J.kind[j];
    if (kind == 0) {
        int Cout = J.cout[j], Cin = J.cin[j], KK = J.kk[j];
        int oc = i % Cout; int t2 = i / Cout; int t = t2 % KK; int c = t2 / KK;
        dst[i] = src[(oc * Cin + c) * KK + t];
    } else if (kind == 1) {
        int oc = i & 63; int t = (i >> 6) & 15; int c = i >> 10;
        dst[i] = src[(c * 64 + oc) * 16 + t];
    } else {
        int o = i % 3; int t = (i / 3) % 9; int c = i / 27;
        dst[i] = src[(o * 64 + c) * 9 + t];
    }
}

// split OIHW [128][128][3][3] fp32 -> whi/wlo bf16 in [9 tap][8 cb][128 oc][16 ci]
__global__ void wt_split_k(const float* __restrict__ w,
                           unsigned short* __restrict__ whi,
                           unsigned short* __restrict__ wlo)
{
    int i = blockIdx.x * 256 + threadIdx.x;
    if (i >= 147456) return;
    int ci = i & 15;
    int oc = (i >> 4) & 127;
    int rest = i >> 11;           // 0..71
    int cb = rest & 7;
    int tap = rest >> 3;          // 0..8
    float v = w[(oc * 128 + cb * 16 + ci) * 9 + tap];
    unsigned short h = f2bf(v);
    whi[i] = h;
    wlo[i] = f2bf(v - bf2f(h));
}

// ---------------- MFMA conv3x3 s1 p1, 128->128, 64x64, batch 8 -------------
__global__ __launch_bounds__(512) void conv3x3_mfma(
    const float* __restrict__ in,           // [8,128,64,64]
    const unsigned short* __restrict__ whi, // [9][8][128][16] bf16
    const unsigned short* __restrict__ wlo,
    float* __restrict__ out)                // [8,128,64,64]
{
    constexpr int CST = 40;
    __shared__ unsigned short ls_hi[4 * 68 * CST];
    __shared__ unsigned short ls_lo[4 * 68 * CST];

    int tid = threadIdx.x;
    int lane = tid & 63;
    int w = tid >> 6;
    int myrow = w & 1;
    int oc0 = (w >> 1) * 32;
    int y0 = (blockIdx.x & 31) * 2;
    int b  = blockIdx.x >> 5;
    int ln31 = lane & 31;
    int lhf  = lane >> 5;

    f32x16 acc0 = {};
    f32x16 acc1 = {};

    const float* inb = in + (size_t)b * 128 * 4096;

    for (int chunk = 0; chunk < 4; ++chunk) {
        int c0 = chunk * 32;
        __syncthreads();
        for (int i = tid; i < 4 * 66 * 16; i += 512) {
            int x = i % 66;
            int t = i / 66;
            int cp = t & 15;
            int r = t >> 4;
            int gy = y0 - 1 + r, gx = x - 1;
            float v0 = 0.f, v1 = 0.f;
            if ((unsigned)gy < 64u && (unsigned)gx < 64u) {
                const float* p = inb + (size_t)(c0 + 2 * cp) * 4096 + gy * 64 + gx;
                v0 = p[0];
                v1 = p[4096];
            }
            unsigned short h0 = f2bf(v0), h1 = f2bf(v1);
            unsigned short l0 = f2bf(v0 - bf2f(h0)), l1 = f2bf(v1 - bf2f(h1));
            int a = (r * 68 + x) * CST + 2 * cp;
            *reinterpret_cast<unsigned int*>(&ls_hi[a]) = (unsigned)h0 | ((unsigned)h1 << 16);
            *reinterpret_cast<unsigned int*>(&ls_lo[a]) = (unsigned)l0 | ((unsigned)l1 << 16);
        }
        __syncthreads();

        #pragma unroll
        for (int tap = 0; tap < 9; ++tap) {
            int dy = tap / 3, dx = tap - 3 * (tap / 3);
            int rbase = (myrow + dy) * 68;
            #pragma unroll
            for (int cb = 0; cb < 2; ++cb) {
                int cbg = chunk * 2 + cb;
                size_t wofs = (((size_t)tap * 8 + cbg) * 128 + oc0 + ln31) * 16 + lhf * 8;
                short8v ah = *reinterpret_cast<const short8v*>(whi + wofs);
                short8v al = *reinterpret_cast<const short8v*>(wlo + wofs);
                int k0 = cb * 16 + lhf * 8;
                int xo0 = (rbase + ln31 + dx) * CST + k0;
                int xo1 = (rbase + 32 + ln31 + dx) * CST + k0;
                short8v bh0 = *reinterpret_cast<const short8v*>(&ls_hi[xo0]);
                short8v bl0 = *reinterpret_cast<const short8v*>(&ls_lo[xo0]);
                short8v bh1 = *reinterpret_cast<const short8v*>(&ls_hi[xo1]);
                short8v bl1 = *reinterpret_cast<const short8v*>(&ls_lo[xo1]);
                acc0 = __builtin_amdgcn_mfma_f32_32x32x16_bf16(ah, bh0, acc0, 0, 0, 0);
                acc1 = __builtin_amdgcn_mfma_f32_32x32x16_bf16(ah, bh1, acc1, 0, 0, 0);
                acc0 = __builtin_amdgcn_mfma_f32_32x32x16_bf16(ah, bl0, acc0, 0, 0, 0);
                acc1 = __builtin_amdgcn_mfma_f32_32x32x16_bf16(ah, bl1, acc1, 0, 0, 0);
                acc0 = __builtin_amdgcn_mfma_f32_32x32x16_bf16(al, bh0, acc0, 0, 0, 0);
                acc1 = __builtin_amdgcn_mfma_f32_32x32x16_bf16(al, bh1, acc1, 0, 0, 0);
            }
        }
    }

    float* ob = out + (size_t)b * 128 * 4096 + (size_t)(y0 + myrow) * 64;
    #pragma unroll
    for (int r = 0; r < 16; ++r) {
        int oc = oc0 + (r & 3) + 8 * (r >> 2) + 4 * lhf;
        ob[(size_t)oc * 4096 + ln31]      = acc0[r];
        ob[(size_t)oc * 4096 + 32 + ln31] = acc1[r];
    }
}

// ---------------- split-K res conv3x3: 128->32, relu(in), raw out ----------
__global__ __launch_bounds__(512) void conv3x3_res_k(
    const float* __restrict__ in, const float* __restrict__ wT,  // [c][9][32]
    float* __restrict__ out)
{
    constexpr int CC = 8;
    __shared__ __align__(16) float ls_in[2][CC][3][68];
    __shared__ __align__(16) float ls_w[2][CC][9][32];
    __shared__ float ts[8][256];
    int tid = threadIdx.x;
    int g = tid >> 8, t = tid & 255;
    int pxg = t & 15, ocg = t >> 4;
    int x0 = pxg * 4, oc0 = ocg * 2;
    int y = blockIdx.x & 63, b = blockIdx.x >> 6;
    const float* inb = in + ((size_t)b * 128 + g * 64) * 4096;

    float acc[2][4];
    #pragma unroll
    for (int o = 0; o < 2; ++o)
        #pragma unroll
        for (int p = 0; p < 4; ++p) acc[o][p] = 0.f;

    for (int c0 = 0; c0 < 64; c0 += CC) {
        __syncthreads();
        for (int i = t; i < CC * 3 * 66; i += 256) {
            int xx = i % 66; int tt = i / 66; int r = tt % 3; int cc = tt / 3;
            int gy = y - 1 + r, gx = xx - 1;
            float v = 0.f;
            if ((unsigned)gy < 64u && (unsigned)gx < 64u)
                v = fmaxf(inb[(c0 + cc) * 4096 + gy * 64 + gx], 0.f);
            ls_in[g][cc][r][xx] = v;
        }
        const float* wsrc = wT + (size_t)(g * 64 + c0) * 9 * 32;
        for (int i = t; i < CC * 9 * 32; i += 256)
            (&ls_w[g][0][0][0])[i] = wsrc[i];
        __syncthreads();

        for (int cc = 0; cc < CC; ++cc) {
            float rv[3][6];
            #pragma unroll
            for (int r = 0; r < 3; ++r) {
                const float* base = &ls_in[g][cc][r][x0];
                float4 v = *reinterpret_cast<const float4*>(base);
                rv[r][0]=v.x; rv[r][1]=v.y; rv[r][2]=v.z; rv[r][3]=v.w;
                rv[r][4]=base[4]; rv[r][5]=base[5];
            }
            const float* lw = &ls_w[g][cc][0][0];
            #pragma unroll
            for (int dy = 0; dy < 3; ++dy) {
                #pragma unroll
                for (int dx = 0; dx < 3; ++dx) {
                    float2 w2 = *reinterpret_cast<const float2*>(lw + (dy * 3 + dx) * 32 + oc0);
                    float wv[2] = {w2.x, w2.y};
                    #pragma unroll
                    for (int p = 0; p < 4; ++p) {
                        float iv = rv[dy][p + dx];
                        acc[0][p] = fmaf(iv, wv[0], acc[0][p]);
                        acc[1][p] = fmaf(iv, wv[1], acc[1][p]);
                    }
                }
            }
        }
    }
    if (g == 0) {
        #pragma unroll
        for (int o = 0; o < 2; ++o)
            #pragma unroll
            for (int p = 0; p < 4; ++p) ts[o * 4 + p][t] = acc[o][p];
    }
    __syncthreads();
    if (g == 1) {
        #pragma unroll
        for (int o = 0; o < 2; ++o) {
            float4 v = make_float4(ts[o*4+0][t] + acc[o][0], ts[o*4+1][t] + acc[o][1],
                                   ts[o*4+2][t] + acc[o][2], ts[o*4+3][t] + acc[o][3]);
            float* op = out + (((size_t)b * 32 + oc0 + o) * 64 + y) * 64 + x0;
            *reinterpret_cast<float4*>(op) = v;
        }
    }
}

// ---------------- conv 1x1 on 64x64 (COUT must be 128) ----------------
template<int CIN, int COUT, int CC, bool IN_RELU, bool ADD_RES>
__global__ __launch_bounds__(256) void conv1x1_k(
    const float* __restrict__ in, const float* __restrict__ wT,
    const float* __restrict__ res, float* __restrict__ out)
{
    static_assert(COUT == 128, "tile assumes 128");
    __shared__ __align__(16) float ls_in[CC][64];
    __shared__ __align__(16) float ls_w[CC][COUT];
    int tid = threadIdx.x;
    int pxg = tid & 7, ocg = tid >> 3;
    int x0 = pxg * 8, oc0 = ocg * 4;
    int y = blockIdx.x & 63, b = blockIdx.x >> 6;

    float acc[4][8];
    #pragma unroll
    for (int o = 0; o < 4; ++o)
        #pragma unroll
        for (int p = 0; p < 8; ++p) acc[o][p] = 0.f;

    for (int c0 = 0; c0 < CIN; c0 += CC) {
        __syncthreads();
        for (int i = tid; i < CC * 64; i += 256) {
            int xx = i & 63, cc = i >> 6;
            float v = in[(((size_t)b * CIN + c0 + cc) * 64 + y) * 64 + xx];
            if (IN_RELU) v = fmaxf(v, 0.f);
            ls_in[cc][xx] = v;
        }
        const float* wsrc = wT + (size_t)c0 * COUT;
        for (int i = tid; i < CC * COUT; i += 256)
            (&ls_w[0][0])[i] = wsrc[i];
        __syncthreads();

        for (int cc = 0; cc < CC; ++cc) {
            float rv[8];
            const float* base = &ls_in[cc][x0];
            float4 v0 = *reinterpret_cast<const float4*>(base);
            float4 v1 = *reinterpret_cast<const float4*>(base + 4);
            rv[0]=v0.x; rv[1]=v0.y; rv[2]=v0.z; rv[3]=v0.w;
            rv[4]=v1.x; rv[5]=v1.y; rv[6]=v1.z; rv[7]=v1.w;
            float4 w4 = *reinterpret_cast<const float4*>(&ls_w[cc][oc0]);
            float wv[4] = {w4.x, w4.y, w4.z, w4.w};
            #pragma unroll
            for (int p = 0; p < 8; ++p)
                #pragma unroll
                for (int o = 0; o < 4; ++o)
                    acc[o][p] = fmaf(rv[p], wv[o], acc[o][p]);
        }
    }
    #pragma unroll
    for (int o = 0; o < 4; ++o) {
        float* op = out + (((size_t)b * COUT + oc0 + o) * 64 + y) * 64 + x0;
        const float* rp = res + (((size_t)b * COUT + oc0 + o) * 64 + y) * 64 + x0;
        #pragma unroll
        for (int q = 0; q < 2; ++q) {
            float4 v = make_float4(acc[o][4*q], acc[o][4*q+1],
                                   acc[o][4*q+2], acc[o][4*q+3]);
            if (ADD_RES) {
                float4 r4 = *reinterpret_cast<const float4*>(rp + 4 * q);
                v.x += r4.x; v.y += r4.y; v.z += r4.z; v.w += r4.w;
            }
            *reinterpret_cast<float4*>(op + 4 * q) = v;
        }
    }
}

// ---------------- conv 4x4 s2 p1, relu out, optional oc-slice ----------------
template<int CIN, int COUT, int WOUT, int CC, int OCB, int WOC, int NSLICE>
__global__ __launch_bounds__(256) void conv4x4s2_k(
    const float* __restrict__ in, const float* __restrict__ wT,
    float* __restrict__ out)
{
    constexpr int WIN = WOUT * 2;
    constexpr int NPXG = WOUT / 8, NOCG = COUT / OCB;
    static_assert(NPXG * NOCG == 256, "bad tile");
    constexpr int WUSE = 2 * WOUT + 2;
    constexpr int PADLEN = ((WUSE + (WUSE / 16 + 1) * 4) + 3) & ~3;
    __shared__ __align__(16) float ls_in[CC][4][PADLEN];
    __shared__ __align__(16) float ls_w[CC][16][COUT];

    int tid = threadIdx.x;
    int pxg = tid % NPXG, ocg = tid / NPXG;
    int x0 = pxg * 8, oc0 = ocg * OCB;
    int blk = blockIdx.x;
    int y = blk % WOUT; int rest = blk / WOUT;
    int slice = rest % NSLICE; int b = rest / NSLICE;
    int oc_base = slice * COUT;
    const float* inb = in + (size_t)b * CIN * WIN * WIN;

    float acc[OCB][8];
    #pragma unroll
    for (int o = 0; o < OCB; ++o)
        #pragma unroll
        for (int p = 0; p < 8; ++p) acc[o][p] = 0.f;

    for (int c0 = 0; c0 < CIN; c0 += CC) {
        __syncthreads();
        for (int i = tid; i < CC * 4 * WUSE; i += 256) {
            int xx = i % WUSE; int t = i / WUSE; int r = t & 3; int cc = t >> 2;
            int gy = 2 * y - 1 + r, gx = xx - 1;
            float v = 0.f;
            if ((unsigned)gy < (unsigned)WIN && (unsigned)gx < (unsigned)WIN)
                v = inb[(c0 + cc) * WIN * WIN + gy * WIN + gx];
            ls_in[cc][r][xx + ((xx >> 4) << 2)] = v;
        }
        const float* wsrc = wT + (size_t)c0 * 16 * WOC + oc_base;
        for (int i = tid; i < CC * 16 * COUT; i += 256) {
            int o = i % COUT; int tt = (i / COUT) % 16; int cc = i / (16 * COUT);
            ls_w[cc][tt][o] = wsrc[(cc * 16 + tt) * WOC + o];
        }
        __syncthreads();

        for (int cc = 0; cc < CC; ++cc) {
            const float* lw = &ls_w[cc][0][0];
            #pragma unroll
            for (int ky = 0; ky < 4; ++ky) {
                float rv[18];
                const float* base = &ls_in[cc][ky][20 * pxg];
                #pragma unroll
                for (int q = 0; q < 4; ++q) {
                    float4 v = *reinterpret_cast<const float4*>(base + 4 * q);
                    rv[4*q]=v.x; rv[4*q+1]=v.y; rv[4*q+2]=v.z; rv[4*q+3]=v.w;
                }
                rv[16] = base[20]; rv[17] = base[21];
                #pragma unroll
                for (int kx = 0; kx < 4; ++kx) {
                    const float* wp = lw + (ky * 4 + kx) * COUT + oc0;
                    float wv[OCB];
                    if constexpr (OCB == 4) {
                        float4 w4 = *reinterpret_cast<const float4*>(wp);
                        wv[0]=w4.x; wv[1]=w4.y; wv[2]=w4.z; wv[3]=w4.w;
                    } else {
                        float2 w2 = *reinterpret_cast<const float2*>(wp);
                        wv[0]=w2.x; wv[1]=w2.y;
                    }
                    #pragma unroll
                    for (int p = 0; p < 8; ++p) {
                        float iv = rv[2 * p + kx];
                        #pragma unroll
                        for (int o = 0; o < OCB; ++o)
                            acc[o][p] = fmaf(iv, wv[o], acc[o][p]);
                    }
                }
            }
        }
    }
    #pragma unroll
    for (int o = 0; o < OCB; ++o) {
        float* op = out + (((size_t)b * (COUT * NSLICE) + oc_base + oc0 + o) * WOUT + y) * WOUT + x0;
        #pragma unroll
        for (int q = 0; q < 2; ++q) {
            float4 v = make_float4(fmaxf(acc[o][4*q],0.f), fmaxf(acc[o][4*q+1],0.f),
                                   fmaxf(acc[o][4*q+2],0.f), fmaxf(acc[o][4*q+3],0.f));
            *reinterpret_cast<float4*>(op + 4 * q) = v;
        }
    }
}

// ---------------- deconv 4x4 s2 p1, 128->64, relu(in) folded, relu out ------
#define DECONV_TAPS(RV, KY)                                                   \
    {                                                                         \
        int ky_ = (KY);                                                       \
        _Pragma("unroll")                                                     \
        for (int kx = 0; kx < 4; ++kx) {                                      \
            float4 w4 = *reinterpret_cast<const float4*>(                     \
                lw + (ky_ * 4 + kx) * 64 + oc0);                              \
            float wv[4] = {w4.x, w4.y, w4.z, w4.w};                           \
            if (kx & 1) {                                                     \
                _Pragma("unroll")                                             \
                for (int ph = 0; ph < 4; ++ph) {                              \
                    float iv = RV[(kx == 1) ? (ph + 1) : ph];                 \
                    _Pragma("unroll")                                         \
                    for (int o = 0; o < 4; ++o)                               \
                        acc[o][2*ph] = fmaf(iv, wv[o], acc[o][2*ph]);         \
                }                                                             \
            } else {                                                          \
                _Pragma("unroll")                                             \
                for (int ph = 0; ph < 4; ++ph) {                              \
                    float iv = RV[(kx == 0) ? (ph + 2) : (ph + 1)];           \
                    _Pragma("unroll")                                         \
                    for (int o = 0; o < 4; ++o)                               \
                        acc[o][2*ph+1] = fmaf(iv, wv[o], acc[o][2*ph+1]);     \
                }                                                             \
            }                                                                 \
        }                                                                     \
    }

template<int CC>
__global__ __launch_bounds__(256) void deconv_k(
    const float* __restrict__ in, const float* __restrict__ wT,
    float* __restrict__ out)
{
    __shared__ __align__(16) float ls_in[CC][2][68];
    __shared__ __align__(16) float ls_w[CC][16][64];
    int tid = threadIdx.x;
    int pxg = tid & 15, ocg = tid >> 4;
    int x0 = pxg * 8, oc0 = ocg * 4, xh = pxg * 4;
    int oy = blockIdx.x & 127, b = blockIdx.x >> 7;
    int r1 = (oy + 1) >> 1;
    int ky0 = (oy + 1) & 1;
    const float* inb = in + (size_t)b * 128 * 4096;

    float acc[4][8];
    #pragma unroll
    for (int o = 0; o < 4; ++o)
        #pragma unroll
        for (int p = 0; p < 8; ++p) acc[o][p] = 0.f;

    for (int c0 = 0; c0 < 128; c0 += CC) {
        __syncthreads();
        for (int i = tid; i < CC * 2 * 66; i += 256) {
            int xx = i % 66; int t = i / 66; int rr = t & 1; int cc = t >> 1;
            int iy = r1 - 1 + rr, gx = xx - 1;
            float v = 0.f;
            if ((unsigned)iy < 64u && (unsigned)gx < 64u)
                v = fmaxf(inb[(c0 + cc) * 4096 + iy * 64 + gx], 0.f);
            ls_in[cc][rr][xx] = v;
        }
        const float* wsrc = wT + (size_t)c0 * 16 * 64;
        for (int i = tid; i < CC * 16 * 64; i += 256)
            (&ls_w[0][0][0])[i] = wsrc[i];
        __syncthreads();

        for (int cc = 0; cc < CC; ++cc) {
            float rvA[6], rvB[6];
            {
                const float* bA = &ls_in[cc][1][xh];
                float4 v = *reinterpret_cast<const float4*>(bA);
                rvA[0]=v.x; rvA[1]=v.y; rvA[2]=v.z; rvA[3]=v.w;
                rvA[4]=bA[4]; rvA[5]=bA[5];
                const float* bB = &ls_in[cc][0][xh];
                float4 u = *reinterpret_cast<const float4*>(bB);
                rvB[0]=u.x; rvB[1]=u.y; rvB[2]=u.z; rvB[3]=u.w;
                rvB[4]=bB[4]; rvB[5]=bB[5];
            }
            const float* lw = &ls_w[cc][0][0];
            DECONV_TAPS(rvA, ky0);
            DECONV_TAPS(rvB, ky0 + 2);
        }
    }
    #pragma unroll
    for (int o = 0; o < 4; ++o) {
        float* op = out + (((size_t)b * 64 + oc0 + o) * 128 + oy) * 128 + x0;
        #pragma unroll
        for (int q = 0; q < 2; ++q) {
            float4 v = make_float4(fmaxf(acc[o][4*q],0.f), fmaxf(acc[o][4*q+1],0.f),
                                   fmaxf(acc[o][4*q+2],0.f), fmaxf(acc[o][4*q+3],0.f));
            *reinterpret_cast<float4*>(op + 4 * q) = v;
        }
    }
}

// ---------------- fused bilinear-2x(align) + conv3x3 64->3 + 2*sigmoid-1 ----
template<int CC>
__global__ __launch_bounds__(256) void upconv_k(
    const float* __restrict__ in, const float* __restrict__ wT3,
    float* __restrict__ out)
{
    __shared__ __align__(16) float ls_u[CC][6][260];
    __shared__ float ls_w[64 * 27];
    int tid = threadIdx.x;
    int pxg = tid & 63, row = tid >> 6;
    int x0 = pxg * 4;
    int yblk = blockIdx.x & 63, b = blockIdx.x >> 6;
    int y0 = yblk * 4, y = y0 + row;
    const float SCL = 127.0f / 255.0f;
    const float* hb = in + (size_t)b * 64 * 16384;

    for (int i = tid; i < 1728; i += 256) ls_w[i] = wT3[i];

    float acc[3][4];
    #pragma unroll
    for (int o = 0; o < 3; ++o)
        #pragma unroll
        for (int p = 0; p < 4; ++p) acc[o][p] = 0.f;

    for (int c0 = 0; c0 < 64; c0 += CC) {
        __syncthreads();
        for (int i = tid; i < CC * 6 * 258; i += 256) {
            int xx = i % 258; int t = i / 258; int r = t % 6; int cc = t / 6;
            int uy = y0 - 1 + r, gx = xx - 1;
            float v = 0.f;
            if ((unsigned)uy < 256u && (unsigned)gx < 256u) {
                float py = uy * SCL;
                int ylo = (int)py; int yhi = min(ylo + 1, 127); float fy = py - ylo;
                float px = gx * SCL;
                int xlo = (int)px; int xhi = min(xlo + 1, 127); float fx = px - xlo;
                const float* hp = hb + (c0 + cc) * 16384 + ylo * 128;
                const float* hq = hb + (c0 + cc) * 16384 + yhi * 128;
                float a = hp[xlo], b2 = hp[xhi], c2 = hq[xlo], d2 = hq[xhi];
                float top = a + (b2 - a) * fx;
                float bot = c2 + (d2 - c2) * fx;
                v = top + (bot - top) * fy;
            }
            ls_u[cc][r][xx] = v;
        }
        __syncthreads();

        for (int cc = 0; cc < CC; ++cc) {
            #pragma unroll
            for (int j = 0; j < 3; ++j) {
                float rv[6];
                const float* base = &ls_u[cc][row + j][x0];
                float4 v = *reinterpret_cast<const float4*>(base);
                rv[0]=v.x; rv[1]=v.y; rv[2]=v.z; rv[3]=v.w;
                rv[4]=base[4]; rv[5]=base[5];
                #pragma unroll
                for (int i2 = 0; i2 < 3; ++i2) {
                    const float* wp = &ls_w[((c0 + cc) * 9 + (j * 3 + i2)) * 3];
                    float w0 = wp[0], w1 = wp[1], w2 = wp[2];
                    #pragma unroll
                    for (int p = 0; p < 4; ++p) {
                        float iv = rv[p + i2];
                        acc[0][p] = fmaf(iv, w0, acc[0][p]);
                        acc[1][p] = fmaf(iv, w1, acc[1][p]);
                        acc[2][p] = fmaf(iv, w2, acc[2][p]);
                    }
                }
            }
        }
    }
    #pragma unroll
    for (int o = 0; o < 3; ++o) {
        float4 v;
        v.x = 2.f / (1.f + expf(-acc[o][0])) - 1.f;
        v.y = 2.f / (1.f + expf(-acc[o][1])) - 1.f;
        v.z = 2.f / (1.f + expf(-acc[o][2])) - 1.f;
        v.w = 2.f / (1.f + expf(-acc[o][3])) - 1.f;
        float* op = out + (((size_t)b * 3 + o) * 256 + y) * 256 + x0;
        *reinterpret_cast<float4*>(op) = v;
    }
}

// ---------------- codebook prep (also zeroes counts) ----------------
__global__ void prep_codebook(const float* __restrict__ cb,
                              float* __restrict__ cbT, float* __restrict__ ce2,
                              unsigned int* __restrict__ counts)
{
    int k = blockIdx.x * 256 + threadIdx.x;
    if (k >= 1024) return;
    float s = 0.f;
    for (int d = 0; d < 128; ++d) {
        float v = cb[k * 128 + d];
        cbT[d * 1024 + k] = v;
        s = fmaf(v, v, s);
    }
    ce2[k] = s;
    counts[k] = 0u;
}

// ---------------- fused VQ v6: 8x8 tile, single barrier, z-broadcast -------
// 512 blocks x 256 thr; 64 px/block; cg=tid&31 (8 codes), pxg=tid>>5 (8 px).
// z staged once in LDS (broadcast reads); cb streamed from L1/L2, 1-deep
// prefetch. No inner-loop barriers.
__global__ __launch_bounds__(256) void vq_fused(
    const float* __restrict__ z, const float* __restrict__ cb,
    const float* __restrict__ cbT, const float* __restrict__ ce2,
    unsigned int* __restrict__ counts, float* __restrict__ q,
    double* __restrict__ partial)
{
    __shared__ float zl[128][64];        // 32 KB
    __shared__ int sidx[64];
    __shared__ float red[4];

    int tid = threadIdx.x;
    int cg  = tid & 31;                  // code group: 8 codes
    int pxg = tid >> 5;                  // pixel group: 8 px
    int px0 = pxg * 8;
    int b = blockIdx.x >> 6;
    int p0 = (blockIdx.x & 63) * 64;

    for (int i = tid; i < 8192; i += 256) {
        int d = i >> 6, pix = i & 63;
        zl[d][pix] = z[((size_t)b * 128 + d) * 4096 + p0 + pix];
    }
    __syncthreads();

    float best[8]; int bidx[8];
    #pragma unroll
    for (int j = 0; j < 8; ++j) { best[j] = 3.4e38f; bidx[j] = 0; }

    for (int pass = 0; pass < 4; ++pass) {
        int k0 = pass * 256 + cg * 8;
        const float* cbp = cbT + k0;

        float acc[8][8];
        #pragma unroll
        for (int p = 0; p < 8; ++p)
            #pragma unroll
            for (int c = 0; c < 8; ++c) acc[p][c] = 0.f;

        float4 c0 = *reinterpret_cast<const float4*>(cbp);
        float4 c1 = *reinterpret_cast<const float4*>(cbp + 4);
        for (int d = 0; d < 128; ++d) {
            float4 n0, n1;
            if (d < 127) {
                n0 = *reinterpret_cast<const float4*>(cbp + (size_t)(d + 1) * 1024);
                n1 = *reinterpret_cast<const float4*>(cbp + (size_t)(d + 1) * 1024 + 4);
            }
            float4 z0 = *reinterpret_cast<const float4*>(&zl[d][px0]);
            float4 z1 = *reinterpret_cast<const float4*>(&zl[d][px0 + 4]);
            float zv[8] = {z0.x, z0.y, z0.z, z0.w, z1.x, z1.y, z1.z, z1.w};
            float cv[8] = {c0.x, c0.y, c0.z, c0.w, c1.x, c1.y, c1.z, c1.w};
            #pragma unroll
            for (int p = 0; p < 8; ++p)
                #pragma unroll
                for (int c = 0; c < 8; ++c)
                    acc[p][c] = fmaf(zv[p], cv[c], acc[p][c]);
            c0 = n0; c1 = n1;
        }

        float4 e0 = *reinterpret_cast<const float4*>(ce2 + k0);
        float4 e1 = *reinterpret_cast<const float4*>(ce2 + k0 + 4);
        float ev[8] = {e0.x, e0.y, e0.z, e0.w, e1.x, e1.y, e1.z, e1.w};
        #pragma unroll
        for (int c = 0; c < 8; ++c) {
            #pragma unroll
            for (int p = 0; p < 8; ++p) {
                float dist = ev[c] - 2.f * acc[p][c];
                if (dist < best[p]) { best[p] = dist; bidx[p] = k0 + c; }
            }
        }
    }

    // per-pixel argmin across 32 cg lanes (half-wave; shfl_xor off<32 stays
    // within each 32-lane half). Tie: prefer smaller index.
    #pragma unroll
    for (int j = 0; j < 8; ++j) {
        float bv = best[j]; int bi = bidx[j];
        #pragma unroll
        for (int off = 16; off > 0; off >>= 1) {
            float ov = __shfl_xor(bv, off);
            int   oi = __shfl_xor(bi, off);
            if (ov < bv || (ov == bv && oi < bi)) { bv = ov; bi = oi; }
        }
        if (cg == 0) {
            sidx[px0 + j] = bi;
            atomicAdd(&counts[bi], 1u);
        }
    }
    __syncthreads();

    // gather + q write + loss: pix = tid&63, dg = tid>>6 (4 groups x 32 d)
    int pix = tid & 63, dg = tid >> 6;
    int kidx = sidx[pix];
    const float* crow = cb + (size_t)kidx * 128 + dg * 32;
    float sq = 0.f;
    size_t qbase = ((size_t)b * 128 + dg * 32) * 4096 + p0 + pix;
    #pragma unroll
    for (int ii = 0; ii < 8; ++ii) {
        float4 c4 = *reinterpret_cast<const float4*>(crow + 4 * ii);
        float vals[4] = {c4.x, c4.y, c4.z, c4.w};
        #pragma unroll
        for (int jj = 0; jj < 4; ++jj) {
            int dl = ii * 4 + jj;
            float qv = vals[jj];
            float zv = zl[dg * 32 + dl][pix];
            float df = qv - zv;
            sq = fmaf(df, df, sq);
            q[qbase + (size_t)dl * 4096] = qv;
        }
    }
    #pragma unroll
    for (int off = 32; off > 0; off >>= 1) sq += __shfl_xor(sq, off);
    if ((tid & 63) == 0) red[tid >> 6] = sq;
    __syncthreads();
    if (tid == 0) {
        double s = 0.0;
        #pragma unroll
        for (int ww = 0; ww < 4; ++ww) s += (double)red[ww];
        partial[blockIdx.x] = s;
    }
}

// ---------------- finalize ----------------
__global__ __launch_bounds__(256) void finalize_kernel(
    const double* __restrict__ partial, const unsigned int* __restrict__ counts,
    float* __restrict__ dout)
{
    __shared__ double sd[256];
    __shared__ double lossSh;
    int tid = threadIdx.x;
    double s = 0.0;
    for (int i = tid; i < 512; i += 256) s += partial[i];
    sd[tid] = s; __syncthreads();
    for (int off = 128; off > 0; off >>= 1) {
        if (tid < off) sd[tid] += sd[tid + off];
        __syncthreads();
    }
    if (tid == 0) lossSh = CC_COST * sd[0] / 4194304.0;
    __syncthreads();

    double h = 0.0;
    for (int k = tid; k < 1024; k += 256) {
        double pp = (double)counts[k] / 32768.0;
        h += pp * log(pp + 1e-10);
    }
    sd[tid] = h; __syncthreads();
    for (int off = 128; off > 0; off >>= 1) {
        if (tid < off) sd[tid] += sd[tid + off];
        __syncthreads();
    }
    if (tid == 0) {
        dout[0]       = (float)lossSh;
        dout[1572865] = (float)exp(-sd[0]);
    }
}

// ===========================================================================
extern "C" void kernel_launch(void* const* d_in, const int* in_sizes, int n_in,
                              void* d_out, int out_size, void* d_ws, size_t ws_size,
                              hipStream_t stream)
{
    const float* x        = (const float*)d_in[0];
    const float* enc_c1   = (const float*)d_in[1];
    const float* enc_c2   = (const float*)d_in[2];
    const float* enc_c3   = (const float*)d_in[3];
    const float* enc_r1a  = (const float*)d_in[4];
    const float* enc_r1b  = (const float*)d_in[5];
    const float* enc_r2a  = (const float*)d_in[6];
    const float* enc_r2b  = (const float*)d_in[7];
    const float* pre_vq_w = (const float*)d_in[8];
    const float* codebook = (const float*)d_in[9];
    const float* dec_c1   = (const float*)d_in[10];
    const float* dec_r1a  = (const float*)d_in[11];
    const float* dec_r1b  = (const float*)d_in[12];
    const float* dec_r2a  = (const float*)d_in[13];
    const float* dec_r2b  = (const float*)d_in[14];
    const float* dec_dc   = (const float*)d_in[15];
    const float* dec_c3   = (const float*)d_in[16];
    float* dout = (float*)d_out;

    char* wsp = (char*)d_ws;
    auto alloc = [&](size_t bytes) {
        void* p = (void*)wsp;
        wsp += (bytes + 255) & ~(size_t)255;
        return p;
    };
    float* h1   = (float*)alloc(8ull*64*128*128*4);   // 32MB; also qb alias
    float* bufA = (float*)alloc(8ull*128*64*64*4);    // 16MB; also zb alias
    float* bufB = (float*)alloc(8ull*128*64*64*4);    // 16MB
    float* bufT = (float*)alloc(8ull*32*64*64*4);     // 4MB
    float* cbT  = (float*)alloc(128*1024*4);
    float* ce2  = (float*)alloc(1024*4);
    unsigned int* counts = (unsigned int*)alloc(1024*4);
    double* partial = (double*)alloc(512*8);
    float* wt_ec1  = (float*)alloc(3072*4);
    float* wt_ec2  = (float*)alloc(131072*4);
    float* wt_er1a = (float*)alloc(36864*4);
    float* wt_er1b = (float*)alloc(4096*4);
    float* wt_er2a = (float*)alloc(36864*4);
    float* wt_er2b = (float*)alloc(4096*4);
    float* wt_pvq  = (float*)alloc(16384*4);
    float* wt_dr1a = (float*)alloc(36864*4);
    float* wt_dr1b = (float*)alloc(4096*4);
    float* wt_dr2a = (float*)alloc(36864*4);
    float* wt_dr2b = (float*)alloc(4096*4);
    float* wt_ddc  = (float*)alloc(131072*4);
    float* wt_dc3  = (float*)alloc(1728*4);
    unsigned short* w3hi_e = (unsigned short*)alloc(147456*2);
    unsigned short* w3lo_e = (unsigned short*)alloc(147456*2);
    unsigned short* w3hi_d = (unsigned short*)alloc(147456*2);
    unsigned short* w3lo_d = (unsigned short*)alloc(147456*2);
    float* zb = bufA;   // alias: pre_vq out, dead before dec_c1 writes bufA
    float* qb = h1;     // alias: dead before deconv overwrites h1

    // VQ prep (+counts zero)
    prep_codebook<<<4, 256, 0, stream>>>(codebook, cbT, ce2, counts);

    // batched weight transforms (13 jobs; conv3x3 layers use MFMA split path)
    WtJobs J;
    const float* srcs[13] = {enc_c1, enc_c2, enc_r1a, enc_r1b, enc_r2a,
                             enc_r2b, pre_vq_w, dec_r1a, dec_r1b,
                             dec_r2a, dec_r2b, dec_dc, dec_c3};
    float* dsts[13] = {wt_ec1, wt_ec2, wt_er1a, wt_er1b, wt_er2a,
                       wt_er2b, wt_pvq, wt_dr1a, wt_dr1b,
                       wt_dr2a, wt_dr2b, wt_ddc, wt_dc3};
    int couts[13] = {64, 128, 32, 128, 32, 128, 128, 32, 128, 32, 128, 64, 3};
    int cins[13]  = {3, 64, 128, 32, 128, 32, 128, 128, 32, 128, 32, 128, 64};
    int kks[13]   = {16, 16, 9, 1, 9, 1, 1, 9, 1, 9, 1, 16, 9};
    int kinds[13] = {0, 0, 0, 0, 0, 0, 0, 0, 0, 0, 0, 1, 2};
    int off = 0;
    for (int j = 0; j < 13; ++j) {
        J.src[j] = srcs[j]; J.dst[j] = dsts[j];
        J.cout[j] = couts[j]; J.cin[j] = cins[j]; J.kk[j] = kks[j];
        J.kind[j] = kinds[j];
        J.blk0[j] = off;
        off += (couts[j] * cins[j] * kks[j] + 255) / 256;
    }
    for (int j = 13; j < 16; ++j) J.blk0[j] = off + 1000000;  // sentinels
    J.blk0[13] = off;
    wt_batch_k<<<off, 256, 0, stream>>>(J);
    wt_split_k<<<576, 256, 0, stream>>>(enc_c3, w3hi_e, w3lo_e);
    wt_split_k<<<576, 256, 0, stream>>>(dec_c1, w3hi_d, w3lo_d);

    // ---- encoder ----
    conv4x4s2_k<3, 64, 128, 3, 4, 64, 1><<<1024, 256, 0, stream>>>(x, wt_ec1, h1);
    conv4x4s2_k<64, 64, 64, 4, 2, 128, 2><<<1024, 256, 0, stream>>>(h1, wt_ec2, bufA);
    conv3x3_mfma<<<256, 512, 0, stream>>>(bufA, w3hi_e, w3lo_e, bufB);
    conv3x3_res_k<<<512, 512, 0, stream>>>(bufB, wt_er1a, bufT);
    conv1x1_k<32, 128, 32, true, true><<<512, 256, 0, stream>>>(bufT, wt_er1b, bufB, bufB);
    conv3x3_res_k<<<512, 512, 0, stream>>>(bufB, wt_er2a, bufT);
    conv1x1_k<32, 128, 32, true, true><<<512, 256, 0, stream>>>(bufT, wt_er2b, bufB, bufB);
    conv1x1_k<128, 128, 32, true, false><<<512, 256, 0, stream>>>(bufB, wt_pvq, bufB, zb);

    // ---- VQ ----
    vq_fused<<<512, 256, 0, stream>>>(zb, codebook, cbT, ce2, counts, qb, partial);

    // ---- decoder ----
    conv3x3_mfma<<<256, 512, 0, stream>>>(qb, w3hi_d, w3lo_d, bufA);
    conv3x3_res_k<<<512, 512, 0, stream>>>(bufA, wt_dr1a, bufT);
    conv1x1_k<32, 128, 32, true, true><<<512, 256, 0, stream>>>(bufT, wt_dr1b, bufA, bufA);
    conv3x3_res_k<<<512, 512, 0, stream>>>(bufA, wt_dr2a, bufT);
    conv1x1_k<32, 128, 32, true, true><<<512, 256, 0, stream>>>(bufT, wt_dr2b, bufA, bufA);
    deconv_k<4><<<1024, 256, 0, stream>>>(bufA, wt_ddc, h1);
    upconv_k<2><<<512, 256, 0, stream>>>(h1, wt_dc3, dout + 1);

    // ---- scalars ----
    finalize_kernel<<<1, 256, 0, stream>>>(partial, counts, dout);
}

// Round 13
// 1185.525 us; speedup vs baseline: 1.0439x; 1.0439x over previous
//
#include <hip/hip_runtime.h>
#include <hip/hip_bf16.h>
#include <math.h>

#define CC_COST 0.25

typedef __attribute__((ext_vector_type(8))) short short8v;
typedef __attribute__((ext_vector_type(16))) float f32x16;

__device__ __forceinline__ unsigned short f2bf(float f) {
    unsigned u = __float_as_uint(f);
    unsigned r = (u + 0x7FFFu + ((u >> 16) & 1u)) >> 16;
    return (unsigned short)r;
}
__device__ __forceinline__ float bf2f(unsigned short h) {
    return __uint_as_float(((unsigned)h) << 16);
}

// ===========================================================================
// VQ-VAE forward. Big 3x3 convs AND VQ distance GEMM on MFMA (bf16 hi/lo
// 3-product ~ fp32). d_out[0]=loss, [1..1572864]=recon, [1572865]=perplexity
// ===========================================================================

// ---------------- batched weight transforms (fp32 vector kernels) ----------
struct WtJobs {
    const float* src[15];
    float* dst[15];
    int cout[15], cin[15], kk[15], kind[15];
    int blk0[16];
};

__global__ void wt_batch_k(WtJobs J)
{
    int blk = blockIdx.x;
    int j = 0;
    while (j < 14 && blk >= J.blk0[j + 1]) ++j;
    int i = (blk - J.blk0[j]) * 256 + threadIdx.x;
    int total = J.cout[j] * J.cin[j] * J.kk[j];
    if (i >= total) return;
    const float* src = J.src[j];
    float* dst = J.dst[j];
    int kind = J.kind[j];
    if (kind == 0) {
        int Cout = J.cout[j], Cin = J.cin[j], KK = J.kk[j];
        int oc = i % Cout; int t2 = i / Cout; int t = t2 % KK; int c = t2 / KK;
        dst[i] = src[(oc * Cin + c) * KK + t];
    } else if (kind == 1) {
        int oc = i & 63; int t = (i >> 6) & 15; int c = i >> 10;
        dst[i] = src[(c * 64 + oc) * 16 + t];
    } else {
        int o = i % 3; int t = (i / 3) % 9; int c = i / 27;
        dst[i] = src[(o * 64 + c) * 9 + t];
    }
}

// split OIHW [128][128][3][3] fp32 -> whi/wlo bf16 in [9 tap][8 cb][128 oc][16 ci]
__global__ void wt_split_k(const float* __restrict__ w,
                           unsigned short* __restrict__ whi,
                           unsigned short* __restrict__ wlo)
{
    int i = blockIdx.x * 256 + threadIdx.x;
    if (i >= 147456) return;
    int ci = i & 15;
    int oc = (i >> 4) & 127;
    int rest = i >> 11;           // 0..71
    int cb = rest & 7;
    int tap = rest >> 3;          // 0..8
    float v = w[(oc * 128 + cb * 16 + ci) * 9 + tap];
    unsigned short h = f2bf(v);
    whi[i] = h;
    wlo[i] = f2bf(v - bf2f(h));
}

// ---------------- MFMA conv3x3 s1 p1, 128->128, 64x64, batch 8 -------------
__global__ __launch_bounds__(512) void conv3x3_mfma(
    const float* __restrict__ in,           // [8,128,64,64]
    const unsigned short* __restrict__ whi, // [9][8][128][16] bf16
    const unsigned short* __restrict__ wlo,
    float* __restrict__ out)                // [8,128,64,64]
{
    constexpr int CST = 40;
    __shared__ unsigned short ls_hi[4 * 68 * CST];
    __shared__ unsigned short ls_lo[4 * 68 * CST];

    int tid = threadIdx.x;
    int lane = tid & 63;
    int w = tid >> 6;
    int myrow = w & 1;
    int oc0 = (w >> 1) * 32;
    int y0 = (blockIdx.x & 31) * 2;
    int b  = blockIdx.x >> 5;
    int ln31 = lane & 31;
    int lhf  = lane >> 5;

    f32x16 acc0 = {};
    f32x16 acc1 = {};

    const float* inb = in + (size_t)b * 128 * 4096;

    for (int chunk = 0; chunk < 4; ++chunk) {
        int c0 = chunk * 32;
        __syncthreads();
        for (int i = tid; i < 4 * 66 * 16; i += 512) {
            int x = i % 66;
            int t = i / 66;
            int cp = t & 15;
            int r = t >> 4;
            int gy = y0 - 1 + r, gx = x - 1;
            float v0 = 0.f, v1 = 0.f;
            if ((unsigned)gy < 64u && (unsigned)gx < 64u) {
                const float* p = inb + (size_t)(c0 + 2 * cp) * 4096 + gy * 64 + gx;
                v0 = p[0];
                v1 = p[4096];
            }
            unsigned short h0 = f2bf(v0), h1 = f2bf(v1);
            unsigned short l0 = f2bf(v0 - bf2f(h0)), l1 = f2bf(v1 - bf2f(h1));
            int a = (r * 68 + x) * CST + 2 * cp;
            *reinterpret_cast<unsigned int*>(&ls_hi[a]) = (unsigned)h0 | ((unsigned)h1 << 16);
            *reinterpret_cast<unsigned int*>(&ls_lo[a]) = (unsigned)l0 | ((unsigned)l1 << 16);
        }
        __syncthreads();

        #pragma unroll
        for (int tap = 0; tap < 9; ++tap) {
            int dy = tap / 3, dx = tap - 3 * (tap / 3);
            int rbase = (myrow + dy) * 68;
            #pragma unroll
            for (int cb = 0; cb < 2; ++cb) {
                int cbg = chunk * 2 + cb;
                size_t wofs = (((size_t)tap * 8 + cbg) * 128 + oc0 + ln31) * 16 + lhf * 8;
                short8v ah = *reinterpret_cast<const short8v*>(whi + wofs);
                short8v al = *reinterpret_cast<const short8v*>(wlo + wofs);
                int k0 = cb * 16 + lhf * 8;
                int xo0 = (rbase + ln31 + dx) * CST + k0;
                int xo1 = (rbase + 32 + ln31 + dx) * CST + k0;
                short8v bh0 = *reinterpret_cast<const short8v*>(&ls_hi[xo0]);
                short8v bl0 = *reinterpret_cast<const short8v*>(&ls_lo[xo0]);
                short8v bh1 = *reinterpret_cast<const short8v*>(&ls_hi[xo1]);
                short8v bl1 = *reinterpret_cast<const short8v*>(&ls_lo[xo1]);
                acc0 = __builtin_amdgcn_mfma_f32_32x32x16_bf16(ah, bh0, acc0, 0, 0, 0);
                acc1 = __builtin_amdgcn_mfma_f32_32x32x16_bf16(ah, bh1, acc1, 0, 0, 0);
                acc0 = __builtin_amdgcn_mfma_f32_32x32x16_bf16(ah, bl0, acc0, 0, 0, 0);
                acc1 = __builtin_amdgcn_mfma_f32_32x32x16_bf16(ah, bl1, acc1, 0, 0, 0);
                acc0 = __builtin_amdgcn_mfma_f32_32x32x16_bf16(al, bh0, acc0, 0, 0, 0);
                acc1 = __builtin_amdgcn_mfma_f32_32x32x16_bf16(al, bh1, acc1, 0, 0, 0);
            }
        }
    }

    float* ob = out + (size_t)b * 128 * 4096 + (size_t)(y0 + myrow) * 64;
    #pragma unroll
    for (int r = 0; r < 16; ++r) {
        int oc = oc0 + (r & 3) + 8 * (r >> 2) + 4 * lhf;
        ob[(size_t)oc * 4096 + ln31]      = acc0[r];
        ob[(size_t)oc * 4096 + 32 + ln31] = acc1[r];
    }
}

// ---------------- split-K res conv3x3: 128->32, relu(in), raw out ----------
__global__ __launch_bounds__(512) void conv3x3_res_k(
    const float* __restrict__ in, const float* __restrict__ wT,  // [c][9][32]
    float* __restrict__ out)
{
    constexpr int CC = 8;
    __shared__ __align__(16) float ls_in[2][CC][3][68];
    __shared__ __align__(16) float ls_w[2][CC][9][32];
    __shared__ float ts[8][256];
    int tid = threadIdx.x;
    int g = tid >> 8, t = tid & 255;
    int pxg = t & 15, ocg = t >> 4;
    int x0 = pxg * 4, oc0 = ocg * 2;
    int y = blockIdx.x & 63, b = blockIdx.x >> 6;
    const float* inb = in + ((size_t)b * 128 + g * 64) * 4096;

    float acc[2][4];
    #pragma unroll
    for (int o = 0; o < 2; ++o)
        #pragma unroll
        for (int p = 0; p < 4; ++p) acc[o][p] = 0.f;

    for (int c0 = 0; c0 < 64; c0 += CC) {
        __syncthreads();
        for (int i = t; i < CC * 3 * 66; i += 256) {
            int xx = i % 66; int tt = i / 66; int r = tt % 3; int cc = tt / 3;
            int gy = y - 1 + r, gx = xx - 1;
            float v = 0.f;
            if ((unsigned)gy < 64u && (unsigned)gx < 64u)
                v = fmaxf(inb[(c0 + cc) * 4096 + gy * 64 + gx], 0.f);
            ls_in[g][cc][r][xx] = v;
        }
        const float* wsrc = wT + (size_t)(g * 64 + c0) * 9 * 32;
        for (int i = t; i < CC * 9 * 32; i += 256)
            (&ls_w[g][0][0][0])[i] = wsrc[i];
        __syncthreads();

        for (int cc = 0; cc < CC; ++cc) {
            float rv[3][6];
            #pragma unroll
            for (int r = 0; r < 3; ++r) {
                const float* base = &ls_in[g][cc][r][x0];
                float4 v = *reinterpret_cast<const float4*>(base);
                rv[r][0]=v.x; rv[r][1]=v.y; rv[r][2]=v.z; rv[r][3]=v.w;
                rv[r][4]=base[4]; rv[r][5]=base[5];
            }
            const float* lw = &ls_w[g][cc][0][0];
            #pragma unroll
            for (int dy = 0; dy < 3; ++dy) {
                #pragma unroll
                for (int dx = 0; dx < 3; ++dx) {
                    float2 w2 = *reinterpret_cast<const float2*>(lw + (dy * 3 + dx) * 32 + oc0);
                    float wv[2] = {w2.x, w2.y};
                    #pragma unroll
                    for (int p = 0; p < 4; ++p) {
                        float iv = rv[dy][p + dx];
                        acc[0][p] = fmaf(iv, wv[0], acc[0][p]);
                        acc[1][p] = fmaf(iv, wv[1], acc[1][p]);
                    }
                }
            }
        }
    }
    if (g == 0) {
        #pragma unroll
        for (int o = 0; o < 2; ++o)
            #pragma unroll
            for (int p = 0; p < 4; ++p) ts[o * 4 + p][t] = acc[o][p];
    }
    __syncthreads();
    if (g == 1) {
        #pragma unroll
        for (int o = 0; o < 2; ++o) {
            float4 v = make_float4(ts[o*4+0][t] + acc[o][0], ts[o*4+1][t] + acc[o][1],
                                   ts[o*4+2][t] + acc[o][2], ts[o*4+3][t] + acc[o][3]);
            float* op = out + (((size_t)b * 32 + oc0 + o) * 64 + y) * 64 + x0;
            *reinterpret_cast<float4*>(op) = v;
        }
    }
}

// ---------------- conv 1x1 on 64x64 (COUT must be 128) ----------------
template<int CIN, int COUT, int CC, bool IN_RELU, bool ADD_RES>
__global__ __launch_bounds__(256) void conv1x1_k(
    const float* __restrict__ in, const float* __restrict__ wT,
    const float* __restrict__ res, float* __restrict__ out)
{
    static_assert(COUT == 128, "tile assumes 128");
    __shared__ __align__(16) float ls_in[CC][64];
    __shared__ __align__(16) float ls_w[CC][COUT];
    int tid = threadIdx.x;
    int pxg = tid & 7, ocg = tid >> 3;
    int x0 = pxg * 8, oc0 = ocg * 4;
    int y = blockIdx.x & 63, b = blockIdx.x >> 6;

    float acc[4][8];
    #pragma unroll
    for (int o = 0; o < 4; ++o)
        #pragma unroll
        for (int p = 0; p < 8; ++p) acc[o][p] = 0.f;

    for (int c0 = 0; c0 < CIN; c0 += CC) {
        __syncthreads();
        for (int i = tid; i < CC * 64; i += 256) {
            int xx = i & 63, cc = i >> 6;
            float v = in[(((size_t)b * CIN + c0 + cc) * 64 + y) * 64 + xx];
            if (IN_RELU) v = fmaxf(v, 0.f);
            ls_in[cc][xx] = v;
        }
        const float* wsrc = wT + (size_t)c0 * COUT;
        for (int i = tid; i < CC * COUT; i += 256)
            (&ls_w[0][0])[i] = wsrc[i];
        __syncthreads();

        for (int cc = 0; cc < CC; ++cc) {
            float rv[8];
            const float* base = &ls_in[cc][x0];
            float4 v0 = *reinterpret_cast<const float4*>(base);
            float4 v1 = *reinterpret_cast<const float4*>(base + 4);
            rv[0]=v0.x; rv[1]=v0.y; rv[2]=v0.z; rv[3]=v0.w;
            rv[4]=v1.x; rv[5]=v1.y; rv[6]=v1.z; rv[7]=v1.w;
            float4 w4 = *reinterpret_cast<const float4*>(&ls_w[cc][oc0]);
            float wv[4] = {w4.x, w4.y, w4.z, w4.w};
            #pragma unroll
            for (int p = 0; p < 8; ++p)
                #pragma unroll
                for (int o = 0; o < 4; ++o)
                    acc[o][p] = fmaf(rv[p], wv[o], acc[o][p]);
        }
    }
    #pragma unroll
    for (int o = 0; o < 4; ++o) {
        float* op = out + (((size_t)b * COUT + oc0 + o) * 64 + y) * 64 + x0;
        const float* rp = res + (((size_t)b * COUT + oc0 + o) * 64 + y) * 64 + x0;
        #pragma unroll
        for (int q = 0; q < 2; ++q) {
            float4 v = make_float4(acc[o][4*q], acc[o][4*q+1],
                                   acc[o][4*q+2], acc[o][4*q+3]);
            if (ADD_RES) {
                float4 r4 = *reinterpret_cast<const float4*>(rp + 4 * q);
                v.x += r4.x; v.y += r4.y; v.z += r4.z; v.w += r4.w;
            }
            *reinterpret_cast<float4*>(op + 4 * q) = v;
        }
    }
}

// ---------------- conv 4x4 s2 p1, relu out, optional oc-slice ----------------
template<int CIN, int COUT, int WOUT, int CC, int OCB, int WOC, int NSLICE>
__global__ __launch_bounds__(256) void conv4x4s2_k(
    const float* __restrict__ in, const float* __restrict__ wT,
    float* __restrict__ out)
{
    constexpr int WIN = WOUT * 2;
    constexpr int NPXG = WOUT / 8, NOCG = COUT / OCB;
    static_assert(NPXG * NOCG == 256, "bad tile");
    constexpr int WUSE = 2 * WOUT + 2;
    constexpr int PADLEN = ((WUSE + (WUSE / 16 + 1) * 4) + 3) & ~3;
    __shared__ __align__(16) float ls_in[CC][4][PADLEN];
    __shared__ __align__(16) float ls_w[CC][16][COUT];

    int tid = threadIdx.x;
    int pxg = tid % NPXG, ocg = tid / NPXG;
    int x0 = pxg * 8, oc0 = ocg * OCB;
    int blk = blockIdx.x;
    int y = blk % WOUT; int rest = blk / WOUT;
    int slice = rest % NSLICE; int b = rest / NSLICE;
    int oc_base = slice * COUT;
    const float* inb = in + (size_t)b * CIN * WIN * WIN;

    float acc[OCB][8];
    #pragma unroll
    for (int o = 0; o < OCB; ++o)
        #pragma unroll
        for (int p = 0; p < 8; ++p) acc[o][p] = 0.f;

    for (int c0 = 0; c0 < CIN; c0 += CC) {
        __syncthreads();
        for (int i = tid; i < CC * 4 * WUSE; i += 256) {
            int xx = i % WUSE; int t = i / WUSE; int r = t & 3; int cc = t >> 2;
            int gy = 2 * y - 1 + r, gx = xx - 1;
            float v = 0.f;
            if ((unsigned)gy < (unsigned)WIN && (unsigned)gx < (unsigned)WIN)
                v = inb[(c0 + cc) * WIN * WIN + gy * WIN + gx];
            ls_in[cc][r][xx + ((xx >> 4) << 2)] = v;
        }
        const float* wsrc = wT + (size_t)c0 * 16 * WOC + oc_base;
        for (int i = tid; i < CC * 16 * COUT; i += 256) {
            int o = i % COUT; int tt = (i / COUT) % 16; int cc = i / (16 * COUT);
            ls_w[cc][tt][o] = wsrc[(cc * 16 + tt) * WOC + o];
        }
        __syncthreads();

        for (int cc = 0; cc < CC; ++cc) {
            const float* lw = &ls_w[cc][0][0];
            #pragma unroll
            for (int ky = 0; ky < 4; ++ky) {
                float rv[18];
                const float* base = &ls_in[cc][ky][20 * pxg];
                #pragma unroll
                for (int q = 0; q < 4; ++q) {
                    float4 v = *reinterpret_cast<const float4*>(base + 4 * q);
                    rv[4*q]=v.x; rv[4*q+1]=v.y; rv[4*q+2]=v.z; rv[4*q+3]=v.w;
                }
                rv[16] = base[20]; rv[17] = base[21];
                #pragma unroll
                for (int kx = 0; kx < 4; ++kx) {
                    const float* wp = lw + (ky * 4 + kx) * COUT + oc0;
                    float wv[OCB];
                    if constexpr (OCB == 4) {
                        float4 w4 = *reinterpret_cast<const float4*>(wp);
                        wv[0]=w4.x; wv[1]=w4.y; wv[2]=w4.z; wv[3]=w4.w;
                    } else {
                        float2 w2 = *reinterpret_cast<const float2*>(wp);
                        wv[0]=w2.x; wv[1]=w2.y;
                    }
                    #pragma unroll
                    for (int p = 0; p < 8; ++p) {
                        float iv = rv[2 * p + kx];
                        #pragma unroll
                        for (int o = 0; o < OCB; ++o)
                            acc[o][p] = fmaf(iv, wv[o], acc[o][p]);
                    }
                }
            }
        }
    }
    #pragma unroll
    for (int o = 0; o < OCB; ++o) {
        float* op = out + (((size_t)b * (COUT * NSLICE) + oc_base + oc0 + o) * WOUT + y) * WOUT + x0;
        #pragma unroll
        for (int q = 0; q < 2; ++q) {
            float4 v = make_float4(fmaxf(acc[o][4*q],0.f), fmaxf(acc[o][4*q+1],0.f),
                                   fmaxf(acc[o][4*q+2],0.f), fmaxf(acc[o][4*q+3],0.f));
            *reinterpret_cast<float4*>(op + 4 * q) = v;
        }
    }
}

// ---------------- deconv 4x4 s2 p1, 128->64, relu(in) folded, relu out ------
#define DECONV_TAPS(RV, KY)                                                   \
    {                                                                         \
        int ky_ = (KY);                                                       \
        _Pragma("unroll")                                                     \
        for (int kx = 0; kx < 4; ++kx) {                                      \
            float4 w4 = *reinterpret_cast<const float4*>(                     \
                lw + (ky_ * 4 + kx) * 64 + oc0);                              \
            float wv[4] = {w4.x, w4.y, w4.z, w4.w};                           \
            if (kx & 1) {                                                     \
                _Pragma("unroll")                                             \
                for (int ph = 0; ph < 4; ++ph) {                              \
                    float iv = RV[(kx == 1) ? (ph + 1) : ph];                 \
                    _Pragma("unroll")                                         \
                    for (int o = 0; o < 4; ++o)                               \
                        acc[o][2*ph] = fmaf(iv, wv[o], acc[o][2*ph]);         \
                }                                                             \
            } else {                                                          \
                _Pragma("unroll")                                             \
                for (int ph = 0; ph < 4; ++ph) {                              \
                    float iv = RV[(kx == 0) ? (ph + 2) : (ph + 1)];           \
                    _Pragma("unroll")                                         \
                    for (int o = 0; o < 4; ++o)                               \
                        acc[o][2*ph+1] = fmaf(iv, wv[o], acc[o][2*ph+1]);     \
                }                                                             \
            }                                                                 \
        }                                                                     \
    }

template<int CC>
__global__ __launch_bounds__(256) void deconv_k(
    const float* __restrict__ in, const float* __restrict__ wT,
    float* __restrict__ out)
{
    __shared__ __align__(16) float ls_in[CC][2][68];
    __shared__ __align__(16) float ls_w[CC][16][64];
    int tid = threadIdx.x;
    int pxg = tid & 15, ocg = tid >> 4;
    int x0 = pxg * 8, oc0 = ocg * 4, xh = pxg * 4;
    int oy = blockIdx.x & 127, b = blockIdx.x >> 7;
    int r1 = (oy + 1) >> 1;
    int ky0 = (oy + 1) & 1;
    const float* inb = in + (size_t)b * 128 * 4096;

    float acc[4][8];
    #pragma unroll
    for (int o = 0; o < 4; ++o)
        #pragma unroll
        for (int p = 0; p < 8; ++p) acc[o][p] = 0.f;

    for (int c0 = 0; c0 < 128; c0 += CC) {
        __syncthreads();
        for (int i = tid; i < CC * 2 * 66; i += 256) {
            int xx = i % 66; int t = i / 66; int rr = t & 1; int cc = t >> 1;
            int iy = r1 - 1 + rr, gx = xx - 1;
            float v = 0.f;
            if ((unsigned)iy < 64u && (unsigned)gx < 64u)
                v = fmaxf(inb[(c0 + cc) * 4096 + iy * 64 + gx], 0.f);
            ls_in[cc][rr][xx] = v;
        }
        const float* wsrc = wT + (size_t)c0 * 16 * 64;
        for (int i = tid; i < CC * 16 * 64; i += 256)
            (&ls_w[0][0][0])[i] = wsrc[i];
        __syncthreads();

        for (int cc = 0; cc < CC; ++cc) {
            float rvA[6], rvB[6];
            {
                const float* bA = &ls_in[cc][1][xh];
                float4 v = *reinterpret_cast<const float4*>(bA);
                rvA[0]=v.x; rvA[1]=v.y; rvA[2]=v.z; rvA[3]=v.w;
                rvA[4]=bA[4]; rvA[5]=bA[5];
                const float* bB = &ls_in[cc][0][xh];
                float4 u = *reinterpret_cast<const float4*>(bB);
                rvB[0]=u.x; rvB[1]=u.y; rvB[2]=u.z; rvB[3]=u.w;
                rvB[4]=bB[4]; rvB[5]=bB[5];
            }
            const float* lw = &ls_w[cc][0][0];
            DECONV_TAPS(rvA, ky0);
            DECONV_TAPS(rvB, ky0 + 2);
        }
    }
    #pragma unroll
    for (int o = 0; o < 4; ++o) {
        float* op = out + (((size_t)b * 64 + oc0 + o) * 128 + oy) * 128 + x0;
        #pragma unroll
        for (int q = 0; q < 2; ++q) {
            float4 v = make_float4(fmaxf(acc[o][4*q],0.f), fmaxf(acc[o][4*q+1],0.f),
                                   fmaxf(acc[o][4*q+2],0.f), fmaxf(acc[o][4*q+3],0.f));
            *reinterpret_cast<float4*>(op + 4 * q) = v;
        }
    }
}

// ---------------- fused bilinear-2x(align) + conv3x3 64->3 + 2*sigmoid-1 ----
template<int CC>
__global__ __launch_bounds__(256) void upconv_k(
    const float* __restrict__ in, const float* __restrict__ wT3,
    float* __restrict__ out)
{
    __shared__ __align__(16) float ls_u[CC][6][260];
    __shared__ float ls_w[64 * 27];
    int tid = threadIdx.x;
    int pxg = tid & 63, row = tid >> 6;
    int x0 = pxg * 4;
    int yblk = blockIdx.x & 63, b = blockIdx.x >> 6;
    int y0 = yblk * 4, y = y0 + row;
    const float SCL = 127.0f / 255.0f;
    const float* hb = in + (size_t)b * 64 * 16384;

    for (int i = tid; i < 1728; i += 256) ls_w[i] = wT3[i];

    float acc[3][4];
    #pragma unroll
    for (int o = 0; o < 3; ++o)
        #pragma unroll
        for (int p = 0; p < 4; ++p) acc[o][p] = 0.f;

    for (int c0 = 0; c0 < 64; c0 += CC) {
        __syncthreads();
        for (int i = tid; i < CC * 6 * 258; i += 256) {
            int xx = i % 258; int t = i / 258; int r = t % 6; int cc = t / 6;
            int uy = y0 - 1 + r, gx = xx - 1;
            float v = 0.f;
            if ((unsigned)uy < 256u && (unsigned)gx < 256u) {
                float py = uy * SCL;
                int ylo = (int)py; int yhi = min(ylo + 1, 127); float fy = py - ylo;
                float px = gx * SCL;
                int xlo = (int)px; int xhi = min(xlo + 1, 127); float fx = px - xlo;
                const float* hp = hb + (c0 + cc) * 16384 + ylo * 128;
                const float* hq = hb + (c0 + cc) * 16384 + yhi * 128;
                float a = hp[xlo], b2 = hp[xhi], c2 = hq[xlo], d2 = hq[xhi];
                float top = a + (b2 - a) * fx;
                float bot = c2 + (d2 - c2) * fx;
                v = top + (bot - top) * fy;
            }
            ls_u[cc][r][xx] = v;
        }
        __syncthreads();

        for (int cc = 0; cc < CC; ++cc) {
            #pragma unroll
            for (int j = 0; j < 3; ++j) {
                float rv[6];
                const float* base = &ls_u[cc][row + j][x0];
                float4 v = *reinterpret_cast<const float4*>(base);
                rv[0]=v.x; rv[1]=v.y; rv[2]=v.z; rv[3]=v.w;
                rv[4]=base[4]; rv[5]=base[5];
                #pragma unroll
                for (int i2 = 0; i2 < 3; ++i2) {
                    const float* wp = &ls_w[((c0 + cc) * 9 + (j * 3 + i2)) * 3];
                    float w0 = wp[0], w1 = wp[1], w2 = wp[2];
                    #pragma unroll
                    for (int p = 0; p < 4; ++p) {
                        float iv = rv[p + i2];
                        acc[0][p] = fmaf(iv, w0, acc[0][p]);
                        acc[1][p] = fmaf(iv, w1, acc[1][p]);
                        acc[2][p] = fmaf(iv, w2, acc[2][p]);
                    }
                }
            }
        }
    }
    #pragma unroll
    for (int o = 0; o < 3; ++o) {
        float4 v;
        v.x = 2.f / (1.f + expf(-acc[o][0])) - 1.f;
        v.y = 2.f / (1.f + expf(-acc[o][1])) - 1.f;
        v.z = 2.f / (1.f + expf(-acc[o][2])) - 1.f;
        v.w = 2.f / (1.f + expf(-acc[o][3])) - 1.f;
        float* op = out + (((size_t)b * 3 + o) * 256 + y) * 256 + x0;
        *reinterpret_cast<float4*>(op) = v;
    }
}

// ---------------- codebook prep: bf16 hi/lo frag pack + ce2 + zero counts --
// cb [1024][128] -> cbh/cbl [8 kk][1024 c][16 t]
__global__ void prep_codebook(const float* __restrict__ cb,
                              unsigned short* __restrict__ cbh,
                              unsigned short* __restrict__ cbl,
                              float* __restrict__ ce2,
                              unsigned int* __restrict__ counts)
{
    int k = blockIdx.x * 256 + threadIdx.x;
    if (k >= 1024) return;
    float s = 0.f;
    for (int d = 0; d < 128; ++d) {
        float v = cb[k * 128 + d];
        s = fmaf(v, v, s);
        unsigned short h = f2bf(v);
        int kk = d >> 4, t = d & 15;
        cbh[(kk * 1024 + k) * 16 + t] = h;
        cbl[(kk * 1024 + k) * 16 + t] = f2bf(v - bf2f(h));
    }
    ce2[k] = s;
    counts[k] = 0u;
}

// ---------------- fused VQ v7: MFMA distance GEMM (bf16 hi/lo 3-product) ---
// 512 blocks x 512 thr (8 waves = 2 px-tiles x 4 code-groups of 256 codes).
// Wave computes 32 codes x 32 px per MFMA tile; z frags held in registers.
__global__ __launch_bounds__(512) void vq_fused(
    const float* __restrict__ z, const float* __restrict__ cb,
    const unsigned short* __restrict__ cbh,
    const unsigned short* __restrict__ cbl,
    const float* __restrict__ ce2,
    unsigned int* __restrict__ counts, float* __restrict__ q,
    double* __restrict__ partial)
{
    constexpr int ZP = 136;                  // bf16 pitch per px row
    __shared__ unsigned short zh[64 * ZP];   // ~17 KB
    __shared__ unsigned short zlo[64 * ZP];  // ~17 KB
    __shared__ float ce2l[1024];             // 4 KB
    __shared__ float cmbd[4][2][32];
    __shared__ int   cmbi[4][2][32];
    __shared__ int sidx[64];
    __shared__ float red[8];

    int tid = threadIdx.x;
    int lane = tid & 63;
    int w = tid >> 6;
    int pxg = w & 1;                         // px tile (2 x 32 px)
    int cgrp = w >> 1;                       // code group (4 x 256 codes)
    int ln31 = lane & 31;
    int lhf = lane >> 5;
    int p0g = blockIdx.x * 64;
    int b = p0g >> 12;
    int p0 = p0g & 4095;

    // stage z -> bf16 hi/lo, layout [px][d] pitch ZP
    for (int i = tid; i < 8192; i += 512) {
        int d = i >> 6, px = i & 63;
        float v = z[((size_t)b * 128 + d) * 4096 + p0 + px];
        unsigned short h = f2bf(v);
        zh[px * ZP + d]  = h;
        zlo[px * ZP + d] = f2bf(v - bf2f(h));
    }
    for (int i = tid; i < 1024; i += 512) ce2l[i] = ce2[i];
    __syncthreads();

    // B fragments (z) for my px tile, all 8 K-steps, in registers
    int pxrow = pxg * 32 + ln31;
    short8v zfh[8], zfl[8];
    #pragma unroll
    for (int kk = 0; kk < 8; ++kk) {
        int off = pxrow * ZP + kk * 16 + lhf * 8;
        zfh[kk] = *reinterpret_cast<const short8v*>(&zh[off]);
        zfl[kk] = *reinterpret_cast<const short8v*>(&zlo[off]);
    }

    float best = 3.4e38f; int bidx = 0;
    #pragma unroll
    for (int ct = 0; ct < 8; ++ct) {
        int c0 = cgrp * 256 + ct * 32;
        f32x16 acc = {};
        #pragma unroll
        for (int kk = 0; kk < 8; ++kk) {
            size_t aoff = ((size_t)(kk * 1024 + c0 + ln31)) * 16 + lhf * 8;
            short8v ah = *reinterpret_cast<const short8v*>(cbh + aoff);
            short8v al = *reinterpret_cast<const short8v*>(cbl + aoff);
            acc = __builtin_amdgcn_mfma_f32_32x32x16_bf16(ah, zfh[kk], acc, 0, 0, 0);
            acc = __builtin_amdgcn_mfma_f32_32x32x16_bf16(ah, zfl[kk], acc, 0, 0, 0);
            acc = __builtin_amdgcn_mfma_f32_32x32x16_bf16(al, zfh[kk], acc, 0, 0, 0);
        }
        #pragma unroll
        for (int r = 0; r < 16; ++r) {
            int code = c0 + (r & 3) + 8 * (r >> 2) + 4 * lhf;
            float dist = ce2l[code] - 2.f * acc[r];
            // order-independent (min dist, min idx) == jnp.argmin semantics
            if (dist < best || (dist == best && code < bidx)) { best = dist; bidx = code; }
        }
    }
    // combine lane pair (l, l+32): same px, complementary code slices
    {
        float ob = __shfl_xor(best, 32);
        int   oi = __shfl_xor(bidx, 32);
        if (ob < best || (ob == best && oi < bidx)) { best = ob; bidx = oi; }
    }
    if (lane < 32) { cmbd[cgrp][pxg][lane] = best; cmbi[cgrp][pxg][lane] = bidx; }
    __syncthreads();
    if (tid < 64) {
        int pg = tid >> 5, l = tid & 31;
        float bv = cmbd[0][pg][l]; int bi = cmbi[0][pg][l];
        #pragma unroll
        for (int g = 1; g < 4; ++g) {
            float ov = cmbd[g][pg][l]; int oi = cmbi[g][pg][l];
            if (ov < bv || (ov == bv && oi < bi)) { bv = ov; bi = oi; }
        }
        sidx[pg * 32 + l] = bi;
        atomicAdd(&counts[bi], 1u);
    }
    __syncthreads();

    // gather + q write + loss: pix = tid&63, dg = tid>>6 (8 groups x 16 d)
    int pix = tid & 63, dg = tid >> 6;
    int kidx = sidx[pix];
    const float* crow = cb + (size_t)kidx * 128 + dg * 16;
    float sq = 0.f;
    size_t zbase = ((size_t)b * 128 + dg * 16) * 4096 + p0 + pix;
    #pragma unroll
    for (int ii = 0; ii < 4; ++ii) {
        float4 c4 = *reinterpret_cast<const float4*>(crow + 4 * ii);
        float vals[4] = {c4.x, c4.y, c4.z, c4.w};
        #pragma unroll
        for (int jj = 0; jj < 4; ++jj) {
            int dl = ii * 4 + jj;
            float qv = vals[jj];
            float zv = z[zbase + (size_t)dl * 4096];
            float df = qv - zv;
            sq = fmaf(df, df, sq);
            q[zbase + (size_t)dl * 4096] = qv;
        }
    }
    #pragma unroll
    for (int off = 32; off > 0; off >>= 1) sq += __shfl_xor(sq, off);
    if (lane == 0) red[w] = sq;
    __syncthreads();
    if (tid == 0) {
        double s = 0.0;
        #pragma unroll
        for (int ww = 0; ww < 8; ++ww) s += (double)red[ww];
        partial[blockIdx.x] = s;
    }
}

// ---------------- finalize ----------------
__global__ __launch_bounds__(256) void finalize_kernel(
    const double* __restrict__ partial, const unsigned int* __restrict__ counts,
    float* __restrict__ dout)
{
    __shared__ double sd[256];
    __shared__ double lossSh;
    int tid = threadIdx.x;
    double s = 0.0;
    for (int i = tid; i < 512; i += 256) s += partial[i];
    sd[tid] = s; __syncthreads();
    for (int off = 128; off > 0; off >>= 1) {
        if (tid < off) sd[tid] += sd[tid + off];
        __syncthreads();
    }
    if (tid == 0) lossSh = CC_COST * sd[0] / 4194304.0;
    __syncthreads();

    double h = 0.0;
    for (int k = tid; k < 1024; k += 256) {
        double pp = (double)counts[k] / 32768.0;
        h += pp * log(pp + 1e-10);
    }
    sd[tid] = h; __syncthreads();
    for (int off = 128; off > 0; off >>= 1) {
        if (tid < off) sd[tid] += sd[tid + off];
        __syncthreads();
    }
    if (tid == 0) {
        dout[0]       = (float)lossSh;
        dout[1572865] = (float)exp(-sd[0]);
    }
}

// ===========================================================================
extern "C" void kernel_launch(void* const* d_in, const int* in_sizes, int n_in,
                              void* d_out, int out_size, void* d_ws, size_t ws_size,
                              hipStream_t stream)
{
    const float* x        = (const float*)d_in[0];
    const float* enc_c1   = (const float*)d_in[1];
    const float* enc_c2   = (const float*)d_in[2];
    const float* enc_c3   = (const float*)d_in[3];
    const float* enc_r1a  = (const float*)d_in[4];
    const float* enc_r1b  = (const float*)d_in[5];
    const float* enc_r2a  = (const float*)d_in[6];
    const float* enc_r2b  = (const float*)d_in[7];
    const float* pre_vq_w = (const float*)d_in[8];
    const float* codebook = (const float*)d_in[9];
    const float* dec_c1   = (const float*)d_in[10];
    const float* dec_r1a  = (const float*)d_in[11];
    const float* dec_r1b  = (const float*)d_in[12];
    const float* dec_r2a  = (const float*)d_in[13];
    const float* dec_r2b  = (const float*)d_in[14];
    const float* dec_dc   = (const float*)d_in[15];
    const float* dec_c3   = (const float*)d_in[16];
    float* dout = (float*)d_out;

    char* wsp = (char*)d_ws;
    auto alloc = [&](size_t bytes) {
        void* p = (void*)wsp;
        wsp += (bytes + 255) & ~(size_t)255;
        return p;
    };
    float* h1   = (float*)alloc(8ull*64*128*128*4);   // 32MB; also qb alias
    float* bufA = (float*)alloc(8ull*128*64*64*4);    // 16MB; also zb alias
    float* bufB = (float*)alloc(8ull*128*64*64*4);    // 16MB
    float* bufT = (float*)alloc(8ull*32*64*64*4);     // 4MB
    unsigned short* cbh = (unsigned short*)alloc(131072*2);  // [8][1024][16]
    unsigned short* cbl = (unsigned short*)alloc(131072*2);
    float* ce2  = (float*)alloc(1024*4);
    unsigned int* counts = (unsigned int*)alloc(1024*4);
    double* partial = (double*)alloc(512*8);
    float* wt_ec1  = (float*)alloc(3072*4);
    float* wt_ec2  = (float*)alloc(131072*4);
    float* wt_er1a = (float*)alloc(36864*4);
    float* wt_er1b = (float*)alloc(4096*4);
    float* wt_er2a = (float*)alloc(36864*4);
    float* wt_er2b = (float*)alloc(4096*4);
    float* wt_pvq  = (float*)alloc(16384*4);
    float* wt_dr1a = (float*)alloc(36864*4);
    float* wt_dr1b = (float*)alloc(4096*4);
    float* wt_dr2a = (float*)alloc(36864*4);
    float* wt_dr2b = (float*)alloc(4096*4);
    float* wt_ddc  = (float*)alloc(131072*4);
    float* wt_dc3  = (float*)alloc(1728*4);
    unsigned short* w3hi_e = (unsigned short*)alloc(147456*2);
    unsigned short* w3lo_e = (unsigned short*)alloc(147456*2);
    unsigned short* w3hi_d = (unsigned short*)alloc(147456*2);
    unsigned short* w3lo_d = (unsigned short*)alloc(147456*2);
    float* zb = bufA;   // alias: pre_vq out, dead before dec_c1 writes bufA
    float* qb = h1;     // alias: dead before deconv overwrites h1

    // VQ prep: bf16 frag pack + ce2 + zero counts
    prep_codebook<<<4, 256, 0, stream>>>(codebook, cbh, cbl, ce2, counts);

    // batched weight transforms (13 jobs; conv3x3 layers use MFMA split path)
    WtJobs J;
    const float* srcs[13] = {enc_c1, enc_c2, enc_r1a, enc_r1b, enc_r2a,
                             enc_r2b, pre_vq_w, dec_r1a, dec_r1b,
                             dec_r2a, dec_r2b, dec_dc, dec_c3};
    float* dsts[13] = {wt_ec1, wt_ec2, wt_er1a, wt_er1b, wt_er2a,
                       wt_er2b, wt_pvq, wt_dr1a, wt_dr1b,
                       wt_dr2a, wt_dr2b, wt_ddc, wt_dc3};
    int couts[13] = {64, 128, 32, 128, 32, 128, 128, 32, 128, 32, 128, 64, 3};
    int cins[13]  = {3, 64, 128, 32, 128, 32, 128, 128, 32, 128, 32, 128, 64};
    int kks[13]   = {16, 16, 9, 1, 9, 1, 1, 9, 1, 9, 1, 16, 9};
    int kinds[13] = {0, 0, 0, 0, 0, 0, 0, 0, 0, 0, 0, 1, 2};
    int off = 0;
    for (int j = 0; j < 13; ++j) {
        J.src[j] = srcs[j]; J.dst[j] = dsts[j];
        J.cout[j] = couts[j]; J.cin[j] = cins[j]; J.kk[j] = kks[j];
        J.kind[j] = kinds[j];
        J.blk0[j] = off;
        off += (couts[j] * cins[j] * kks[j] + 255) / 256;
    }
    for (int j = 13; j < 16; ++j) J.blk0[j] = off + 1000000;  // sentinels
    J.blk0[13] = off;
    wt_batch_k<<<off, 256, 0, stream>>>(J);
    wt_split_k<<<576, 256, 0, stream>>>(enc_c3, w3hi_e, w3lo_e);
    wt_split_k<<<576, 256, 0, stream>>>(dec_c1, w3hi_d, w3lo_d);

    // ---- encoder ----
    conv4x4s2_k<3, 64, 128, 3, 4, 64, 1><<<1024, 256, 0, stream>>>(x, wt_ec1, h1);
    conv4x4s2_k<64, 64, 64, 4, 2, 128, 2><<<1024, 256, 0, stream>>>(h1, wt_ec2, bufA);
    conv3x3_mfma<<<256, 512, 0, stream>>>(bufA, w3hi_e, w3lo_e, bufB);
    conv3x3_res_k<<<512, 512, 0, stream>>>(bufB, wt_er1a, bufT);
    conv1x1_k<32, 128, 32, true, true><<<512, 256, 0, stream>>>(bufT, wt_er1b, bufB, bufB);
    conv3x3_res_k<<<512, 512, 0, stream>>>(bufB, wt_er2a, bufT);
    conv1x1_k<32, 128, 32, true, true><<<512, 256, 0, stream>>>(bufT, wt_er2b, bufB, bufB);
    conv1x1_k<128, 128, 32, true, false><<<512, 256, 0, stream>>>(bufB, wt_pvq, bufB, zb);

    // ---- VQ (MFMA distances + argmin + gather + loss) ----
    vq_fused<<<512, 512, 0, stream>>>(zb, codebook, cbh, cbl, ce2, counts, qb, partial);

    // ---- decoder ----
    conv3x3_mfma<<<256, 512, 0, stream>>>(qb, w3hi_d, w3lo_d, bufA);
    conv3x3_res_k<<<512, 512, 0, stream>>>(bufA, wt_dr1a, bufT);
    conv1x1_k<32, 128, 32, true, true><<<512, 256, 0, stream>>>(bufT, wt_dr1b, bufA, bufA);
    conv3x3_res_k<<<512, 512, 0, stream>>>(bufA, wt_dr2a, bufT);
    conv1x1_k<32, 128, 32, true, true><<<512, 256, 0, stream>>>(bufT, wt_dr2b, bufA, bufA);
    deconv_k<4><<<1024, 256, 0, stream>>>(bufA, wt_ddc, h1);
    upconv_k<2><<<512, 256, 0, stream>>>(h1, wt_dc3, dout + 1);

    // ---- scalars ----
    finalize_kernel<<<1, 256, 0, stream>>>(partial, counts, dout);
}

// Round 15
// 1090.736 us; speedup vs baseline: 1.1346x; 1.0869x over previous
//
#include <hip/hip_runtime.h>
#include <hip/hip_bf16.h>
#include <math.h>

#define CC_COST 0.25

typedef __attribute__((ext_vector_type(8))) short short8v;
typedef __attribute__((ext_vector_type(16))) float f32x16;

__device__ __forceinline__ unsigned short f2bf(float f) {
    unsigned u = __float_as_uint(f);
    unsigned r = (u + 0x7FFFu + ((u >> 16) & 1u)) >> 16;
    return (unsigned short)r;
}
__device__ __forceinline__ float bf2f(unsigned short h) {
    return __uint_as_float(((unsigned)h) << 16);
}

// ===========================================================================
// VQ-VAE forward. conv3x3 128ch, conv4x4s2 64->128, and VQ GEMM on MFMA
// (bf16 hi/lo 3-product ~ fp32). d_out[0]=loss, [1..]=recon, [last]=perplexity
// ===========================================================================

// ---------------- batched weight transforms (fp32 vector kernels) ----------
struct WtJobs {
    const float* src[15];
    float* dst[15];
    int cout[15], cin[15], kk[15], kind[15];
    int blk0[16];
};

__global__ void wt_batch_k(WtJobs J)
{
    int blk = blockIdx.x;
    int j = 0;
    while (j < 14 && blk >= J.blk0[j + 1]) ++j;
    int i = (blk - J.blk0[j]) * 256 + threadIdx.x;
    int total = J.cout[j] * J.cin[j] * J.kk[j];
    if (i >= total) return;
    const float* src = J.src[j];
    float* dst = J.dst[j];
    int kind = J.kind[j];
    if (kind == 0) {
        int Cout = J.cout[j], Cin = J.cin[j], KK = J.kk[j];
        int oc = i % Cout; int t2 = i / Cout; int t = t2 % KK; int c = t2 / KK;
        dst[i] = src[(oc * Cin + c) * KK + t];
    } else if (kind == 1) {
        int oc = i & 63; int t = (i >> 6) & 15; int c = i >> 10;
        dst[i] = src[(c * 64 + oc) * 16 + t];
    } else {
        int o = i % 3; int t = (i / 3) % 9; int c = i / 27;
        dst[i] = src[(o * 64 + c) * 9 + t];
    }
}

// split OIHW [128][128][3][3] fp32 -> whi/wlo bf16 in [9 tap][8 cb][128 oc][16 ci]
__global__ void wt_split_k(const float* __restrict__ w,
                           unsigned short* __restrict__ whi,
                           unsigned short* __restrict__ wlo)
{
    int i = blockIdx.x * 256 + threadIdx.x;
    if (i >= 147456) return;
    int ci = i & 15;
    int oc = (i >> 4) & 127;
    int rest = i >> 11;           // 0..71
    int cb = rest & 7;
    int tap = rest >> 3;          // 0..8
    float v = w[(oc * 128 + cb * 16 + ci) * 9 + tap];
    unsigned short h = f2bf(v);
    whi[i] = h;
    wlo[i] = f2bf(v - bf2f(h));
}

// split enc_c2 OIHW [128][64][4][4] -> [16 tap][4 cb][128 oc][16 ci] hi/lo
__global__ void wt_split4_k(const float* __restrict__ w,
                            unsigned short* __restrict__ whi,
                            unsigned short* __restrict__ wlo)
{
    int i = blockIdx.x * 256 + threadIdx.x;
    if (i >= 131072) return;
    int t = i & 15;
    int oc = (i >> 4) & 127;
    int rest = i >> 11;           // 0..63
    int cb = rest & 3;
    int tap = rest >> 2;          // 0..15
    float v = w[(oc * 64 + cb * 16 + t) * 16 + tap];
    unsigned short h = f2bf(v);
    whi[i] = h;
    wlo[i] = f2bf(v - bf2f(h));
}

// ---------------- MFMA conv3x3 s1 p1, 128->128, 64x64, batch 8 -------------
__global__ __launch_bounds__(512) void conv3x3_mfma(
    const float* __restrict__ in,           // [8,128,64,64]
    const unsigned short* __restrict__ whi, // [9][8][128][16] bf16
    const unsigned short* __restrict__ wlo,
    float* __restrict__ out)                // [8,128,64,64]
{
    constexpr int CST = 40;
    __shared__ unsigned short ls_hi[4 * 68 * CST];
    __shared__ unsigned short ls_lo[4 * 68 * CST];

    int tid = threadIdx.x;
    int lane = tid & 63;
    int w = tid >> 6;
    int myrow = w & 1;
    int oc0 = (w >> 1) * 32;
    int y0 = (blockIdx.x & 31) * 2;
    int b  = blockIdx.x >> 5;
    int ln31 = lane & 31;
    int lhf  = lane >> 5;

    f32x16 acc0 = {};
    f32x16 acc1 = {};

    const float* inb = in + (size_t)b * 128 * 4096;

    for (int chunk = 0; chunk < 4; ++chunk) {
        int c0 = chunk * 32;
        __syncthreads();
        for (int i = tid; i < 4 * 66 * 16; i += 512) {
            int x = i % 66;
            int t = i / 66;
            int cp = t & 15;
            int r = t >> 4;
            int gy = y0 - 1 + r, gx = x - 1;
            float v0 = 0.f, v1 = 0.f;
            if ((unsigned)gy < 64u && (unsigned)gx < 64u) {
                const float* p = inb + (size_t)(c0 + 2 * cp) * 4096 + gy * 64 + gx;
                v0 = p[0];
                v1 = p[4096];
            }
            unsigned short h0 = f2bf(v0), h1 = f2bf(v1);
            unsigned short l0 = f2bf(v0 - bf2f(h0)), l1 = f2bf(v1 - bf2f(h1));
            int a = (r * 68 + x) * CST + 2 * cp;
            *reinterpret_cast<unsigned int*>(&ls_hi[a]) = (unsigned)h0 | ((unsigned)h1 << 16);
            *reinterpret_cast<unsigned int*>(&ls_lo[a]) = (unsigned)l0 | ((unsigned)l1 << 16);
        }
        __syncthreads();

        #pragma unroll
        for (int tap = 0; tap < 9; ++tap) {
            int dy = tap / 3, dx = tap - 3 * (tap / 3);
            int rbase = (myrow + dy) * 68;
            #pragma unroll
            for (int cb = 0; cb < 2; ++cb) {
                int cbg = chunk * 2 + cb;
                size_t wofs = (((size_t)tap * 8 + cbg) * 128 + oc0 + ln31) * 16 + lhf * 8;
                short8v ah = *reinterpret_cast<const short8v*>(whi + wofs);
                short8v al = *reinterpret_cast<const short8v*>(wlo + wofs);
                int k0 = cb * 16 + lhf * 8;
                int xo0 = (rbase + ln31 + dx) * CST + k0;
                int xo1 = (rbase + 32 + ln31 + dx) * CST + k0;
                short8v bh0 = *reinterpret_cast<const short8v*>(&ls_hi[xo0]);
                short8v bl0 = *reinterpret_cast<const short8v*>(&ls_lo[xo0]);
                short8v bh1 = *reinterpret_cast<const short8v*>(&ls_hi[xo1]);
                short8v bl1 = *reinterpret_cast<const short8v*>(&ls_lo[xo1]);
                acc0 = __builtin_amdgcn_mfma_f32_32x32x16_bf16(ah, bh0, acc0, 0, 0, 0);
                acc1 = __builtin_amdgcn_mfma_f32_32x32x16_bf16(ah, bh1, acc1, 0, 0, 0);
                acc0 = __builtin_amdgcn_mfma_f32_32x32x16_bf16(ah, bl0, acc0, 0, 0, 0);
                acc1 = __builtin_amdgcn_mfma_f32_32x32x16_bf16(ah, bl1, acc1, 0, 0, 0);
                acc0 = __builtin_amdgcn_mfma_f32_32x32x16_bf16(al, bh0, acc0, 0, 0, 0);
                acc1 = __builtin_amdgcn_mfma_f32_32x32x16_bf16(al, bh1, acc1, 0, 0, 0);
            }
        }
    }

    float* ob = out + (size_t)b * 128 * 4096 + (size_t)(y0 + myrow) * 64;
    #pragma unroll
    for (int r = 0; r < 16; ++r) {
        int oc = oc0 + (r & 3) + 8 * (r >> 2) + 4 * lhf;
        ob[(size_t)oc * 4096 + ln31]      = acc0[r];
        ob[(size_t)oc * 4096 + 32 + ln31] = acc1[r];
    }
}

// ---------------- MFMA conv4x4 s2 p1, 64->128, in 128x128 -> out 64x64 -----
__global__ __launch_bounds__(512) void conv4x4s2_mfma(
    const float* __restrict__ in,            // [8,64,128,128] post-relu
    const unsigned short* __restrict__ whi,  // [16 tap][4 cb][128 oc][16 ci]
    const unsigned short* __restrict__ wlo,
    float* __restrict__ out)                 // [8,128,64,64], relu out
{
    constexpr int CST = 24;                  // 16 ci + 8 pad (48B = 16B-aligned)
    __shared__ unsigned short lsEh[6 * 65 * CST];
    __shared__ unsigned short lsEl[6 * 65 * CST];
    __shared__ unsigned short lsOh[6 * 65 * CST];
    __shared__ unsigned short lsOl[6 * 65 * CST];

    int tid = threadIdx.x;
    int lane = tid & 63;
    int w = tid >> 6;
    int myrow = w & 1;
    int oc0 = (w >> 1) * 32;
    int y0 = (blockIdx.x & 31) * 2;
    int b  = blockIdx.x >> 5;
    int ln31 = lane & 31;
    int lhf  = lane >> 5;

    f32x16 acc0 = {};
    f32x16 acc1 = {};

    const float* inb = in + (size_t)b * 64 * 16384;

    for (int cb = 0; cb < 4; ++cb) {
        int c0 = cb * 16;
        __syncthreads();
        for (int i = tid; i < 12480; i += 512) {
            int gxi = i % 130; int t2 = i / 130;
            int r = t2 % 6; int cc = t2 / 6;
            int gx = gxi - 1;
            int gy = 2 * y0 - 1 + r;
            float v = 0.f;
            if ((unsigned)gy < 128u && (unsigned)gx < 128u)
                v = inb[(size_t)(c0 + cc) * 16384 + gy * 128 + gx];
            unsigned short h = f2bf(v);
            unsigned short l = f2bf(v - bf2f(h));
            if (gx & 1) {
                int a = (r * 65 + ((gx + 1) >> 1)) * CST + cc;
                lsOh[a] = h; lsOl[a] = l;
            } else {
                int a = (r * 65 + (gx >> 1)) * CST + cc;
                lsEh[a] = h; lsEl[a] = l;
            }
        }
        __syncthreads();

        #pragma unroll
        for (int tap = 0; tap < 16; ++tap) {
            int ky = tap >> 2, kx = tap & 3;
            int ridx = 2 * myrow + ky;
            int dlt = kx >> 1;
            const unsigned short* ph = (kx & 1) ? lsEh : lsOh;
            const unsigned short* pl = (kx & 1) ? lsEl : lsOl;
            size_t aoff = ((size_t)((tap * 4 + cb) * 128 + oc0 + ln31)) * 16 + lhf * 8;
            short8v ah = *reinterpret_cast<const short8v*>(whi + aoff);
            short8v al = *reinterpret_cast<const short8v*>(wlo + aoff);
            int base0 = (ridx * 65 + ln31 + dlt) * CST + lhf * 8;
            int base1 = (ridx * 65 + 32 + ln31 + dlt) * CST + lhf * 8;
            short8v bh0 = *reinterpret_cast<const short8v*>(ph + base0);
            short8v bl0 = *reinterpret_cast<const short8v*>(pl + base0);
            short8v bh1 = *reinterpret_cast<const short8v*>(ph + base1);
            short8v bl1 = *reinterpret_cast<const short8v*>(pl + base1);
            acc0 = __builtin_amdgcn_mfma_f32_32x32x16_bf16(ah, bh0, acc0, 0, 0, 0);
            acc1 = __builtin_amdgcn_mfma_f32_32x32x16_bf16(ah, bh1, acc1, 0, 0, 0);
            acc0 = __builtin_amdgcn_mfma_f32_32x32x16_bf16(ah, bl0, acc0, 0, 0, 0);
            acc1 = __builtin_amdgcn_mfma_f32_32x32x16_bf16(ah, bl1, acc1, 0, 0, 0);
            acc0 = __builtin_amdgcn_mfma_f32_32x32x16_bf16(al, bh0, acc0, 0, 0, 0);
            acc1 = __builtin_amdgcn_mfma_f32_32x32x16_bf16(al, bh1, acc1, 0, 0, 0);
        }
    }

    int y = y0 + myrow;
    float* ob = out + (size_t)b * 128 * 4096 + (size_t)y * 64;
    #pragma unroll
    for (int r = 0; r < 16; ++r) {
        int oc = oc0 + (r & 3) + 8 * (r >> 2) + 4 * lhf;
        ob[(size_t)oc * 4096 + ln31]      = fmaxf(acc0[r], 0.f);
        ob[(size_t)oc * 4096 + 32 + ln31] = fmaxf(acc1[r], 0.f);
    }
}

// ---------------- split-K res conv3x3: 128->32, relu(in), raw out ----------
__global__ __launch_bounds__(512) void conv3x3_res_k(
    const float* __restrict__ in, const float* __restrict__ wT,  // [c][9][32]
    float* __restrict__ out)
{
    constexpr int CC = 8;
    __shared__ __align__(16) float ls_in[2][CC][3][68];
    __shared__ __align__(16) float ls_w[2][CC][9][32];
    __shared__ float ts[8][256];
    int tid = threadIdx.x;
    int g = tid >> 8, t = tid & 255;
    int pxg = t & 15, ocg = t >> 4;
    int x0 = pxg * 4, oc0 = ocg * 2;
    int y = blockIdx.x & 63, b = blockIdx.x >> 6;
    const float* inb = in + ((size_t)b * 128 + g * 64) * 4096;

    float acc[2][4];
    #pragma unroll
    for (int o = 0; o < 2; ++o)
        #pragma unroll
        for (int p = 0; p < 4; ++p) acc[o][p] = 0.f;

    for (int c0 = 0; c0 < 64; c0 += CC) {
        __syncthreads();
        for (int i = t; i < CC * 3 * 66; i += 256) {
            int xx = i % 66; int tt = i / 66; int r = tt % 3; int cc = tt / 3;
            int gy = y - 1 + r, gx = xx - 1;
            float v = 0.f;
            if ((unsigned)gy < 64u && (unsigned)gx < 64u)
                v = fmaxf(inb[(c0 + cc) * 4096 + gy * 64 + gx], 0.f);
            ls_in[g][cc][r][xx] = v;
        }
        const float* wsrc = wT + (size_t)(g * 64 + c0) * 9 * 32;
        for (int i = t; i < CC * 9 * 32; i += 256)
            (&ls_w[g][0][0][0])[i] = wsrc[i];
        __syncthreads();

        for (int cc = 0; cc < CC; ++cc) {
            float rv[3][6];
            #pragma unroll
            for (int r = 0; r < 3; ++r) {
                const float* base = &ls_in[g][cc][r][x0];
                float4 v = *reinterpret_cast<const float4*>(base);
                rv[r][0]=v.x; rv[r][1]=v.y; rv[r][2]=v.z; rv[r][3]=v.w;
                rv[r][4]=base[4]; rv[r][5]=base[5];
            }
            const float* lw = &ls_w[g][cc][0][0];
            #pragma unroll
            for (int dy = 0; dy < 3; ++dy) {
                #pragma unroll
                for (int dx = 0; dx < 3; ++dx) {
                    float2 w2 = *reinterpret_cast<const float2*>(lw + (dy * 3 + dx) * 32 + oc0);
                    float wv[2] = {w2.x, w2.y};
                    #pragma unroll
                    for (int p = 0; p < 4; ++p) {
                        float iv = rv[dy][p + dx];
                        acc[0][p] = fmaf(iv, wv[0], acc[0][p]);
                        acc[1][p] = fmaf(iv, wv[1], acc[1][p]);
                    }
                }
            }
        }
    }
    if (g == 0) {
        #pragma unroll
        for (int o = 0; o < 2; ++o)
            #pragma unroll
            for (int p = 0; p < 4; ++p) ts[o * 4 + p][t] = acc[o][p];
    }
    __syncthreads();
    if (g == 1) {
        #pragma unroll
        for (int o = 0; o < 2; ++o) {
            float4 v = make_float4(ts[o*4+0][t] + acc[o][0], ts[o*4+1][t] + acc[o][1],
                                   ts[o*4+2][t] + acc[o][2], ts[o*4+3][t] + acc[o][3]);
            float* op = out + (((size_t)b * 32 + oc0 + o) * 64 + y) * 64 + x0;
            *reinterpret_cast<float4*>(op) = v;
        }
    }
}

// ---------------- conv 1x1 on 64x64 (COUT must be 128) ----------------
template<int CIN, int COUT, int CC, bool IN_RELU, bool ADD_RES>
__global__ __launch_bounds__(256) void conv1x1_k(
    const float* __restrict__ in, const float* __restrict__ wT,
    const float* __restrict__ res, float* __restrict__ out)
{
    static_assert(COUT == 128, "tile assumes 128");
    __shared__ __align__(16) float ls_in[CC][64];
    __shared__ __align__(16) float ls_w[CC][COUT];
    int tid = threadIdx.x;
    int pxg = tid & 7, ocg = tid >> 3;
    int x0 = pxg * 8, oc0 = ocg * 4;
    int y = blockIdx.x & 63, b = blockIdx.x >> 6;

    float acc[4][8];
    #pragma unroll
    for (int o = 0; o < 4; ++o)
        #pragma unroll
        for (int p = 0; p < 8; ++p) acc[o][p] = 0.f;

    for (int c0 = 0; c0 < CIN; c0 += CC) {
        __syncthreads();
        for (int i = tid; i < CC * 64; i += 256) {
            int xx = i & 63, cc = i >> 6;
            float v = in[(((size_t)b * CIN + c0 + cc) * 64 + y) * 64 + xx];
            if (IN_RELU) v = fmaxf(v, 0.f);
            ls_in[cc][xx] = v;
        }
        const float* wsrc = wT + (size_t)c0 * COUT;
        for (int i = tid; i < CC * COUT; i += 256)
            (&ls_w[0][0])[i] = wsrc[i];
        __syncthreads();

        for (int cc = 0; cc < CC; ++cc) {
            float rv[8];
            const float* base = &ls_in[cc][x0];
            float4 v0 = *reinterpret_cast<const float4*>(base);
            float4 v1 = *reinterpret_cast<const float4*>(base + 4);
            rv[0]=v0.x; rv[1]=v0.y; rv[2]=v0.z; rv[3]=v0.w;
            rv[4]=v1.x; rv[5]=v1.y; rv[6]=v1.z; rv[7]=v1.w;
            float4 w4 = *reinterpret_cast<const float4*>(&ls_w[cc][oc0]);
            float wv[4] = {w4.x, w4.y, w4.z, w4.w};
            #pragma unroll
            for (int p = 0; p < 8; ++p)
                #pragma unroll
                for (int o = 0; o < 4; ++o)
                    acc[o][p] = fmaf(rv[p], wv[o], acc[o][p]);
        }
    }
    #pragma unroll
    for (int o = 0; o < 4; ++o) {
        float* op = out + (((size_t)b * COUT + oc0 + o) * 64 + y) * 64 + x0;
        const float* rp = res + (((size_t)b * COUT + oc0 + o) * 64 + y) * 64 + x0;
        #pragma unroll
        for (int q = 0; q < 2; ++q) {
            float4 v = make_float4(acc[o][4*q], acc[o][4*q+1],
                                   acc[o][4*q+2], acc[o][4*q+3]);
            if (ADD_RES) {
                float4 r4 = *reinterpret_cast<const float4*>(rp + 4 * q);
                v.x += r4.x; v.y += r4.y; v.z += r4.z; v.w += r4.w;
            }
            *reinterpret_cast<float4*>(op + 4 * q) = v;
        }
    }
}

// ---------------- conv 4x4 s2 p1 (vector; used for enc_c1 3->64) -----------
template<int CIN, int COUT, int WOUT, int CC, int OCB, int WOC, int NSLICE>
__global__ __launch_bounds__(256) void conv4x4s2_k(
    const float* __restrict__ in, const float* __restrict__ wT,
    float* __restrict__ out)
{
    constexpr int WIN = WOUT * 2;
    constexpr int NPXG = WOUT / 8, NOCG = COUT / OCB;
    static_assert(NPXG * NOCG == 256, "bad tile");
    constexpr int WUSE = 2 * WOUT + 2;
    constexpr int PADLEN = ((WUSE + (WUSE / 16 + 1) * 4) + 3) & ~3;
    __shared__ __align__(16) float ls_in[CC][4][PADLEN];
    __shared__ __align__(16) float ls_w[CC][16][COUT];

    int tid = threadIdx.x;
    int pxg = tid % NPXG, ocg = tid / NPXG;
    int x0 = pxg * 8, oc0 = ocg * OCB;
    int blk = blockIdx.x;
    int y = blk % WOUT; int rest = blk / WOUT;
    int slice = rest % NSLICE; int b = rest / NSLICE;
    int oc_base = slice * COUT;
    const float* inb = in + (size_t)b * CIN * WIN * WIN;

    float acc[OCB][8];
    #pragma unroll
    for (int o = 0; o < OCB; ++o)
        #pragma unroll
        for (int p = 0; p < 8; ++p) acc[o][p] = 0.f;

    for (int c0 = 0; c0 < CIN; c0 += CC) {
        __syncthreads();
        for (int i = tid; i < CC * 4 * WUSE; i += 256) {
            int xx = i % WUSE; int t = i / WUSE; int r = t & 3; int cc = t >> 2;
            int gy = 2 * y - 1 + r, gx = xx - 1;
            float v = 0.f;
            if ((unsigned)gy < (unsigned)WIN && (unsigned)gx < (unsigned)WIN)
                v = inb[(c0 + cc) * WIN * WIN + gy * WIN + gx];
            ls_in[cc][r][xx + ((xx >> 4) << 2)] = v;
        }
        const float* wsrc = wT + (size_t)c0 * 16 * WOC + oc_base;
        for (int i = tid; i < CC * 16 * COUT; i += 256) {
            int o = i % COUT; int tt = (i / COUT) % 16; int cc = i / (16 * COUT);
            ls_w[cc][tt][o] = wsrc[(cc * 16 + tt) * WOC + o];
        }
        __syncthreads();

        for (int cc = 0; cc < CC; ++cc) {
            const float* lw = &ls_w[cc][0][0];
            #pragma unroll
            for (int ky = 0; ky < 4; ++ky) {
                float rv[18];
                const float* base = &ls_in[cc][ky][20 * pxg];
                #pragma unroll
                for (int q = 0; q < 4; ++q) {
                    float4 v = *reinterpret_cast<const float4*>(base + 4 * q);
                    rv[4*q]=v.x; rv[4*q+1]=v.y; rv[4*q+2]=v.z; rv[4*q+3]=v.w;
                }
                rv[16] = base[20]; rv[17] = base[21];
                #pragma unroll
                for (int kx = 0; kx < 4; ++kx) {
                    const float* wp = lw + (ky * 4 + kx) * COUT + oc0;
                    float wv[OCB];
                    if constexpr (OCB == 4) {
                        float4 w4 = *reinterpret_cast<const float4*>(wp);
                        wv[0]=w4.x; wv[1]=w4.y; wv[2]=w4.z; wv[3]=w4.w;
                    } else {
                        float2 w2 = *reinterpret_cast<const float2*>(wp);
                        wv[0]=w2.x; wv[1]=w2.y;
                    }
                    #pragma unroll
                    for (int p = 0; p < 8; ++p) {
                        float iv = rv[2 * p + kx];
                        #pragma unroll
                        for (int o = 0; o < OCB; ++o)
                            acc[o][p] = fmaf(iv, wv[o], acc[o][p]);
                    }
                }
            }
        }
    }
    #pragma unroll
    for (int o = 0; o < OCB; ++o) {
        float* op = out + (((size_t)b * (COUT * NSLICE) + oc_base + oc0 + o) * WOUT + y) * WOUT + x0;
        #pragma unroll
        for (int q = 0; q < 2; ++q) {
            float4 v = make_float4(fmaxf(acc[o][4*q],0.f), fmaxf(acc[o][4*q+1],0.f),
                                   fmaxf(acc[o][4*q+2],0.f), fmaxf(acc[o][4*q+3],0.f));
            *reinterpret_cast<float4*>(op + 4 * q) = v;
        }
    }
}

// ---------------- deconv 4x4 s2 p1, 128->64, relu(in) folded, relu out ------
#define DECONV_TAPS(RV, KY)                                                   \
    {                                                                         \
        int ky_ = (KY);                                                       \
        _Pragma("unroll")                                                     \
        for (int kx = 0; kx < 4; ++kx) {                                      \
            float4 w4 = *reinterpret_cast<const float4*>(                     \
                lw + (ky_ * 4 + kx) * 64 + oc0);                              \
            float wv[4] = {w4.x, w4.y, w4.z, w4.w};                           \
            if (kx & 1) {                                                     \
                _Pragma("unroll")                                             \
                for (int ph = 0; ph < 4; ++ph) {                              \
                    float iv = RV[(kx == 1) ? (ph + 1) : ph];                 \
                    _Pragma("unroll")                                         \
                    for (int o = 0; o < 4; ++o)                               \
                        acc[o][2*ph] = fmaf(iv, wv[o], acc[o][2*ph]);         \
                }                                                             \
            } else {                                                          \
                _Pragma("unroll")                                             \
                for (int ph = 0; ph < 4; ++ph) {                              \
                    float iv = RV[(kx == 0) ? (ph + 2) : (ph + 1)];           \
                    _Pragma("unroll")                                         \
                    for (int o = 0; o < 4; ++o)                               \
                        acc[o][2*ph+1] = fmaf(iv, wv[o], acc[o][2*ph+1]);     \
                }                                                             \
            }                                                                 \
        }                                                                     \
    }

template<int CC>
__global__ __launch_bounds__(256) void deconv_k(
    const float* __restrict__ in, const float* __restrict__ wT,
    float* __restrict__ out)
{
    __shared__ __align__(16) float ls_in[CC][2][68];
    __shared__ __align__(16) float ls_w[CC][16][64];
    int tid = threadIdx.x;
    int pxg = tid & 15, ocg = tid >> 4;
    int x0 = pxg * 8, oc0 = ocg * 4, xh = pxg * 4;
    int oy = blockIdx.x & 127, b = blockIdx.x >> 7;
    int r1 = (oy + 1) >> 1;
    int ky0 = (oy + 1) & 1;
    const float* inb = in + (size_t)b * 128 * 4096;

    float acc[4][8];
    #pragma unroll
    for (int o = 0; o < 4; ++o)
        #pragma unroll
        for (int p = 0; p < 8; ++p) acc[o][p] = 0.f;

    for (int c0 = 0; c0 < 128; c0 += CC) {
        __syncthreads();
        for (int i = tid; i < CC * 2 * 66; i += 256) {
            int xx = i % 66; int t = i / 66; int rr = t & 1; int cc = t >> 1;
            int iy = r1 - 1 + rr, gx = xx - 1;
            float v = 0.f;
            if ((unsigned)iy < 64u && (unsigned)gx < 64u)
                v = fmaxf(inb[(c0 + cc) * 4096 + iy * 64 + gx], 0.f);
            ls_in[cc][rr][xx] = v;
        }
        const float* wsrc = wT + (size_t)c0 * 16 * 64;
        for (int i = tid; i < CC * 16 * 64; i += 256)
            (&ls_w[0][0][0])[i] = wsrc[i];
        __syncthreads();

        for (int cc = 0; cc < CC; ++cc) {
            float rvA[6], rvB[6];
            {
                const float* bA = &ls_in[cc][1][xh];
                float4 v = *reinterpret_cast<const float4*>(bA);
                rvA[0]=v.x; rvA[1]=v.y; rvA[2]=v.z; rvA[3]=v.w;
                rvA[4]=bA[4]; rvA[5]=bA[5];
                const float* bB = &ls_in[cc][0][xh];
                float4 u = *reinterpret_cast<const float4*>(bB);
                rvB[0]=u.x; rvB[1]=u.y; rvB[2]=u.z; rvB[3]=u.w;
                rvB[4]=bB[4]; rvB[5]=bB[5];
            }
            const float* lw = &ls_w[cc][0][0];
            DECONV_TAPS(rvA, ky0);
            DECONV_TAPS(rvB, ky0 + 2);
        }
    }
    #pragma unroll
    for (int o = 0; o < 4; ++o) {
        float* op = out + (((size_t)b * 64 + oc0 + o) * 128 + oy) * 128 + x0;
        #pragma unroll
        for (int q = 0; q < 2; ++q) {
            float4 v = make_float4(fmaxf(acc[o][4*q],0.f), fmaxf(acc[o][4*q+1],0.f),
                                   fmaxf(acc[o][4*q+2],0.f), fmaxf(acc[o][4*q+3],0.f));
            *reinterpret_cast<float4*>(op + 4 * q) = v;
        }
    }
}

// ---------------- fused bilinear-2x(align) + conv3x3 64->3 + 2*sigmoid-1 ----
template<int CC>
__global__ __launch_bounds__(256) void upconv_k(
    const float* __restrict__ in, const float* __restrict__ wT3,
    float* __restrict__ out)
{
    __shared__ __align__(16) float ls_u[CC][6][260];
    __shared__ float ls_w[64 * 27];
    int tid = threadIdx.x;
    int pxg = tid & 63, row = tid >> 6;
    int x0 = pxg * 4;
    int yblk = blockIdx.x & 63, b = blockIdx.x >> 6;
    int y0 = yblk * 4, y = y0 + row;
    const float SCL = 127.0f / 255.0f;
    const float* hb = in + (size_t)b * 64 * 16384;

    for (int i = tid; i < 1728; i += 256) ls_w[i] = wT3[i];

    float acc[3][4];
    #pragma unroll
    for (int o = 0; o < 3; ++o)
        #pragma unroll
        for (int p = 0; p < 4; ++p) acc[o][p] = 0.f;

    for (int c0 = 0; c0 < 64; c0 += CC) {
        __syncthreads();
        for (int i = tid; i < CC * 6 * 258; i += 256) {
            int xx = i % 258; int t = i / 258; int r = t % 6; int cc = t / 6;
            int uy = y0 - 1 + r, gx = xx - 1;
            float v = 0.f;
            if ((unsigned)uy < 256u && (unsigned)gx < 256u) {
                float py = uy * SCL;
                int ylo = (int)py; int yhi = min(ylo + 1, 127); float fy = py - ylo;
                float px = gx * SCL;
                int xlo = (int)px; int xhi = min(xlo + 1, 127); float fx = px - xlo;
                const float* hp = hb + (c0 + cc) * 16384 + ylo * 128;
                const float* hq = hb + (c0 + cc) * 16384 + yhi * 128;
                float a = hp[xlo], b2 = hp[xhi], c2 = hq[xlo], d2 = hq[xhi];
                float top = a + (b2 - a) * fx;
                float bot = c2 + (d2 - c2) * fx;
                v = top + (bot - top) * fy;
            }
            ls_u[cc][r][xx] = v;
        }
        __syncthreads();

        for (int cc = 0; cc < CC; ++cc) {
            #pragma unroll
            for (int j = 0; j < 3; ++j) {
                float rv[6];
                const float* base = &ls_u[cc][row + j][x0];
                float4 v = *reinterpret_cast<const float4*>(base);
                rv[0]=v.x; rv[1]=v.y; rv[2]=v.z; rv[3]=v.w;
                rv[4]=base[4]; rv[5]=base[5];
                #pragma unroll
                for (int i2 = 0; i2 < 3; ++i2) {
                    const float* wp = &ls_w[((c0 + cc) * 9 + (j * 3 + i2)) * 3];
                    float w0 = wp[0], w1 = wp[1], w2 = wp[2];
                    #pragma unroll
                    for (int p = 0; p < 4; ++p) {
                        float iv = rv[p + i2];
                        acc[0][p] = fmaf(iv, w0, acc[0][p]);
                        acc[1][p] = fmaf(iv, w1, acc[1][p]);
                        acc[2][p] = fmaf(iv, w2, acc[2][p]);
                    }
                }
            }
        }
    }
    #pragma unroll
    for (int o = 0; o < 3; ++o) {
        float4 v;
        v.x = 2.f / (1.f + expf(-acc[o][0])) - 1.f;
        v.y = 2.f / (1.f + expf(-acc[o][1])) - 1.f;
        v.z = 2.f / (1.f + expf(-acc[o][2])) - 1.f;
        v.w = 2.f / (1.f + expf(-acc[o][3])) - 1.f;
        float* op = out + (((size_t)b * 3 + o) * 256 + y) * 256 + x0;
        *reinterpret_cast<float4*>(op) = v;
    }
}

// ---------------- codebook prep: bf16 hi/lo frag pack + ce2 + zero counts --
__global__ void prep_codebook(const float* __restrict__ cb,
                              unsigned short* __restrict__ cbh,
                              unsigned short* __restrict__ cbl,
                              float* __restrict__ ce2,
                              unsigned int* __restrict__ counts)
{
    int k = blockIdx.x * 256 + threadIdx.x;
    if (k >= 1024) return;
    float s = 0.f;
    for (int d = 0; d < 128; ++d) {
        float v = cb[k * 128 + d];
        s = fmaf(v, v, s);
        unsigned short h = f2bf(v);
        int kk = d >> 4, t = d & 15;
        cbh[(kk * 1024 + k) * 16 + t] = h;
        cbl[(kk * 1024 + k) * 16 + t] = f2bf(v - bf2f(h));
    }
    ce2[k] = s;
    counts[k] = 0u;
}

// ---------------- fused VQ v7: MFMA distance GEMM (bf16 hi/lo 3-product) ---
__global__ __launch_bounds__(512) void vq_fused(
    const float* __restrict__ z, const float* __restrict__ cb,
    const unsigned short* __restrict__ cbh,
    const unsigned short* __restrict__ cbl,
    const float* __restrict__ ce2,
    unsigned int* __restrict__ counts, float* __restrict__ q,
    double* __restrict__ partial)
{
    constexpr int ZP = 136;
    __shared__ unsigned short zh[64 * ZP];
    __shared__ unsigned short zlo[64 * ZP];
    __shared__ float ce2l[1024];
    __shared__ float cmbd[4][2][32];
    __shared__ int   cmbi[4][2][32];
    __shared__ int sidx[64];
    __shared__ float red[8];

    int tid = threadIdx.x;
    int lane = tid & 63;
    int w = tid >> 6;
    int pxg = w & 1;
    int cgrp = w >> 1;
    int ln31 = lane & 31;
    int lhf = lane >> 5;
    int p0g = blockIdx.x * 64;
    int b = p0g >> 12;
    int p0 = p0g & 4095;

    for (int i = tid; i < 8192; i += 512) {
        int d = i >> 6, px = i & 63;
        float v = z[((size_t)b * 128 + d) * 4096 + p0 + px];
        unsigned short h = f2bf(v);
        zh[px * ZP + d]  = h;
        zlo[px * ZP + d] = f2bf(v - bf2f(h));
    }
    for (int i = tid; i < 1024; i += 512) ce2l[i] = ce2[i];
    __syncthreads();

    int pxrow = pxg * 32 + ln31;
    short8v zfh[8], zfl[8];
    #pragma unroll
    for (int kk = 0; kk < 8; ++kk) {
        int off = pxrow * ZP + kk * 16 + lhf * 8;
        zfh[kk] = *reinterpret_cast<const short8v*>(&zh[off]);
        zfl[kk] = *reinterpret_cast<const short8v*>(&zlo[off]);
    }

    float best = 3.4e38f; int bidx = 0;
    #pragma unroll
    for (int ct = 0; ct < 8; ++ct) {
        int c0 = cgrp * 256 + ct * 32;
        f32x16 acc = {};
        #pragma unroll
        for (int kk = 0; kk < 8; ++kk) {
            size_t aoff = ((size_t)(kk * 1024 + c0 + ln31)) * 16 + lhf * 8;
            short8v ah = *reinterpret_cast<const short8v*>(cbh + aoff);
            short8v al = *reinterpret_cast<const short8v*>(cbl + aoff);
            acc = __builtin_amdgcn_mfma_f32_32x32x16_bf16(ah, zfh[kk], acc, 0, 0, 0);
            acc = __builtin_amdgcn_mfma_f32_32x32x16_bf16(ah, zfl[kk], acc, 0, 0, 0);
            acc = __builtin_amdgcn_mfma_f32_32x32x16_bf16(al, zfh[kk], acc, 0, 0, 0);
        }
        #pragma unroll
        for (int r = 0; r < 16; ++r) {
            int code = c0 + (r & 3) + 8 * (r >> 2) + 4 * lhf;
            float dist = ce2l[code] - 2.f * acc[r];
            if (dist < best || (dist == best && code < bidx)) { best = dist; bidx = code; }
        }
    }
    {
        float ob = __shfl_xor(best, 32);
        int   oi = __shfl_xor(bidx, 32);
        if (ob < best || (ob == best && oi < bidx)) { best = ob; bidx = oi; }
    }
    if (lane < 32) { cmbd[cgrp][pxg][lane] = best; cmbi[cgrp][pxg][lane] = bidx; }
    __syncthreads();
    if (tid < 64) {
        int pg = tid >> 5, l = tid & 31;
        float bv = cmbd[0][pg][l]; int bi = cmbi[0][pg][l];
        #pragma unroll
        for (int g = 1; g < 4; ++g) {
            float ov = cmbd[g][pg][l]; int oi = cmbi[g][pg][l];
            if (ov < bv || (ov == bv && oi < bi)) { bv = ov; bi = oi; }
        }
        sidx[pg * 32 + l] = bi;
        atomicAdd(&counts[bi], 1u);
    }
    __syncthreads();

    int pix = tid & 63, dg = tid >> 6;
    int kidx = sidx[pix];
    const float* crow = cb + (size_t)kidx * 128 + dg * 16;
    float sq = 0.f;
    size_t zbase = ((size_t)b * 128 + dg * 16) * 4096 + p0 + pix;
    #pragma unroll
    for (int ii = 0; ii < 4; ++ii) {
        float4 c4 = *reinterpret_cast<const float4*>(crow + 4 * ii);
        float vals[4] = {c4.x, c4.y, c4.z, c4.w};
        #pragma unroll
        for (int jj = 0; jj < 4; ++jj) {
            int dl = ii * 4 + jj;
            float qv = vals[jj];
            float zv = z[zbase + (size_t)dl * 4096];
            float df = qv - zv;
            sq = fmaf(df, df, sq);
            q[zbase + (size_t)dl * 4096] = qv;
        }
    }
    #pragma unroll
    for (int off = 32; off > 0; off >>= 1) sq += __shfl_xor(sq, off);
    if (lane == 0) red[w] = sq;
    __syncthreads();
    if (tid == 0) {
        double s = 0.0;
        #pragma unroll
        for (int ww = 0; ww < 8; ++ww) s += (double)red[ww];
        partial[blockIdx.x] = s;
    }
}

// ---------------- finalize ----------------
__global__ __launch_bounds__(256) void finalize_kernel(
    const double* __restrict__ partial, const unsigned int* __restrict__ counts,
    float* __restrict__ dout)
{
    __shared__ double sd[256];
    __shared__ double lossSh;
    int tid = threadIdx.x;
    double s = 0.0;
    for (int i = tid; i < 512; i += 256) s += partial[i];
    sd[tid] = s; __syncthreads();
    for (int off = 128; off > 0; off >>= 1) {
        if (tid < off) sd[tid] += sd[tid + off];
        __syncthreads();
    }
    if (tid == 0) lossSh = CC_COST * sd[0] / 4194304.0;
    __syncthreads();

    double h = 0.0;
    for (int k = tid; k < 1024; k += 256) {
        double pp = (double)counts[k] / 32768.0;
        h += pp * log(pp + 1e-10);
    }
    sd[tid] = h; __syncthreads();
    for (int off = 128; off > 0; off >>= 1) {
        if (tid < off) sd[tid] += sd[tid + off];
        __syncthreads();
    }
    if (tid == 0) {
        dout[0]       = (float)lossSh;
        dout[1572865] = (float)exp(-sd[0]);
    }
}

// ===========================================================================
extern "C" void kernel_launch(void* const* d_in, const int* in_sizes, int n_in,
                              void* d_out, int out_size, void* d_ws, size_t ws_size,
                              hipStream_t stream)
{
    const float* x        = (const float*)d_in[0];
    const float* enc_c1   = (const float*)d_in[1];
    const float* enc_c2   = (const float*)d_in[2];
    const float* enc_c3   = (const float*)d_in[3];
    const float* enc_r1a  = (const float*)d_in[4];
    const float* enc_r1b  = (const float*)d_in[5];
    const float* enc_r2a  = (const float*)d_in[6];
    const float* enc_r2b  = (const float*)d_in[7];
    const float* pre_vq_w = (const float*)d_in[8];
    const float* codebook = (const float*)d_in[9];
    const float* dec_c1   = (const float*)d_in[10];
    const float* dec_r1a  = (const float*)d_in[11];
    const float* dec_r1b  = (const float*)d_in[12];
    const float* dec_r2a  = (const float*)d_in[13];
    const float* dec_r2b  = (const float*)d_in[14];
    const float* dec_dc   = (const float*)d_in[15];
    const float* dec_c3   = (const float*)d_in[16];
    float* dout = (float*)d_out;

    char* wsp = (char*)d_ws;
    auto alloc = [&](size_t bytes) {
        void* p = (void*)wsp;
        wsp += (bytes + 255) & ~(size_t)255;
        return p;
    };
    float* h1   = (float*)alloc(8ull*64*128*128*4);   // 32MB; also qb alias
    float* bufA = (float*)alloc(8ull*128*64*64*4);    // 16MB; also zb alias
    float* bufB = (float*)alloc(8ull*128*64*64*4);    // 16MB
    float* bufT = (float*)alloc(8ull*32*64*64*4);     // 4MB
    unsigned short* cbh = (unsigned short*)alloc(131072*2);  // [8][1024][16]
    unsigned short* cbl = (unsigned short*)alloc(131072*2);
    float* ce2  = (float*)alloc(1024*4);
    unsigned int* counts = (unsigned int*)alloc(1024*4);
    double* partial = (double*)alloc(512*8);
    float* wt_ec1  = (float*)alloc(3072*4);
    float* wt_er1a = (float*)alloc(36864*4);
    float* wt_er1b = (float*)alloc(4096*4);
    float* wt_er2a = (float*)alloc(36864*4);
    float* wt_er2b = (float*)alloc(4096*4);
    float* wt_pvq  = (float*)alloc(16384*4);
    float* wt_dr1a = (float*)alloc(36864*4);
    float* wt_dr1b = (float*)alloc(4096*4);
    float* wt_dr2a = (float*)alloc(36864*4);
    float* wt_dr2b = (float*)alloc(4096*4);
    float* wt_ddc  = (float*)alloc(131072*4);
    float* wt_dc3  = (float*)alloc(1728*4);
    unsigned short* w3hi_e = (unsigned short*)alloc(147456*2);
    unsigned short* w3lo_e = (unsigned short*)alloc(147456*2);
    unsigned short* w3hi_d = (unsigned short*)alloc(147456*2);
    unsigned short* w3lo_d = (unsigned short*)alloc(147456*2);
    unsigned short* w4hi   = (unsigned short*)alloc(131072*2);
    unsigned short* w4lo   = (unsigned short*)alloc(131072*2);
    float* zb = bufA;   // alias: pre_vq out, dead before dec_c1 writes bufA
    float* qb = h1;     // alias: dead before deconv overwrites h1

    // VQ prep: bf16 frag pack + ce2 + zero counts
    prep_codebook<<<4, 256, 0, stream>>>(codebook, cbh, cbl, ce2, counts);

    // batched weight transforms (12 jobs; MFMA layers use split kernels)
    WtJobs J;
    const float* srcs[12] = {enc_c1, enc_r1a, enc_r1b, enc_r2a, enc_r2b,
                             pre_vq_w, dec_r1a, dec_r1b, dec_r2a, dec_r2b,
                             dec_dc, dec_c3};
    float* dsts[12] = {wt_ec1, wt_er1a, wt_er1b, wt_er2a, wt_er2b,
                       wt_pvq, wt_dr1a, wt_dr1b, wt_dr2a, wt_dr2b,
                       wt_ddc, wt_dc3};
    int couts[12] = {64, 32, 128, 32, 128, 128, 32, 128, 32, 128, 64, 3};
    int cins[12]  = {3, 128, 32, 128, 32, 128, 128, 32, 128, 32, 128, 64};
    int kks[12]   = {16, 9, 1, 9, 1, 1, 9, 1, 9, 1, 16, 9};
    int kinds[12] = {0, 0, 0, 0, 0, 0, 0, 0, 0, 0, 1, 2};
    int off = 0;
    for (int j = 0; j < 12; ++j) {
        J.src[j] = srcs[j]; J.dst[j] = dsts[j];
        J.cout[j] = couts[j]; J.cin[j] = cins[j]; J.kk[j] = kks[j];
        J.kind[j] = kinds[j];
        J.blk0[j] = off;
        off += (couts[j] * cins[j] * kks[j] + 255) / 256;
    }
    J.blk0[12] = off;
    for (int j = 13; j < 16; ++j) J.blk0[j] = off + 1000000;  // sentinels
    wt_batch_k<<<off, 256, 0, stream>>>(J);
    wt_split_k<<<576, 256, 0, stream>>>(enc_c3, w3hi_e, w3lo_e);
    wt_split_k<<<576, 256, 0, stream>>>(dec_c1, w3hi_d, w3lo_d);
    wt_split4_k<<<512, 256, 0, stream>>>(enc_c2, w4hi, w4lo);

    // ---- encoder ----
    conv4x4s2_k<3, 64, 128, 3, 4, 64, 1><<<1024, 256, 0, stream>>>(x, wt_ec1, h1);
    conv4x4s2_mfma<<<256, 512, 0, stream>>>(h1, w4hi, w4lo, bufA);
    conv3x3_mfma<<<256, 512, 0, stream>>>(bufA, w3hi_e, w3lo_e, bufB);
    conv3x3_res_k<<<512, 512, 0, stream>>>(bufB, wt_er1a, bufT);
    conv1x1_k<32, 128, 32, true, true><<<512, 256, 0, stream>>>(bufT, wt_er1b, bufB, bufB);
    conv3x3_res_k<<<512, 512, 0, stream>>>(bufB, wt_er2a, bufT);
    conv1x1_k<32, 128, 32, true, true><<<512, 256, 0, stream>>>(bufT, wt_er2b, bufB, bufB);
    conv1x1_k<128, 128, 32, true, false><<<512, 256, 0, stream>>>(bufB, wt_pvq, bufB, zb);

    // ---- VQ (MFMA distances + argmin + gather + loss) ----
    vq_fused<<<512, 512, 0, stream>>>(zb, codebook, cbh, cbl, ce2, counts, qb, partial);

    // ---- decoder ----
    conv3x3_mfma<<<256, 512, 0, stream>>>(qb, w3hi_d, w3lo_d, bufA);
    conv3x3_res_k<<<512, 512, 0, stream>>>(bufA, wt_dr1a, bufT);
    conv1x1_k<32, 128, 32, true, true><<<512, 256, 0, stream>>>(bufT, wt_dr1b, bufA, bufA);
    conv3x3_res_k<<<512, 512, 0, stream>>>(bufA, wt_dr2a, bufT);
    conv1x1_k<32, 128, 32, true, true><<<512, 256, 0, stream>>>(bufT, wt_dr2b, bufA, bufA);
    deconv_k<4><<<1024, 256, 0, stream>>>(bufA, wt_ddc, h1);
    upconv_k<2><<<512, 256, 0, stream>>>(h1, wt_dc3, dout + 1);

    // ---- scalars ----
    finalize_kernel<<<1, 256, 0, stream>>>(partial, counts, dout);
}

// Round 16
// 1037.873 us; speedup vs baseline: 1.1924x; 1.0509x over previous
//
#include <hip/hip_runtime.h>
#include <hip/hip_bf16.h>
#include <math.h>

#define CC_COST 0.25

typedef __attribute__((ext_vector_type(8))) short short8v;
typedef __attribute__((ext_vector_type(16))) float f32x16;

__device__ __forceinline__ unsigned short f2bf(float f) {
    unsigned u = __float_as_uint(f);
    unsigned r = (u + 0x7FFFu + ((u >> 16) & 1u)) >> 16;
    return (unsigned short)r;
}
__device__ __forceinline__ float bf2f(unsigned short h) {
    return __uint_as_float(((unsigned)h) << 16);
}

// ===========================================================================
// VQ-VAE forward. conv3x3 128ch, conv4x4s2 64->128, and VQ GEMM on MFMA
// (bf16 hi/lo 3-product ~ fp32). d_out[0]=loss, [1..]=recon, [last]=perplexity
// ===========================================================================

// ---------------- batched weight transforms (fp32 vector kernels) ----------
struct WtJobs {
    const float* src[15];
    float* dst[15];
    int cout[15], cin[15], kk[15], kind[15];
    int blk0[16];
};

__global__ void wt_batch_k(WtJobs J)
{
    int blk = blockIdx.x;
    int j = 0;
    while (j < 14 && blk >= J.blk0[j + 1]) ++j;
    int i = (blk - J.blk0[j]) * 256 + threadIdx.x;
    int total = J.cout[j] * J.cin[j] * J.kk[j];
    if (i >= total) return;
    const float* src = J.src[j];
    float* dst = J.dst[j];
    int kind = J.kind[j];
    if (kind == 0) {
        int Cout = J.cout[j], Cin = J.cin[j], KK = J.kk[j];
        int oc = i % Cout; int t2 = i / Cout; int t = t2 % KK; int c = t2 / KK;
        dst[i] = src[(oc * Cin + c) * KK + t];
    } else if (kind == 1) {
        int oc = i & 63; int t = (i >> 6) & 15; int c = i >> 10;
        dst[i] = src[(c * 64 + oc) * 16 + t];
    } else {
        int o = i % 3; int t = (i / 3) % 9; int c = i / 27;
        dst[i] = src[(o * 64 + c) * 9 + t];
    }
}

// split OIHW [128][128][3][3] fp32 -> whi/wlo bf16 in [9 tap][8 cb][128 oc][16 ci]
__global__ void wt_split_k(const float* __restrict__ w,
                           unsigned short* __restrict__ whi,
                           unsigned short* __restrict__ wlo)
{
    int i = blockIdx.x * 256 + threadIdx.x;
    if (i >= 147456) return;
    int ci = i & 15;
    int oc = (i >> 4) & 127;
    int rest = i >> 11;           // 0..71
    int cb = rest & 7;
    int tap = rest >> 3;          // 0..8
    float v = w[(oc * 128 + cb * 16 + ci) * 9 + tap];
    unsigned short h = f2bf(v);
    whi[i] = h;
    wlo[i] = f2bf(v - bf2f(h));
}

// split enc_c2 OIHW [128][64][4][4] -> [16 tap][4 cb][128 oc][16 ci] hi/lo
__global__ void wt_split4_k(const float* __restrict__ w,
                            unsigned short* __restrict__ whi,
                            unsigned short* __restrict__ wlo)
{
    int i = blockIdx.x * 256 + threadIdx.x;
    if (i >= 131072) return;
    int t = i & 15;
    int oc = (i >> 4) & 127;
    int rest = i >> 11;           // 0..63
    int cb = rest & 3;
    int tap = rest >> 2;          // 0..15
    float v = w[(oc * 64 + cb * 16 + t) * 16 + tap];
    unsigned short h = f2bf(v);
    whi[i] = h;
    wlo[i] = f2bf(v - bf2f(h));
}

// ---------------- MFMA conv3x3 s1 p1, 128->128, 64x64, batch 8 -------------
__global__ __launch_bounds__(512) void conv3x3_mfma(
    const float* __restrict__ in,           // [8,128,64,64]
    const unsigned short* __restrict__ whi, // [9][8][128][16] bf16
    const unsigned short* __restrict__ wlo,
    float* __restrict__ out)                // [8,128,64,64]
{
    constexpr int CST = 40;
    __shared__ unsigned short ls_hi[4 * 68 * CST];
    __shared__ unsigned short ls_lo[4 * 68 * CST];

    int tid = threadIdx.x;
    int lane = tid & 63;
    int w = tid >> 6;
    int myrow = w & 1;
    int oc0 = (w >> 1) * 32;
    int y0 = (blockIdx.x & 31) * 2;
    int b  = blockIdx.x >> 5;
    int ln31 = lane & 31;
    int lhf  = lane >> 5;

    f32x16 acc0 = {};
    f32x16 acc1 = {};

    const float* inb = in + (size_t)b * 128 * 4096;

    for (int chunk = 0; chunk < 4; ++chunk) {
        int c0 = chunk * 32;
        __syncthreads();
        for (int i = tid; i < 4 * 66 * 16; i += 512) {
            int x = i % 66;
            int t = i / 66;
            int cp = t & 15;
            int r = t >> 4;
            int gy = y0 - 1 + r, gx = x - 1;
            float v0 = 0.f, v1 = 0.f;
            if ((unsigned)gy < 64u && (unsigned)gx < 64u) {
                const float* p = inb + (size_t)(c0 + 2 * cp) * 4096 + gy * 64 + gx;
                v0 = p[0];
                v1 = p[4096];
            }
            unsigned short h0 = f2bf(v0), h1 = f2bf(v1);
            unsigned short l0 = f2bf(v0 - bf2f(h0)), l1 = f2bf(v1 - bf2f(h1));
            int a = (r * 68 + x) * CST + 2 * cp;
            *reinterpret_cast<unsigned int*>(&ls_hi[a]) = (unsigned)h0 | ((unsigned)h1 << 16);
            *reinterpret_cast<unsigned int*>(&ls_lo[a]) = (unsigned)l0 | ((unsigned)l1 << 16);
        }
        __syncthreads();

        #pragma unroll
        for (int tap = 0; tap < 9; ++tap) {
            int dy = tap / 3, dx = tap - 3 * (tap / 3);
            int rbase = (myrow + dy) * 68;
            #pragma unroll
            for (int cb = 0; cb < 2; ++cb) {
                int cbg = chunk * 2 + cb;
                size_t wofs = (((size_t)tap * 8 + cbg) * 128 + oc0 + ln31) * 16 + lhf * 8;
                short8v ah = *reinterpret_cast<const short8v*>(whi + wofs);
                short8v al = *reinterpret_cast<const short8v*>(wlo + wofs);
                int k0 = cb * 16 + lhf * 8;
                int xo0 = (rbase + ln31 + dx) * CST + k0;
                int xo1 = (rbase + 32 + ln31 + dx) * CST + k0;
                short8v bh0 = *reinterpret_cast<const short8v*>(&ls_hi[xo0]);
                short8v bl0 = *reinterpret_cast<const short8v*>(&ls_lo[xo0]);
                short8v bh1 = *reinterpret_cast<const short8v*>(&ls_hi[xo1]);
                short8v bl1 = *reinterpret_cast<const short8v*>(&ls_lo[xo1]);
                acc0 = __builtin_amdgcn_mfma_f32_32x32x16_bf16(ah, bh0, acc0, 0, 0, 0);
                acc1 = __builtin_amdgcn_mfma_f32_32x32x16_bf16(ah, bh1, acc1, 0, 0, 0);
                acc0 = __builtin_amdgcn_mfma_f32_32x32x16_bf16(ah, bl0, acc0, 0, 0, 0);
                acc1 = __builtin_amdgcn_mfma_f32_32x32x16_bf16(ah, bl1, acc1, 0, 0, 0);
                acc0 = __builtin_amdgcn_mfma_f32_32x32x16_bf16(al, bh0, acc0, 0, 0, 0);
                acc1 = __builtin_amdgcn_mfma_f32_32x32x16_bf16(al, bh1, acc1, 0, 0, 0);
            }
        }
    }

    float* ob = out + (size_t)b * 128 * 4096 + (size_t)(y0 + myrow) * 64;
    #pragma unroll
    for (int r = 0; r < 16; ++r) {
        int oc = oc0 + (r & 3) + 8 * (r >> 2) + 4 * lhf;
        ob[(size_t)oc * 4096 + ln31]      = acc0[r];
        ob[(size_t)oc * 4096 + 32 + ln31] = acc1[r];
    }
}

// ---------------- MFMA conv4x4 s2 p1, 64->128, in 128x128 -> out 64x64 -----
__global__ __launch_bounds__(512) void conv4x4s2_mfma(
    const float* __restrict__ in,            // [8,64,128,128] post-relu
    const unsigned short* __restrict__ whi,  // [16 tap][4 cb][128 oc][16 ci]
    const unsigned short* __restrict__ wlo,
    float* __restrict__ out)                 // [8,128,64,64], relu out
{
    constexpr int CST = 24;                  // 16 ci + 8 pad (48B = 16B-aligned)
    __shared__ unsigned short lsEh[6 * 65 * CST];
    __shared__ unsigned short lsEl[6 * 65 * CST];
    __shared__ unsigned short lsOh[6 * 65 * CST];
    __shared__ unsigned short lsOl[6 * 65 * CST];

    int tid = threadIdx.x;
    int lane = tid & 63;
    int w = tid >> 6;
    int myrow = w & 1;
    int oc0 = (w >> 1) * 32;
    int y0 = (blockIdx.x & 31) * 2;
    int b  = blockIdx.x >> 5;
    int ln31 = lane & 31;
    int lhf  = lane >> 5;

    f32x16 acc0 = {};
    f32x16 acc1 = {};

    const float* inb = in + (size_t)b * 64 * 16384;

    for (int cb = 0; cb < 4; ++cb) {
        int c0 = cb * 16;
        __syncthreads();
        for (int i = tid; i < 12480; i += 512) {
            int gxi = i % 130; int t2 = i / 130;
            int r = t2 % 6; int cc = t2 / 6;
            int gx = gxi - 1;
            int gy = 2 * y0 - 1 + r;
            float v = 0.f;
            if ((unsigned)gy < 128u && (unsigned)gx < 128u)
                v = inb[(size_t)(c0 + cc) * 16384 + gy * 128 + gx];
            unsigned short h = f2bf(v);
            unsigned short l = f2bf(v - bf2f(h));
            if (gx & 1) {
                int a = (r * 65 + ((gx + 1) >> 1)) * CST + cc;
                lsOh[a] = h; lsOl[a] = l;
            } else {
                int a = (r * 65 + (gx >> 1)) * CST + cc;
                lsEh[a] = h; lsEl[a] = l;
            }
        }
        __syncthreads();

        #pragma unroll
        for (int tap = 0; tap < 16; ++tap) {
            int ky = tap >> 2, kx = tap & 3;
            int ridx = 2 * myrow + ky;
            int dlt = kx >> 1;
            const unsigned short* ph = (kx & 1) ? lsEh : lsOh;
            const unsigned short* pl = (kx & 1) ? lsEl : lsOl;
            size_t aoff = ((size_t)((tap * 4 + cb) * 128 + oc0 + ln31)) * 16 + lhf * 8;
            short8v ah = *reinterpret_cast<const short8v*>(whi + aoff);
            short8v al = *reinterpret_cast<const short8v*>(wlo + aoff);
            int base0 = (ridx * 65 + ln31 + dlt) * CST + lhf * 8;
            int base1 = (ridx * 65 + 32 + ln31 + dlt) * CST + lhf * 8;
            short8v bh0 = *reinterpret_cast<const short8v*>(ph + base0);
            short8v bl0 = *reinterpret_cast<const short8v*>(pl + base0);
            short8v bh1 = *reinterpret_cast<const short8v*>(ph + base1);
            short8v bl1 = *reinterpret_cast<const short8v*>(pl + base1);
            acc0 = __builtin_amdgcn_mfma_f32_32x32x16_bf16(ah, bh0, acc0, 0, 0, 0);
            acc1 = __builtin_amdgcn_mfma_f32_32x32x16_bf16(ah, bh1, acc1, 0, 0, 0);
            acc0 = __builtin_amdgcn_mfma_f32_32x32x16_bf16(ah, bl0, acc0, 0, 0, 0);
            acc1 = __builtin_amdgcn_mfma_f32_32x32x16_bf16(ah, bl1, acc1, 0, 0, 0);
            acc0 = __builtin_amdgcn_mfma_f32_32x32x16_bf16(al, bh0, acc0, 0, 0, 0);
            acc1 = __builtin_amdgcn_mfma_f32_32x32x16_bf16(al, bh1, acc1, 0, 0, 0);
        }
    }

    int y = y0 + myrow;
    float* ob = out + (size_t)b * 128 * 4096 + (size_t)y * 64;
    #pragma unroll
    for (int r = 0; r < 16; ++r) {
        int oc = oc0 + (r & 3) + 8 * (r >> 2) + 4 * lhf;
        ob[(size_t)oc * 4096 + ln31]      = fmaxf(acc0[r], 0.f);
        ob[(size_t)oc * 4096 + 32 + ln31] = fmaxf(acc1[r], 0.f);
    }
}

// ---------------- split-K res conv3x3: 128->32, relu(in), raw out ----------
__global__ __launch_bounds__(512) void conv3x3_res_k(
    const float* __restrict__ in, const float* __restrict__ wT,  // [c][9][32]
    float* __restrict__ out)
{
    constexpr int CC = 8;
    __shared__ __align__(16) float ls_in[2][CC][3][68];
    __shared__ __align__(16) float ls_w[2][CC][9][32];
    __shared__ float ts[8][256];
    int tid = threadIdx.x;
    int g = tid >> 8, t = tid & 255;
    int pxg = t & 15, ocg = t >> 4;
    int x0 = pxg * 4, oc0 = ocg * 2;
    int y = blockIdx.x & 63, b = blockIdx.x >> 6;
    const float* inb = in + ((size_t)b * 128 + g * 64) * 4096;

    float acc[2][4];
    #pragma unroll
    for (int o = 0; o < 2; ++o)
        #pragma unroll
        for (int p = 0; p < 4; ++p) acc[o][p] = 0.f;

    for (int c0 = 0; c0 < 64; c0 += CC) {
        __syncthreads();
        for (int i = t; i < CC * 3 * 66; i += 256) {
            int xx = i % 66; int tt = i / 66; int r = tt % 3; int cc = tt / 3;
            int gy = y - 1 + r, gx = xx - 1;
            float v = 0.f;
            if ((unsigned)gy < 64u && (unsigned)gx < 64u)
                v = fmaxf(inb[(c0 + cc) * 4096 + gy * 64 + gx], 0.f);
            ls_in[g][cc][r][xx] = v;
        }
        const float* wsrc = wT + (size_t)(g * 64 + c0) * 9 * 32;
        for (int i = t; i < CC * 9 * 32; i += 256)
            (&ls_w[g][0][0][0])[i] = wsrc[i];
        __syncthreads();

        for (int cc = 0; cc < CC; ++cc) {
            float rv[3][6];
            #pragma unroll
            for (int r = 0; r < 3; ++r) {
                const float* base = &ls_in[g][cc][r][x0];
                float4 v = *reinterpret_cast<const float4*>(base);
                rv[r][0]=v.x; rv[r][1]=v.y; rv[r][2]=v.z; rv[r][3]=v.w;
                rv[r][4]=base[4]; rv[r][5]=base[5];
            }
            const float* lw = &ls_w[g][cc][0][0];
            #pragma unroll
            for (int dy = 0; dy < 3; ++dy) {
                #pragma unroll
                for (int dx = 0; dx < 3; ++dx) {
                    float2 w2 = *reinterpret_cast<const float2*>(lw + (dy * 3 + dx) * 32 + oc0);
                    float wv[2] = {w2.x, w2.y};
                    #pragma unroll
                    for (int p = 0; p < 4; ++p) {
                        float iv = rv[dy][p + dx];
                        acc[0][p] = fmaf(iv, wv[0], acc[0][p]);
                        acc[1][p] = fmaf(iv, wv[1], acc[1][p]);
                    }
                }
            }
        }
    }
    if (g == 0) {
        #pragma unroll
        for (int o = 0; o < 2; ++o)
            #pragma unroll
            for (int p = 0; p < 4; ++p) ts[o * 4 + p][t] = acc[o][p];
    }
    __syncthreads();
    if (g == 1) {
        #pragma unroll
        for (int o = 0; o < 2; ++o) {
            float4 v = make_float4(ts[o*4+0][t] + acc[o][0], ts[o*4+1][t] + acc[o][1],
                                   ts[o*4+2][t] + acc[o][2], ts[o*4+3][t] + acc[o][3]);
            float* op = out + (((size_t)b * 32 + oc0 + o) * 64 + y) * 64 + x0;
            *reinterpret_cast<float4*>(op) = v;
        }
    }
}

// ---------------- conv 1x1 on 64x64 (COUT must be 128) ----------------
template<int CIN, int COUT, int CC, bool IN_RELU, bool ADD_RES>
__global__ __launch_bounds__(256) void conv1x1_k(
    const float* __restrict__ in, const float* __restrict__ wT,
    const float* __restrict__ res, float* __restrict__ out)
{
    static_assert(COUT == 128, "tile assumes 128");
    __shared__ __align__(16) float ls_in[CC][64];
    __shared__ __align__(16) float ls_w[CC][COUT];
    int tid = threadIdx.x;
    int pxg = tid & 7, ocg = tid >> 3;
    int x0 = pxg * 8, oc0 = ocg * 4;
    int y = blockIdx.x & 63, b = blockIdx.x >> 6;

    float acc[4][8];
    #pragma unroll
    for (int o = 0; o < 4; ++o)
        #pragma unroll
        for (int p = 0; p < 8; ++p) acc[o][p] = 0.f;

    for (int c0 = 0; c0 < CIN; c0 += CC) {
        __syncthreads();
        for (int i = tid; i < CC * 64; i += 256) {
            int xx = i & 63, cc = i >> 6;
            float v = in[(((size_t)b * CIN + c0 + cc) * 64 + y) * 64 + xx];
            if (IN_RELU) v = fmaxf(v, 0.f);
            ls_in[cc][xx] = v;
        }
        const float* wsrc = wT + (size_t)c0 * COUT;
        for (int i = tid; i < CC * COUT; i += 256)
            (&ls_w[0][0])[i] = wsrc[i];
        __syncthreads();

        for (int cc = 0; cc < CC; ++cc) {
            float rv[8];
            const float* base = &ls_in[cc][x0];
            float4 v0 = *reinterpret_cast<const float4*>(base);
            float4 v1 = *reinterpret_cast<const float4*>(base + 4);
            rv[0]=v0.x; rv[1]=v0.y; rv[2]=v0.z; rv[3]=v0.w;
            rv[4]=v1.x; rv[5]=v1.y; rv[6]=v1.z; rv[7]=v1.w;
            float4 w4 = *reinterpret_cast<const float4*>(&ls_w[cc][oc0]);
            float wv[4] = {w4.x, w4.y, w4.z, w4.w};
            #pragma unroll
            for (int p = 0; p < 8; ++p)
                #pragma unroll
                for (int o = 0; o < 4; ++o)
                    acc[o][p] = fmaf(rv[p], wv[o], acc[o][p]);
        }
    }
    #pragma unroll
    for (int o = 0; o < 4; ++o) {
        float* op = out + (((size_t)b * COUT + oc0 + o) * 64 + y) * 64 + x0;
        const float* rp = res + (((size_t)b * COUT + oc0 + o) * 64 + y) * 64 + x0;
        #pragma unroll
        for (int q = 0; q < 2; ++q) {
            float4 v = make_float4(acc[o][4*q], acc[o][4*q+1],
                                   acc[o][4*q+2], acc[o][4*q+3]);
            if (ADD_RES) {
                float4 r4 = *reinterpret_cast<const float4*>(rp + 4 * q);
                v.x += r4.x; v.y += r4.y; v.z += r4.z; v.w += r4.w;
            }
            *reinterpret_cast<float4*>(op + 4 * q) = v;
        }
    }
}

// ---------------- conv 4x4 s2 p1 (vector; used for enc_c1 3->64) -----------
template<int CIN, int COUT, int WOUT, int CC, int OCB, int WOC, int NSLICE>
__global__ __launch_bounds__(256) void conv4x4s2_k(
    const float* __restrict__ in, const float* __restrict__ wT,
    float* __restrict__ out)
{
    constexpr int WIN = WOUT * 2;
    constexpr int NPXG = WOUT / 8, NOCG = COUT / OCB;
    static_assert(NPXG * NOCG == 256, "bad tile");
    constexpr int WUSE = 2 * WOUT + 2;
    constexpr int PADLEN = ((WUSE + (WUSE / 16 + 1) * 4) + 3) & ~3;
    __shared__ __align__(16) float ls_in[CC][4][PADLEN];
    __shared__ __align__(16) float ls_w[CC][16][COUT];

    int tid = threadIdx.x;
    int pxg = tid % NPXG, ocg = tid / NPXG;
    int x0 = pxg * 8, oc0 = ocg * OCB;
    int blk = blockIdx.x;
    int y = blk % WOUT; int rest = blk / WOUT;
    int slice = rest % NSLICE; int b = rest / NSLICE;
    int oc_base = slice * COUT;
    const float* inb = in + (size_t)b * CIN * WIN * WIN;

    float acc[OCB][8];
    #pragma unroll
    for (int o = 0; o < OCB; ++o)
        #pragma unroll
        for (int p = 0; p < 8; ++p) acc[o][p] = 0.f;

    for (int c0 = 0; c0 < CIN; c0 += CC) {
        __syncthreads();
        for (int i = tid; i < CC * 4 * WUSE; i += 256) {
            int xx = i % WUSE; int t = i / WUSE; int r = t & 3; int cc = t >> 2;
            int gy = 2 * y - 1 + r, gx = xx - 1;
            float v = 0.f;
            if ((unsigned)gy < (unsigned)WIN && (unsigned)gx < (unsigned)WIN)
                v = inb[(c0 + cc) * WIN * WIN + gy * WIN + gx];
            ls_in[cc][r][xx + ((xx >> 4) << 2)] = v;
        }
        const float* wsrc = wT + (size_t)c0 * 16 * WOC + oc_base;
        for (int i = tid; i < CC * 16 * COUT; i += 256) {
            int o = i % COUT; int tt = (i / COUT) % 16; int cc = i / (16 * COUT);
            ls_w[cc][tt][o] = wsrc[(cc * 16 + tt) * WOC + o];
        }
        __syncthreads();

        for (int cc = 0; cc < CC; ++cc) {
            const float* lw = &ls_w[cc][0][0];
            #pragma unroll
            for (int ky = 0; ky < 4; ++ky) {
                float rv[18];
                const float* base = &ls_in[cc][ky][20 * pxg];
                #pragma unroll
                for (int q = 0; q < 4; ++q) {
                    float4 v = *reinterpret_cast<const float4*>(base + 4 * q);
                    rv[4*q]=v.x; rv[4*q+1]=v.y; rv[4*q+2]=v.z; rv[4*q+3]=v.w;
                }
                rv[16] = base[20]; rv[17] = base[21];
                #pragma unroll
                for (int kx = 0; kx < 4; ++kx) {
                    const float* wp = lw + (ky * 4 + kx) * COUT + oc0;
                    float wv[OCB];
                    if constexpr (OCB == 4) {
                        float4 w4 = *reinterpret_cast<const float4*>(wp);
                        wv[0]=w4.x; wv[1]=w4.y; wv[2]=w4.z; wv[3]=w4.w;
                    } else {
                        float2 w2 = *reinterpret_cast<const float2*>(wp);
                        wv[0]=w2.x; wv[1]=w2.y;
                    }
                    #pragma unroll
                    for (int p = 0; p < 8; ++p) {
                        float iv = rv[2 * p + kx];
                        #pragma unroll
                        for (int o = 0; o < OCB; ++o)
                            acc[o][p] = fmaf(iv, wv[o], acc[o][p]);
                    }
                }
            }
        }
    }
    #pragma unroll
    for (int o = 0; o < OCB; ++o) {
        float* op = out + (((size_t)b * (COUT * NSLICE) + oc_base + oc0 + o) * WOUT + y) * WOUT + x0;
        #pragma unroll
        for (int q = 0; q < 2; ++q) {
            float4 v = make_float4(fmaxf(acc[o][4*q],0.f), fmaxf(acc[o][4*q+1],0.f),
                                   fmaxf(acc[o][4*q+2],0.f), fmaxf(acc[o][4*q+3],0.f));
            *reinterpret_cast<float4*>(op + 4 * q) = v;
        }
    }
}

// ---------------- deconv 4x4 s2 p1, 128->64, relu(in) folded, relu out ------
#define DECONV_TAPS(RV, KY)                                                   \
    {                                                                         \
        int ky_ = (KY);                                                       \
        _Pragma("unroll")                                                     \
        for (int kx = 0; kx < 4; ++kx) {                                      \
            float4 w4 = *reinterpret_cast<const float4*>(                     \
                lw + (ky_ * 4 + kx) * 64 + oc0);                              \
            float wv[4] = {w4.x, w4.y, w4.z, w4.w};                           \
            if (kx & 1) {                                                     \
                _Pragma("unroll")                                             \
                for (int ph = 0; ph < 4; ++ph) {                              \
                    float iv = RV[(kx == 1) ? (ph + 1) : ph];                 \
                    _Pragma("unroll")                                         \
                    for (int o = 0; o < 4; ++o)                               \
                        acc[o][2*ph] = fmaf(iv, wv[o], acc[o][2*ph]);         \
                }                                                             \
            } else {                                                          \
                _Pragma("unroll")                                             \
                for (int ph = 0; ph < 4; ++ph) {                              \
                    float iv = RV[(kx == 0) ? (ph + 2) : (ph + 1)];           \
                    _Pragma("unroll")                                         \
                    for (int o = 0; o < 4; ++o)                               \
                        acc[o][2*ph+1] = fmaf(iv, wv[o], acc[o][2*ph+1]);     \
                }                                                             \
            }                                                                 \
        }                                                                     \
    }

template<int CC>
__global__ __launch_bounds__(256) void deconv_k(
    const float* __restrict__ in, const float* __restrict__ wT,
    float* __restrict__ out)
{
    __shared__ __align__(16) float ls_in[CC][2][68];
    __shared__ __align__(16) float ls_w[CC][16][64];
    int tid = threadIdx.x;
    int pxg = tid & 15, ocg = tid >> 4;
    int x0 = pxg * 8, oc0 = ocg * 4, xh = pxg * 4;
    int oy = blockIdx.x & 127, b = blockIdx.x >> 7;
    int r1 = (oy + 1) >> 1;
    int ky0 = (oy + 1) & 1;
    const float* inb = in + (size_t)b * 128 * 4096;

    float acc[4][8];
    #pragma unroll
    for (int o = 0; o < 4; ++o)
        #pragma unroll
        for (int p = 0; p < 8; ++p) acc[o][p] = 0.f;

    for (int c0 = 0; c0 < 128; c0 += CC) {
        __syncthreads();
        for (int i = tid; i < CC * 2 * 66; i += 256) {
            int xx = i % 66; int t = i / 66; int rr = t & 1; int cc = t >> 1;
            int iy = r1 - 1 + rr, gx = xx - 1;
            float v = 0.f;
            if ((unsigned)iy < 64u && (unsigned)gx < 64u)
                v = fmaxf(inb[(c0 + cc) * 4096 + iy * 64 + gx], 0.f);
            ls_in[cc][rr][xx] = v;
        }
        const float* wsrc = wT + (size_t)c0 * 16 * 64;
        for (int i = tid; i < CC * 16 * 64; i += 256)
            (&ls_w[0][0][0])[i] = wsrc[i];
        __syncthreads();

        for (int cc = 0; cc < CC; ++cc) {
            float rvA[6], rvB[6];
            {
                const float* bA = &ls_in[cc][1][xh];
                float4 v = *reinterpret_cast<const float4*>(bA);
                rvA[0]=v.x; rvA[1]=v.y; rvA[2]=v.z; rvA[3]=v.w;
                rvA[4]=bA[4]; rvA[5]=bA[5];
                const float* bB = &ls_in[cc][0][xh];
                float4 u = *reinterpret_cast<const float4*>(bB);
                rvB[0]=u.x; rvB[1]=u.y; rvB[2]=u.z; rvB[3]=u.w;
                rvB[4]=bB[4]; rvB[5]=bB[5];
            }
            const float* lw = &ls_w[cc][0][0];
            DECONV_TAPS(rvA, ky0);
            DECONV_TAPS(rvB, ky0 + 2);
        }
    }
    #pragma unroll
    for (int o = 0; o < 4; ++o) {
        float* op = out + (((size_t)b * 64 + oc0 + o) * 128 + oy) * 128 + x0;
        #pragma unroll
        for (int q = 0; q < 2; ++q) {
            float4 v = make_float4(fmaxf(acc[o][4*q],0.f), fmaxf(acc[o][4*q+1],0.f),
                                   fmaxf(acc[o][4*q+2],0.f), fmaxf(acc[o][4*q+3],0.f));
            *reinterpret_cast<float4*>(op + 4 * q) = v;
        }
    }
}

// ---------------- fused bilinear-2x(align) + conv3x3 64->3 + 2*sigmoid-1 ----
// v2: x-split (grid 1024 = b*yblk*2), precomputed x-weight tables, CC=8.
// Block: 4 output rows x 128 px; thread: 3 oc x 2 px.
template<int CC>
__global__ __launch_bounds__(256) void upconv_k(
    const float* __restrict__ in,    // h1 [8,64,128,128] post-relu
    const float* __restrict__ wT3,   // [64][9][3]
    float* __restrict__ out)         // [8,3,256,256]
{
    __shared__ __align__(16) float ls_u[CC][6][132];
    __shared__ float ls_w[64 * 27];
    __shared__ float xfx[132];
    __shared__ int   xloT[132];

    int tid = threadIdx.x;
    int row = tid >> 6;              // 0..3
    int pxl = tid & 63;              // 64 groups x 2 px
    int blk = blockIdx.x;
    int xh = blk & 1;
    int yblk = (blk >> 1) & 63;
    int b = blk >> 7;
    int xbase = xh * 128;
    int y0 = yblk * 4, y = y0 + row;
    const float SCL = 127.0f / 255.0f;
    const float* hb = in + (size_t)b * 64 * 16384;

    for (int i = tid; i < 1728; i += 256) ls_w[i] = wT3[i];
    if (tid < 130) {
        int ux = xbase - 1 + tid;
        bool v = ((unsigned)ux < 256u);
        float px = (v ? ux : 0) * SCL;
        int lo = (int)px;
        xloT[tid] = lo;
        xfx[tid] = v ? (px - (float)lo) : -1.0f;   // -1 marks OOB
    }

    float acc[3][2];
    #pragma unroll
    for (int o = 0; o < 3; ++o) { acc[o][0] = 0.f; acc[o][1] = 0.f; }

    for (int c0 = 0; c0 < 64; c0 += CC) {
        __syncthreads();
        for (int i = tid; i < CC * 6 * 130; i += 256) {
            int xx = i % 130; int t = i / 130; int r = t % 6; int cc = t / 6;
            int uy = y0 - 1 + r;
            float v = 0.f;
            float fx = xfx[xx];
            if ((unsigned)uy < 256u && fx >= 0.f) {
                float py = uy * SCL;
                int ylo = (int)py; int yhi = min(ylo + 1, 127); float fy = py - (float)ylo;
                int lo = xloT[xx]; int hi = min(lo + 1, 127);
                const float* hp = hb + (size_t)(c0 + cc) * 16384 + ylo * 128;
                const float* hq = hb + (size_t)(c0 + cc) * 16384 + yhi * 128;
                float a = hp[lo], b2 = hp[hi], c2 = hq[lo], d2 = hq[hi];
                float top = a + (b2 - a) * fx;
                float bot = c2 + (d2 - c2) * fx;
                v = top + (bot - top) * fy;
            }
            ls_u[cc][r][xx] = v;
        }
        __syncthreads();

        for (int cc = 0; cc < CC; ++cc) {
            #pragma unroll
            for (int j = 0; j < 3; ++j) {
                const float* base = &ls_u[cc][row + j][pxl * 2];
                float2 a0 = *reinterpret_cast<const float2*>(base);
                float2 a1 = *reinterpret_cast<const float2*>(base + 2);
                float rv[4] = {a0.x, a0.y, a1.x, a1.y};
                #pragma unroll
                for (int i2 = 0; i2 < 3; ++i2) {
                    const float* wp = &ls_w[((c0 + cc) * 9 + (j * 3 + i2)) * 3];
                    float w0 = wp[0], w1 = wp[1], w2 = wp[2];
                    #pragma unroll
                    for (int p = 0; p < 2; ++p) {
                        float iv = rv[p + i2];
                        acc[0][p] = fmaf(iv, w0, acc[0][p]);
                        acc[1][p] = fmaf(iv, w1, acc[1][p]);
                        acc[2][p] = fmaf(iv, w2, acc[2][p]);
                    }
                }
            }
        }
    }
    int x0 = xbase + pxl * 2;
    #pragma unroll
    for (int o = 0; o < 3; ++o) {
        float2 v;
        v.x = 2.f / (1.f + expf(-acc[o][0])) - 1.f;
        v.y = 2.f / (1.f + expf(-acc[o][1])) - 1.f;
        float* op = out + (((size_t)b * 3 + o) * 256 + y) * 256 + x0;
        *reinterpret_cast<float2*>(op) = v;
    }
}

// ---------------- codebook prep: bf16 hi/lo frag pack + ce2 + zero counts --
__global__ void prep_codebook(const float* __restrict__ cb,
                              unsigned short* __restrict__ cbh,
                              unsigned short* __restrict__ cbl,
                              float* __restrict__ ce2,
                              unsigned int* __restrict__ counts)
{
    int k = blockIdx.x * 256 + threadIdx.x;
    if (k >= 1024) return;
    float s = 0.f;
    for (int d = 0; d < 128; ++d) {
        float v = cb[k * 128 + d];
        s = fmaf(v, v, s);
        unsigned short h = f2bf(v);
        int kk = d >> 4, t = d & 15;
        cbh[(kk * 1024 + k) * 16 + t] = h;
        cbl[(kk * 1024 + k) * 16 + t] = f2bf(v - bf2f(h));
    }
    ce2[k] = s;
    counts[k] = 0u;
}

// ---------------- fused VQ v7: MFMA distance GEMM (bf16 hi/lo 3-product) ---
__global__ __launch_bounds__(512) void vq_fused(
    const float* __restrict__ z, const float* __restrict__ cb,
    const unsigned short* __restrict__ cbh,
    const unsigned short* __restrict__ cbl,
    const float* __restrict__ ce2,
    unsigned int* __restrict__ counts, float* __restrict__ q,
    double* __restrict__ partial)
{
    constexpr int ZP = 136;
    __shared__ unsigned short zh[64 * ZP];
    __shared__ unsigned short zlo[64 * ZP];
    __shared__ float ce2l[1024];
    __shared__ float cmbd[4][2][32];
    __shared__ int   cmbi[4][2][32];
    __shared__ int sidx[64];
    __shared__ float red[8];

    int tid = threadIdx.x;
    int lane = tid & 63;
    int w = tid >> 6;
    int pxg = w & 1;
    int cgrp = w >> 1;
    int ln31 = lane & 31;
    int lhf = lane >> 5;
    int p0g = blockIdx.x * 64;
    int b = p0g >> 12;
    int p0 = p0g & 4095;

    for (int i = tid; i < 8192; i += 512) {
        int d = i >> 6, px = i & 63;
        float v = z[((size_t)b * 128 + d) * 4096 + p0 + px];
        unsigned short h = f2bf(v);
        zh[px * ZP + d]  = h;
        zlo[px * ZP + d] = f2bf(v - bf2f(h));
    }
    for (int i = tid; i < 1024; i += 512) ce2l[i] = ce2[i];
    __syncthreads();

    int pxrow = pxg * 32 + ln31;
    short8v zfh[8], zfl[8];
    #pragma unroll
    for (int kk = 0; kk < 8; ++kk) {
        int off = pxrow * ZP + kk * 16 + lhf * 8;
        zfh[kk] = *reinterpret_cast<const short8v*>(&zh[off]);
        zfl[kk] = *reinterpret_cast<const short8v*>(&zlo[off]);
    }

    float best = 3.4e38f; int bidx = 0;
    #pragma unroll
    for (int ct = 0; ct < 8; ++ct) {
        int c0 = cgrp * 256 + ct * 32;
        f32x16 acc = {};
        #pragma unroll
        for (int kk = 0; kk < 8; ++kk) {
            size_t aoff = ((size_t)(kk * 1024 + c0 + ln31)) * 16 + lhf * 8;
            short8v ah = *reinterpret_cast<const short8v*>(cbh + aoff);
            short8v al = *reinterpret_cast<const short8v*>(cbl + aoff);
            acc = __builtin_amdgcn_mfma_f32_32x32x16_bf16(ah, zfh[kk], acc, 0, 0, 0);
            acc = __builtin_amdgcn_mfma_f32_32x32x16_bf16(ah, zfl[kk], acc, 0, 0, 0);
            acc = __builtin_amdgcn_mfma_f32_32x32x16_bf16(al, zfh[kk], acc, 0, 0, 0);
        }
        #pragma unroll
        for (int r = 0; r < 16; ++r) {
            int code = c0 + (r & 3) + 8 * (r >> 2) + 4 * lhf;
            float dist = ce2l[code] - 2.f * acc[r];
            if (dist < best || (dist == best && code < bidx)) { best = dist; bidx = code; }
        }
    }
    {
        float ob = __shfl_xor(best, 32);
        int   oi = __shfl_xor(bidx, 32);
        if (ob < best || (ob == best && oi < bidx)) { best = ob; bidx = oi; }
    }
    if (lane < 32) { cmbd[cgrp][pxg][lane] = best; cmbi[cgrp][pxg][lane] = bidx; }
    __syncthreads();
    if (tid < 64) {
        int pg = tid >> 5, l = tid & 31;
        float bv = cmbd[0][pg][l]; int bi = cmbi[0][pg][l];
        #pragma unroll
        for (int g = 1; g < 4; ++g) {
            float ov = cmbd[g][pg][l]; int oi = cmbi[g][pg][l];
            if (ov < bv || (ov == bv && oi < bi)) { bv = ov; bi = oi; }
        }
        sidx[pg * 32 + l] = bi;
        atomicAdd(&counts[bi], 1u);
    }
    __syncthreads();

    int pix = tid & 63, dg = tid >> 6;
    int kidx = sidx[pix];
    const float* crow = cb + (size_t)kidx * 128 + dg * 16;
    float sq = 0.f;
    size_t zbase = ((size_t)b * 128 + dg * 16) * 4096 + p0 + pix;
    #pragma unroll
    for (int ii = 0; ii < 4; ++ii) {
        float4 c4 = *reinterpret_cast<const float4*>(crow + 4 * ii);
        float vals[4] = {c4.x, c4.y, c4.z, c4.w};
        #pragma unroll
        for (int jj = 0; jj < 4; ++jj) {
            int dl = ii * 4 + jj;
            float qv = vals[jj];
            float zv = z[zbase + (size_t)dl * 4096];
            float df = qv - zv;
            sq = fmaf(df, df, sq);
            q[zbase + (size_t)dl * 4096] = qv;
        }
    }
    #pragma unroll
    for (int off = 32; off > 0; off >>= 1) sq += __shfl_xor(sq, off);
    if (lane == 0) red[w] = sq;
    __syncthreads();
    if (tid == 0) {
        double s = 0.0;
        #pragma unroll
        for (int ww = 0; ww < 8; ++ww) s += (double)red[ww];
        partial[blockIdx.x] = s;
    }
}

// ---------------- finalize ----------------
__global__ __launch_bounds__(256) void finalize_kernel(
    const double* __restrict__ partial, const unsigned int* __restrict__ counts,
    float* __restrict__ dout)
{
    __shared__ double sd[256];
    __shared__ double lossSh;
    int tid = threadIdx.x;
    double s = 0.0;
    for (int i = tid; i < 512; i += 256) s += partial[i];
    sd[tid] = s; __syncthreads();
    for (int off = 128; off > 0; off >>= 1) {
        if (tid < off) sd[tid] += sd[tid + off];
        __syncthreads();
    }
    if (tid == 0) lossSh = CC_COST * sd[0] / 4194304.0;
    __syncthreads();

    double h = 0.0;
    for (int k = tid; k < 1024; k += 256) {
        double pp = (double)counts[k] / 32768.0;
        h += pp * log(pp + 1e-10);
    }
    sd[tid] = h; __syncthreads();
    for (int off = 128; off > 0; off >>= 1) {
        if (tid < off) sd[tid] += sd[tid + off];
        __syncthreads();
    }
    if (tid == 0) {
        dout[0]       = (float)lossSh;
        dout[1572865] = (float)exp(-sd[0]);
    }
}

// ===========================================================================
extern "C" void kernel_launch(void* const* d_in, const int* in_sizes, int n_in,
                              void* d_out, int out_size, void* d_ws, size_t ws_size,
                              hipStream_t stream)
{
    const float* x        = (const float*)d_in[0];
    const float* enc_c1   = (const float*)d_in[1];
    const float* enc_c2   = (const float*)d_in[2];
    const float* enc_c3   = (const float*)d_in[3];
    const float* enc_r1a  = (const float*)d_in[4];
    const float* enc_r1b  = (const float*)d_in[5];
    const float* enc_r2a  = (const float*)d_in[6];
    const float* enc_r2b  = (const float*)d_in[7];
    const float* pre_vq_w = (const float*)d_in[8];
    const float* codebook = (const float*)d_in[9];
    const float* dec_c1   = (const float*)d_in[10];
    const float* dec_r1a  = (const float*)d_in[11];
    const float* dec_r1b  = (const float*)d_in[12];
    const float* dec_r2a  = (const float*)d_in[13];
    const float* dec_r2b  = (const float*)d_in[14];
    const float* dec_dc   = (const float*)d_in[15];
    const float* dec_c3   = (const float*)d_in[16];
    float* dout = (float*)d_out;

    char* wsp = (char*)d_ws;
    auto alloc = [&](size_t bytes) {
        void* p = (void*)wsp;
        wsp += (bytes + 255) & ~(size_t)255;
        return p;
    };
    float* h1   = (float*)alloc(8ull*64*128*128*4);   // 32MB; also qb alias
    float* bufA = (float*)alloc(8ull*128*64*64*4);    // 16MB; also zb alias
    float* bufB = (float*)alloc(8ull*128*64*64*4);    // 16MB
    float* bufT = (float*)alloc(8ull*32*64*64*4);     // 4MB
    unsigned short* cbh = (unsigned short*)alloc(131072*2);  // [8][1024][16]
    unsigned short* cbl = (unsigned short*)alloc(131072*2);
    float* ce2  = (float*)alloc(1024*4);
    unsigned int* counts = (unsigned int*)alloc(1024*4);
    double* partial = (double*)alloc(512*8);
    float* wt_ec1  = (float*)alloc(3072*4);
    float* wt_er1a = (float*)alloc(36864*4);
    float* wt_er1b = (float*)alloc(4096*4);
    float* wt_er2a = (float*)alloc(36864*4);
    float* wt_er2b = (float*)alloc(4096*4);
    float* wt_pvq  = (float*)alloc(16384*4);
    float* wt_dr1a = (float*)alloc(36864*4);
    float* wt_dr1b = (float*)alloc(4096*4);
    float* wt_dr2a = (float*)alloc(36864*4);
    float* wt_dr2b = (float*)alloc(4096*4);
    float* wt_ddc  = (float*)alloc(131072*4);
    float* wt_dc3  = (float*)alloc(1728*4);
    unsigned short* w3hi_e = (unsigned short*)alloc(147456*2);
    unsigned short* w3lo_e = (unsigned short*)alloc(147456*2);
    unsigned short* w3hi_d = (unsigned short*)alloc(147456*2);
    unsigned short* w3lo_d = (unsigned short*)alloc(147456*2);
    unsigned short* w4hi   = (unsigned short*)alloc(131072*2);
    unsigned short* w4lo   = (unsigned short*)alloc(131072*2);
    float* zb = bufA;   // alias: pre_vq out, dead before dec_c1 writes bufA
    float* qb = h1;     // alias: dead before deconv overwrites h1

    // VQ prep: bf16 frag pack + ce2 + zero counts
    prep_codebook<<<4, 256, 0, stream>>>(codebook, cbh, cbl, ce2, counts);

    // batched weight transforms (12 jobs; MFMA layers use split kernels)
    WtJobs J;
    const float* srcs[12] = {enc_c1, enc_r1a, enc_r1b, enc_r2a, enc_r2b,
                             pre_vq_w, dec_r1a, dec_r1b, dec_r2a, dec_r2b,
                             dec_dc, dec_c3};
    float* dsts[12] = {wt_ec1, wt_er1a, wt_er1b, wt_er2a, wt_er2b,
                       wt_pvq, wt_dr1a, wt_dr1b, wt_dr2a, wt_dr2b,
                       wt_ddc, wt_dc3};
    int couts[12] = {64, 32, 128, 32, 128, 128, 32, 128, 32, 128, 64, 3};
    int cins[12]  = {3, 128, 32, 128, 32, 128, 128, 32, 128, 32, 128, 64};
    int kks[12]   = {16, 9, 1, 9, 1, 1, 9, 1, 9, 1, 16, 9};
    int kinds[12] = {0, 0, 0, 0, 0, 0, 0, 0, 0, 0, 1, 2};
    int off = 0;
    for (int j = 0; j < 12; ++j) {
        J.src[j] = srcs[j]; J.dst[j] = dsts[j];
        J.cout[j] = couts[j]; J.cin[j] = cins[j]; J.kk[j] = kks[j];
        J.kind[j] = kinds[j];
        J.blk0[j] = off;
        off += (couts[j] * cins[j] * kks[j] + 255) / 256;
    }
    J.blk0[12] = off;
    for (int j = 13; j < 16; ++j) J.blk0[j] = off + 1000000;  // sentinels
    wt_batch_k<<<off, 256, 0, stream>>>(J);
    wt_split_k<<<576, 256, 0, stream>>>(enc_c3, w3hi_e, w3lo_e);
    wt_split_k<<<576, 256, 0, stream>>>(dec_c1, w3hi_d, w3lo_d);
    wt_split4_k<<<512, 256, 0, stream>>>(enc_c2, w4hi, w4lo);

    // ---- encoder ----
    conv4x4s2_k<3, 64, 128, 3, 4, 64, 1><<<1024, 256, 0, stream>>>(x, wt_ec1, h1);
    conv4x4s2_mfma<<<256, 512, 0, stream>>>(h1, w4hi, w4lo, bufA);
    conv3x3_mfma<<<256, 512, 0, stream>>>(bufA, w3hi_e, w3lo_e, bufB);
    conv3x3_res_k<<<512, 512, 0, stream>>>(bufB, wt_er1a, bufT);
    conv1x1_k<32, 128, 32, true, true><<<512, 256, 0, stream>>>(bufT, wt_er1b, bufB, bufB);
    conv3x3_res_k<<<512, 512, 0, stream>>>(bufB, wt_er2a, bufT);
    conv1x1_k<32, 128, 32, true, true><<<512, 256, 0, stream>>>(bufT, wt_er2b, bufB, bufB);
    conv1x1_k<128, 128, 32, true, false><<<512, 256, 0, stream>>>(bufB, wt_pvq, bufB, zb);

    // ---- VQ (MFMA distances + argmin + gather + loss) ----
    vq_fused<<<512, 512, 0, stream>>>(zb, codebook, cbh, cbl, ce2, counts, qb, partial);

    // ---- decoder ----
    conv3x3_mfma<<<256, 512, 0, stream>>>(qb, w3hi_d, w3lo_d, bufA);
    conv3x3_res_k<<<512, 512, 0, stream>>>(bufA, wt_dr1a, bufT);
    conv1x1_k<32, 128, 32, true, true><<<512, 256, 0, stream>>>(bufT, wt_dr1b, bufA, bufA);
    conv3x3_res_k<<<512, 512, 0, stream>>>(bufA, wt_dr2a, bufT);
    conv1x1_k<32, 128, 32, true, true><<<512, 256, 0, stream>>>(bufT, wt_dr2b, bufA, bufA);
    deconv_k<4><<<1024, 256, 0, stream>>>(bufA, wt_ddc, h1);
    upconv_k<8><<<1024, 256, 0, stream>>>(h1, wt_dc3, dout + 1);

    // ---- scalars ----
    finalize_kernel<<<1, 256, 0, stream>>>(partial, counts, dout);
}

// Round 17
// 945.942 us; speedup vs baseline: 1.3082x; 1.0972x over previous
//
#include <hip/hip_runtime.h>
#include <hip/hip_bf16.h>
#include <math.h>

#define CC_COST 0.25

typedef __attribute__((ext_vector_type(8))) short short8v;
typedef __attribute__((ext_vector_type(16))) float f32x16;

__device__ __forceinline__ unsigned short f2bf(float f) {
    unsigned u = __float_as_uint(f);
    unsigned r = (u + 0x7FFFu + ((u >> 16) & 1u)) >> 16;
    return (unsigned short)r;
}
__device__ __forceinline__ float bf2f(unsigned short h) {
    return __uint_as_float(((unsigned)h) << 16);
}

// ===========================================================================
// VQ-VAE forward. conv3x3 128ch, conv4x4s2 64->128, deconv 128->64, and VQ
// GEMM on MFMA (bf16 hi/lo 3-product ~ fp32).
// d_out[0]=loss, [1..]=recon, [last]=perplexity
// ===========================================================================

// ---------------- batched weight transforms (fp32 vector kernels) ----------
struct WtJobs {
    const float* src[15];
    float* dst[15];
    int cout[15], cin[15], kk[15], kind[15];
    int blk0[16];
};

__global__ void wt_batch_k(WtJobs J)
{
    int blk = blockIdx.x;
    int j = 0;
    while (j < 14 && blk >= J.blk0[j + 1]) ++j;
    int i = (blk - J.blk0[j]) * 256 + threadIdx.x;
    int total = J.cout[j] * J.cin[j] * J.kk[j];
    if (i >= total) return;
    const float* src = J.src[j];
    float* dst = J.dst[j];
    int kind = J.kind[j];
    if (kind == 0) {
        int Cout = J.cout[j], Cin = J.cin[j], KK = J.kk[j];
        int oc = i % Cout; int t2 = i / Cout; int t = t2 % KK; int c = t2 / KK;
        dst[i] = src[(oc * Cin + c) * KK + t];
    } else {
        int o = i % 3; int t = (i / 3) % 9; int c = i / 27;
        dst[i] = src[(o * 64 + c) * 9 + t];
    }
}

// split OIHW [128][128][3][3] fp32 -> whi/wlo bf16 in [9 tap][8 cb][128 oc][16 ci]
__global__ void wt_split_k(const float* __restrict__ w,
                           unsigned short* __restrict__ whi,
                           unsigned short* __restrict__ wlo)
{
    int i = blockIdx.x * 256 + threadIdx.x;
    if (i >= 147456) return;
    int ci = i & 15;
    int oc = (i >> 4) & 127;
    int rest = i >> 11;           // 0..71
    int cb = rest & 7;
    int tap = rest >> 3;          // 0..8
    float v = w[(oc * 128 + cb * 16 + ci) * 9 + tap];
    unsigned short h = f2bf(v);
    whi[i] = h;
    wlo[i] = f2bf(v - bf2f(h));
}

// split enc_c2 OIHW [128][64][4][4] -> [16 tap][4 cb][128 oc][16 ci] hi/lo
__global__ void wt_split4_k(const float* __restrict__ w,
                            unsigned short* __restrict__ whi,
                            unsigned short* __restrict__ wlo)
{
    int i = blockIdx.x * 256 + threadIdx.x;
    if (i >= 131072) return;
    int t = i & 15;
    int oc = (i >> 4) & 127;
    int rest = i >> 11;           // 0..63
    int cb = rest & 3;
    int tap = rest >> 2;          // 0..15
    float v = w[(oc * 64 + cb * 16 + t) * 16 + tap];
    unsigned short h = f2bf(v);
    whi[i] = h;
    wlo[i] = f2bf(v - bf2f(h));
}

// split dec_dc [128 cin][64 oc][4 ky][4 kx] -> [ky4][kx4][cb8][64 oc][16 ci] hi/lo
__global__ void wt_split_dc_k(const float* __restrict__ w,
                              unsigned short* __restrict__ whi,
                              unsigned short* __restrict__ wlo)
{
    int i = blockIdx.x * 256 + threadIdx.x;
    if (i >= 131072) return;
    int ci = i & 15;
    int oc = (i >> 4) & 63;
    int cb = (i >> 10) & 7;
    int kx = (i >> 13) & 3;
    int ky = i >> 15;
    float v = w[((size_t)(cb * 16 + ci) * 64 + oc) * 16 + ky * 4 + kx];
    unsigned short h = f2bf(v);
    whi[i] = h;
    wlo[i] = f2bf(v - bf2f(h));
}

// ---------------- MFMA conv3x3 s1 p1, 128->128, 64x64, batch 8 -------------
__global__ __launch_bounds__(512) void conv3x3_mfma(
    const float* __restrict__ in,           // [8,128,64,64]
    const unsigned short* __restrict__ whi, // [9][8][128][16] bf16
    const unsigned short* __restrict__ wlo,
    float* __restrict__ out)                // [8,128,64,64]
{
    constexpr int CST = 40;
    __shared__ unsigned short ls_hi[4 * 68 * CST];
    __shared__ unsigned short ls_lo[4 * 68 * CST];

    int tid = threadIdx.x;
    int lane = tid & 63;
    int w = tid >> 6;
    int myrow = w & 1;
    int oc0 = (w >> 1) * 32;
    int y0 = (blockIdx.x & 31) * 2;
    int b  = blockIdx.x >> 5;
    int ln31 = lane & 31;
    int lhf  = lane >> 5;

    f32x16 acc0 = {};
    f32x16 acc1 = {};

    const float* inb = in + (size_t)b * 128 * 4096;

    for (int chunk = 0; chunk < 4; ++chunk) {
        int c0 = chunk * 32;
        __syncthreads();
        for (int i = tid; i < 4 * 66 * 16; i += 512) {
            int x = i % 66;
            int t = i / 66;
            int cp = t & 15;
            int r = t >> 4;
            int gy = y0 - 1 + r, gx = x - 1;
            float v0 = 0.f, v1 = 0.f;
            if ((unsigned)gy < 64u && (unsigned)gx < 64u) {
                const float* p = inb + (size_t)(c0 + 2 * cp) * 4096 + gy * 64 + gx;
                v0 = p[0];
                v1 = p[4096];
            }
            unsigned short h0 = f2bf(v0), h1 = f2bf(v1);
            unsigned short l0 = f2bf(v0 - bf2f(h0)), l1 = f2bf(v1 - bf2f(h1));
            int a = (r * 68 + x) * CST + 2 * cp;
            *reinterpret_cast<unsigned int*>(&ls_hi[a]) = (unsigned)h0 | ((unsigned)h1 << 16);
            *reinterpret_cast<unsigned int*>(&ls_lo[a]) = (unsigned)l0 | ((unsigned)l1 << 16);
        }
        __syncthreads();

        #pragma unroll
        for (int tap = 0; tap < 9; ++tap) {
            int dy = tap / 3, dx = tap - 3 * (tap / 3);
            int rbase = (myrow + dy) * 68;
            #pragma unroll
            for (int cb = 0; cb < 2; ++cb) {
                int cbg = chunk * 2 + cb;
                size_t wofs = (((size_t)tap * 8 + cbg) * 128 + oc0 + ln31) * 16 + lhf * 8;
                short8v ah = *reinterpret_cast<const short8v*>(whi + wofs);
                short8v al = *reinterpret_cast<const short8v*>(wlo + wofs);
                int k0 = cb * 16 + lhf * 8;
                int xo0 = (rbase + ln31 + dx) * CST + k0;
                int xo1 = (rbase + 32 + ln31 + dx) * CST + k0;
                short8v bh0 = *reinterpret_cast<const short8v*>(&ls_hi[xo0]);
                short8v bl0 = *reinterpret_cast<const short8v*>(&ls_lo[xo0]);
                short8v bh1 = *reinterpret_cast<const short8v*>(&ls_hi[xo1]);
                short8v bl1 = *reinterpret_cast<const short8v*>(&ls_lo[xo1]);
                acc0 = __builtin_amdgcn_mfma_f32_32x32x16_bf16(ah, bh0, acc0, 0, 0, 0);
                acc1 = __builtin_amdgcn_mfma_f32_32x32x16_bf16(ah, bh1, acc1, 0, 0, 0);
                acc0 = __builtin_amdgcn_mfma_f32_32x32x16_bf16(ah, bl0, acc0, 0, 0, 0);
                acc1 = __builtin_amdgcn_mfma_f32_32x32x16_bf16(ah, bl1, acc1, 0, 0, 0);
                acc0 = __builtin_amdgcn_mfma_f32_32x32x16_bf16(al, bh0, acc0, 0, 0, 0);
                acc1 = __builtin_amdgcn_mfma_f32_32x32x16_bf16(al, bh1, acc1, 0, 0, 0);
            }
        }
    }

    float* ob = out + (size_t)b * 128 * 4096 + (size_t)(y0 + myrow) * 64;
    #pragma unroll
    for (int r = 0; r < 16; ++r) {
        int oc = oc0 + (r & 3) + 8 * (r >> 2) + 4 * lhf;
        ob[(size_t)oc * 4096 + ln31]      = acc0[r];
        ob[(size_t)oc * 4096 + 32 + ln31] = acc1[r];
    }
}

// ---------------- MFMA conv4x4 s2 p1, 64->128, in 128x128 -> out 64x64 -----
__global__ __launch_bounds__(512) void conv4x4s2_mfma(
    const float* __restrict__ in,            // [8,64,128,128] post-relu
    const unsigned short* __restrict__ whi,  // [16 tap][4 cb][128 oc][16 ci]
    const unsigned short* __restrict__ wlo,
    float* __restrict__ out)                 // [8,128,64,64], relu out
{
    constexpr int CST = 24;                  // 16 ci + 8 pad (48B = 16B-aligned)
    __shared__ unsigned short lsEh[6 * 65 * CST];
    __shared__ unsigned short lsEl[6 * 65 * CST];
    __shared__ unsigned short lsOh[6 * 65 * CST];
    __shared__ unsigned short lsOl[6 * 65 * CST];

    int tid = threadIdx.x;
    int lane = tid & 63;
    int w = tid >> 6;
    int myrow = w & 1;
    int oc0 = (w >> 1) * 32;
    int y0 = (blockIdx.x & 31) * 2;
    int b  = blockIdx.x >> 5;
    int ln31 = lane & 31;
    int lhf  = lane >> 5;

    f32x16 acc0 = {};
    f32x16 acc1 = {};

    const float* inb = in + (size_t)b * 64 * 16384;

    for (int cb = 0; cb < 4; ++cb) {
        int c0 = cb * 16;
        __syncthreads();
        for (int i = tid; i < 12480; i += 512) {
            int gxi = i % 130; int t2 = i / 130;
            int r = t2 % 6; int cc = t2 / 6;
            int gx = gxi - 1;
            int gy = 2 * y0 - 1 + r;
            float v = 0.f;
            if ((unsigned)gy < 128u && (unsigned)gx < 128u)
                v = inb[(size_t)(c0 + cc) * 16384 + gy * 128 + gx];
            unsigned short h = f2bf(v);
            unsigned short l = f2bf(v - bf2f(h));
            if (gx & 1) {
                int a = (r * 65 + ((gx + 1) >> 1)) * CST + cc;
                lsOh[a] = h; lsOl[a] = l;
            } else {
                int a = (r * 65 + (gx >> 1)) * CST + cc;
                lsEh[a] = h; lsEl[a] = l;
            }
        }
        __syncthreads();

        #pragma unroll
        for (int tap = 0; tap < 16; ++tap) {
            int ky = tap >> 2, kx = tap & 3;
            int ridx = 2 * myrow + ky;
            int dlt = kx >> 1;
            const unsigned short* ph = (kx & 1) ? lsEh : lsOh;
            const unsigned short* pl = (kx & 1) ? lsEl : lsOl;
            size_t aoff = ((size_t)((tap * 4 + cb) * 128 + oc0 + ln31)) * 16 + lhf * 8;
            short8v ah = *reinterpret_cast<const short8v*>(whi + aoff);
            short8v al = *reinterpret_cast<const short8v*>(wlo + aoff);
            int base0 = (ridx * 65 + ln31 + dlt) * CST + lhf * 8;
            int base1 = (ridx * 65 + 32 + ln31 + dlt) * CST + lhf * 8;
            short8v bh0 = *reinterpret_cast<const short8v*>(ph + base0);
            short8v bl0 = *reinterpret_cast<const short8v*>(pl + base0);
            short8v bh1 = *reinterpret_cast<const short8v*>(ph + base1);
            short8v bl1 = *reinterpret_cast<const short8v*>(pl + base1);
            acc0 = __builtin_amdgcn_mfma_f32_32x32x16_bf16(ah, bh0, acc0, 0, 0, 0);
            acc1 = __builtin_amdgcn_mfma_f32_32x32x16_bf16(ah, bh1, acc1, 0, 0, 0);
            acc0 = __builtin_amdgcn_mfma_f32_32x32x16_bf16(ah, bl0, acc0, 0, 0, 0);
            acc1 = __builtin_amdgcn_mfma_f32_32x32x16_bf16(ah, bl1, acc1, 0, 0, 0);
            acc0 = __builtin_amdgcn_mfma_f32_32x32x16_bf16(al, bh0, acc0, 0, 0, 0);
            acc1 = __builtin_amdgcn_mfma_f32_32x32x16_bf16(al, bh1, acc1, 0, 0, 0);
        }
    }

    int y = y0 + myrow;
    float* ob = out + (size_t)b * 128 * 4096 + (size_t)y * 64;
    #pragma unroll
    for (int r = 0; r < 16; ++r) {
        int oc = oc0 + (r & 3) + 8 * (r >> 2) + 4 * lhf;
        ob[(size_t)oc * 4096 + ln31]      = fmaxf(acc0[r], 0.f);
        ob[(size_t)oc * 4096 + 32 + ln31] = fmaxf(acc1[r], 0.f);
    }
}

// ---------------- MFMA deconv 4x4 s2 p1, 128->64, relu(in), relu(out) ------
// Block: (b, yb). 8 waves = 2 out-rows x 2 oc-tiles x 2 ox-parities.
// K = 2 ky x 2 kx x 128 cin per parity class; input rows yb-1..yb+1 staged.
__global__ __launch_bounds__(512) void deconv_mfma(
    const float* __restrict__ in,            // [8,128,64,64] pre-relu
    const unsigned short* __restrict__ whi,  // [ky4][kx4][cb8][64 oc][16 ci]
    const unsigned short* __restrict__ wlo,
    float* __restrict__ out)                 // [8,64,128,128] relu
{
    constexpr int CST = 40;
    __shared__ unsigned short ls_hi[3 * 68 * CST];
    __shared__ unsigned short ls_lo[3 * 68 * CST];

    int tid = threadIdx.x;
    int lane = tid & 63;
    int w = tid >> 6;
    int myrow = w & 1;                 // output row oy = 2*yb + myrow
    int oc0 = ((w >> 1) & 1) * 32;     // oc tile
    int oxp = w >> 2;                  // ox parity (0 even, 1 odd)
    int yb = blockIdx.x & 63;
    int b  = blockIdx.x >> 6;
    int ln31 = lane & 31;
    int lhf  = lane >> 5;

    f32x16 acc0 = {};
    f32x16 acc1 = {};

    const float* inb = in + (size_t)b * 128 * 4096;

    for (int chunk = 0; chunk < 4; ++chunk) {
        int c0 = chunk * 32;
        __syncthreads();
        // stage input rows yb-1..yb+1, gx -1..64 (66 slots), 32 ch, relu folded
        for (int i = tid; i < 3 * 66 * 16; i += 512) {
            int x = i % 66;
            int t = i / 66;
            int cp = t & 15;
            int r = t >> 4;            // 0..2
            int gy = yb - 1 + r, gx = x - 1;
            float v0 = 0.f, v1 = 0.f;
            if ((unsigned)gy < 64u && (unsigned)gx < 64u) {
                const float* p = inb + (size_t)(c0 + 2 * cp) * 4096 + gy * 64 + gx;
                v0 = fmaxf(p[0], 0.f);
                v1 = fmaxf(p[4096], 0.f);
            }
            unsigned short h0 = f2bf(v0), h1 = f2bf(v1);
            unsigned short l0 = f2bf(v0 - bf2f(h0)), l1 = f2bf(v1 - bf2f(h1));
            int a = (r * 68 + x) * CST + 2 * cp;
            *reinterpret_cast<unsigned int*>(&ls_hi[a]) = (unsigned)h0 | ((unsigned)h1 << 16);
            *reinterpret_cast<unsigned int*>(&ls_lo[a]) = (unsigned)l0 | ((unsigned)l1 << 16);
        }
        __syncthreads();

        #pragma unroll
        for (int tki = 0; tki < 2; ++tki) {
            int ky = (1 - myrow) + 2 * tki;
            int ldsrow = 1 + myrow - tki;
            #pragma unroll
            for (int txi = 0; txi < 2; ++txi) {
                int kx = (1 - oxp) + 2 * txi;
                int dlt = oxp - txi;           // ix = dlt + lane index
                #pragma unroll
                for (int cb = 0; cb < 2; ++cb) {
                    int cbg = chunk * 2 + cb;
                    size_t aoff = ((size_t)(((ky * 4 + kx) * 8 + cbg) * 64 + oc0 + ln31)) * 16 + lhf * 8;
                    short8v ah = *reinterpret_cast<const short8v*>(whi + aoff);
                    short8v al = *reinterpret_cast<const short8v*>(wlo + aoff);
                    int k0 = cb * 16 + lhf * 8;
                    int xo0 = (ldsrow * 68 + ln31 + dlt + 1) * CST + k0;
                    int xo1 = (ldsrow * 68 + 32 + ln31 + dlt + 1) * CST + k0;
                    short8v bh0 = *reinterpret_cast<const short8v*>(&ls_hi[xo0]);
                    short8v bl0 = *reinterpret_cast<const short8v*>(&ls_lo[xo0]);
                    short8v bh1 = *reinterpret_cast<const short8v*>(&ls_hi[xo1]);
                    short8v bl1 = *reinterpret_cast<const short8v*>(&ls_lo[xo1]);
                    acc0 = __builtin_amdgcn_mfma_f32_32x32x16_bf16(ah, bh0, acc0, 0, 0, 0);
                    acc1 = __builtin_amdgcn_mfma_f32_32x32x16_bf16(ah, bh1, acc1, 0, 0, 0);
                    acc0 = __builtin_amdgcn_mfma_f32_32x32x16_bf16(ah, bl0, acc0, 0, 0, 0);
                    acc1 = __builtin_amdgcn_mfma_f32_32x32x16_bf16(ah, bl1, acc1, 0, 0, 0);
                    acc0 = __builtin_amdgcn_mfma_f32_32x32x16_bf16(al, bh0, acc0, 0, 0, 0);
                    acc1 = __builtin_amdgcn_mfma_f32_32x32x16_bf16(al, bh1, acc1, 0, 0, 0);
                }
            }
        }
    }

    int oy = 2 * yb + myrow;
    float* ob = out + (size_t)b * 64 * 16384 + (size_t)oy * 128;
    #pragma unroll
    for (int r = 0; r < 16; ++r) {
        int oc = oc0 + (r & 3) + 8 * (r >> 2) + 4 * lhf;
        ob[(size_t)oc * 16384 + oxp + 2 * ln31]      = fmaxf(acc0[r], 0.f);
        ob[(size_t)oc * 16384 + oxp + 64 + 2 * ln31] = fmaxf(acc1[r], 0.f);
    }
}

// ---------------- split-K res conv3x3: 128->32, relu(in), raw out ----------
__global__ __launch_bounds__(512) void conv3x3_res_k(
    const float* __restrict__ in, const float* __restrict__ wT,  // [c][9][32]
    float* __restrict__ out)
{
    constexpr int CC = 8;
    __shared__ __align__(16) float ls_in[2][CC][3][68];
    __shared__ __align__(16) float ls_w[2][CC][9][32];
    __shared__ float ts[8][256];
    int tid = threadIdx.x;
    int g = tid >> 8, t = tid & 255;
    int pxg = t & 15, ocg = t >> 4;
    int x0 = pxg * 4, oc0 = ocg * 2;
    int y = blockIdx.x & 63, b = blockIdx.x >> 6;
    const float* inb = in + ((size_t)b * 128 + g * 64) * 4096;

    float acc[2][4];
    #pragma unroll
    for (int o = 0; o < 2; ++o)
        #pragma unroll
        for (int p = 0; p < 4; ++p) acc[o][p] = 0.f;

    for (int c0 = 0; c0 < 64; c0 += CC) {
        __syncthreads();
        for (int i = t; i < CC * 3 * 66; i += 256) {
            int xx = i % 66; int tt = i / 66; int r = tt % 3; int cc = tt / 3;
            int gy = y - 1 + r, gx = xx - 1;
            float v = 0.f;
            if ((unsigned)gy < 64u && (unsigned)gx < 64u)
                v = fmaxf(inb[(c0 + cc) * 4096 + gy * 64 + gx], 0.f);
            ls_in[g][cc][r][xx] = v;
        }
        const float* wsrc = wT + (size_t)(g * 64 + c0) * 9 * 32;
        for (int i = t; i < CC * 9 * 32; i += 256)
            (&ls_w[g][0][0][0])[i] = wsrc[i];
        __syncthreads();

        for (int cc = 0; cc < CC; ++cc) {
            float rv[3][6];
            #pragma unroll
            for (int r = 0; r < 3; ++r) {
                const float* base = &ls_in[g][cc][r][x0];
                float4 v = *reinterpret_cast<const float4*>(base);
                rv[r][0]=v.x; rv[r][1]=v.y; rv[r][2]=v.z; rv[r][3]=v.w;
                rv[r][4]=base[4]; rv[r][5]=base[5];
            }
            const float* lw = &ls_w[g][cc][0][0];
            #pragma unroll
            for (int dy = 0; dy < 3; ++dy) {
                #pragma unroll
                for (int dx = 0; dx < 3; ++dx) {
                    float2 w2 = *reinterpret_cast<const float2*>(lw + (dy * 3 + dx) * 32 + oc0);
                    float wv[2] = {w2.x, w2.y};
                    #pragma unroll
                    for (int p = 0; p < 4; ++p) {
                        float iv = rv[dy][p + dx];
                        acc[0][p] = fmaf(iv, wv[0], acc[0][p]);
                        acc[1][p] = fmaf(iv, wv[1], acc[1][p]);
                    }
                }
            }
        }
    }
    if (g == 0) {
        #pragma unroll
        for (int o = 0; o < 2; ++o)
            #pragma unroll
            for (int p = 0; p < 4; ++p) ts[o * 4 + p][t] = acc[o][p];
    }
    __syncthreads();
    if (g == 1) {
        #pragma unroll
        for (int o = 0; o < 2; ++o) {
            float4 v = make_float4(ts[o*4+0][t] + acc[o][0], ts[o*4+1][t] + acc[o][1],
                                   ts[o*4+2][t] + acc[o][2], ts[o*4+3][t] + acc[o][3]);
            float* op = out + (((size_t)b * 32 + oc0 + o) * 64 + y) * 64 + x0;
            *reinterpret_cast<float4*>(op) = v;
        }
    }
}

// ---------------- conv 1x1 on 64x64 (COUT must be 128) ----------------
template<int CIN, int COUT, int CC, bool IN_RELU, bool ADD_RES>
__global__ __launch_bounds__(256) void conv1x1_k(
    const float* __restrict__ in, const float* __restrict__ wT,
    const float* __restrict__ res, float* __restrict__ out)
{
    static_assert(COUT == 128, "tile assumes 128");
    __shared__ __align__(16) float ls_in[CC][64];
    __shared__ __align__(16) float ls_w[CC][COUT];
    int tid = threadIdx.x;
    int pxg = tid & 7, ocg = tid >> 3;
    int x0 = pxg * 8, oc0 = ocg * 4;
    int y = blockIdx.x & 63, b = blockIdx.x >> 6;

    float acc[4][8];
    #pragma unroll
    for (int o = 0; o < 4; ++o)
        #pragma unroll
        for (int p = 0; p < 8; ++p) acc[o][p] = 0.f;

    for (int c0 = 0; c0 < CIN; c0 += CC) {
        __syncthreads();
        for (int i = tid; i < CC * 64; i += 256) {
            int xx = i & 63, cc = i >> 6;
            float v = in[(((size_t)b * CIN + c0 + cc) * 64 + y) * 64 + xx];
            if (IN_RELU) v = fmaxf(v, 0.f);
            ls_in[cc][xx] = v;
        }
        const float* wsrc = wT + (size_t)c0 * COUT;
        for (int i = tid; i < CC * COUT; i += 256)
            (&ls_w[0][0])[i] = wsrc[i];
        __syncthreads();

        for (int cc = 0; cc < CC; ++cc) {
            float rv[8];
            const float* base = &ls_in[cc][x0];
            float4 v0 = *reinterpret_cast<const float4*>(base);
            float4 v1 = *reinterpret_cast<const float4*>(base + 4);
            rv[0]=v0.x; rv[1]=v0.y; rv[2]=v0.z; rv[3]=v0.w;
            rv[4]=v1.x; rv[5]=v1.y; rv[6]=v1.z; rv[7]=v1.w;
            float4 w4 = *reinterpret_cast<const float4*>(&ls_w[cc][oc0]);
            float wv[4] = {w4.x, w4.y, w4.z, w4.w};
            #pragma unroll
            for (int p = 0; p < 8; ++p)
                #pragma unroll
                for (int o = 0; o < 4; ++o)
                    acc[o][p] = fmaf(rv[p], wv[o], acc[o][p]);
        }
    }
    #pragma unroll
    for (int o = 0; o < 4; ++o) {
        float* op = out + (((size_t)b * COUT + oc0 + o) * 64 + y) * 64 + x0;
        const float* rp = res + (((size_t)b * COUT + oc0 + o) * 64 + y) * 64 + x0;
        #pragma unroll
        for (int q = 0; q < 2; ++q) {
            float4 v = make_float4(acc[o][4*q], acc[o][4*q+1],
                                   acc[o][4*q+2], acc[o][4*q+3]);
            if (ADD_RES) {
                float4 r4 = *reinterpret_cast<const float4*>(rp + 4 * q);
                v.x += r4.x; v.y += r4.y; v.z += r4.z; v.w += r4.w;
            }
            *reinterpret_cast<float4*>(op + 4 * q) = v;
        }
    }
}

// ---------------- conv 4x4 s2 p1 (vector; used for enc_c1 3->64) -----------
template<int CIN, int COUT, int WOUT, int CC, int OCB, int WOC, int NSLICE>
__global__ __launch_bounds__(256) void conv4x4s2_k(
    const float* __restrict__ in, const float* __restrict__ wT,
    float* __restrict__ out)
{
    constexpr int WIN = WOUT * 2;
    constexpr int NPXG = WOUT / 8, NOCG = COUT / OCB;
    static_assert(NPXG * NOCG == 256, "bad tile");
    constexpr int WUSE = 2 * WOUT + 2;
    constexpr int PADLEN = ((WUSE + (WUSE / 16 + 1) * 4) + 3) & ~3;
    __shared__ __align__(16) float ls_in[CC][4][PADLEN];
    __shared__ __align__(16) float ls_w[CC][16][COUT];

    int tid = threadIdx.x;
    int pxg = tid % NPXG, ocg = tid / NPXG;
    int x0 = pxg * 8, oc0 = ocg * OCB;
    int blk = blockIdx.x;
    int y = blk % WOUT; int rest = blk / WOUT;
    int slice = rest % NSLICE; int b = rest / NSLICE;
    int oc_base = slice * COUT;
    const float* inb = in + (size_t)b * CIN * WIN * WIN;

    float acc[OCB][8];
    #pragma unroll
    for (int o = 0; o < OCB; ++o)
        #pragma unroll
        for (int p = 0; p < 8; ++p) acc[o][p] = 0.f;

    for (int c0 = 0; c0 < CIN; c0 += CC) {
        __syncthreads();
        for (int i = tid; i < CC * 4 * WUSE; i += 256) {
            int xx = i % WUSE; int t = i / WUSE; int r = t & 3; int cc = t >> 2;
            int gy = 2 * y - 1 + r, gx = xx - 1;
            float v = 0.f;
            if ((unsigned)gy < (unsigned)WIN && (unsigned)gx < (unsigned)WIN)
                v = inb[(c0 + cc) * WIN * WIN + gy * WIN + gx];
            ls_in[cc][r][xx + ((xx >> 4) << 2)] = v;
        }
        const float* wsrc = wT + (size_t)c0 * 16 * WOC + oc_base;
        for (int i = tid; i < CC * 16 * COUT; i += 256) {
            int o = i % COUT; int tt = (i / COUT) % 16; int cc = i / (16 * COUT);
            ls_w[cc][tt][o] = wsrc[(cc * 16 + tt) * WOC + o];
        }
        __syncthreads();

        for (int cc = 0; cc < CC; ++cc) {
            const float* lw = &ls_w[cc][0][0];
            #pragma unroll
            for (int ky = 0; ky < 4; ++ky) {
                float rv[18];
                const float* base = &ls_in[cc][ky][20 * pxg];
                #pragma unroll
                for (int q = 0; q < 4; ++q) {
                    float4 v = *reinterpret_cast<const float4*>(base + 4 * q);
                    rv[4*q]=v.x; rv[4*q+1]=v.y; rv[4*q+2]=v.z; rv[4*q+3]=v.w;
                }
                rv[16] = base[20]; rv[17] = base[21];
                #pragma unroll
                for (int kx = 0; kx < 4; ++kx) {
                    const float* wp = lw + (ky * 4 + kx) * COUT + oc0;
                    float wv[OCB];
                    if constexpr (OCB == 4) {
                        float4 w4 = *reinterpret_cast<const float4*>(wp);
                        wv[0]=w4.x; wv[1]=w4.y; wv[2]=w4.z; wv[3]=w4.w;
                    } else {
                        float2 w2 = *reinterpret_cast<const float2*>(wp);
                        wv[0]=w2.x; wv[1]=w2.y;
                    }
                    #pragma unroll
                    for (int p = 0; p < 8; ++p) {
                        float iv = rv[2 * p + kx];
                        #pragma unroll
                        for (int o = 0; o < OCB; ++o)
                            acc[o][p] = fmaf(iv, wv[o], acc[o][p]);
                    }
                }
            }
        }
    }
    #pragma unroll
    for (int o = 0; o < OCB; ++o) {
        float* op = out + (((size_t)b * (COUT * NSLICE) + oc_base + oc0 + o) * WOUT + y) * WOUT + x0;
        #pragma unroll
        for (int q = 0; q < 2; ++q) {
            float4 v = make_float4(fmaxf(acc[o][4*q],0.f), fmaxf(acc[o][4*q+1],0.f),
                                   fmaxf(acc[o][4*q+2],0.f), fmaxf(acc[o][4*q+3],0.f));
            *reinterpret_cast<float4*>(op + 4 * q) = v;
        }
    }
}

// ---------------- fused bilinear-2x(align) + conv3x3 64->3 + 2*sigmoid-1 ----
// v2: x-split (grid 1024 = b*yblk*2), precomputed x-weight tables, CC=8.
template<int CC>
__global__ __launch_bounds__(256) void upconv_k(
    const float* __restrict__ in,    // h1 [8,64,128,128] post-relu
    const float* __restrict__ wT3,   // [64][9][3]
    float* __restrict__ out)         // [8,3,256,256]
{
    __shared__ __align__(16) float ls_u[CC][6][132];
    __shared__ float ls_w[64 * 27];
    __shared__ float xfx[132];
    __shared__ int   xloT[132];

    int tid = threadIdx.x;
    int row = tid >> 6;              // 0..3
    int pxl = tid & 63;              // 64 groups x 2 px
    int blk = blockIdx.x;
    int xh = blk & 1;
    int yblk = (blk >> 1) & 63;
    int b = blk >> 7;
    int xbase = xh * 128;
    int y0 = yblk * 4, y = y0 + row;
    const float SCL = 127.0f / 255.0f;
    const float* hb = in + (size_t)b * 64 * 16384;

    for (int i = tid; i < 1728; i += 256) ls_w[i] = wT3[i];
    if (tid < 130) {
        int ux = xbase - 1 + tid;
        bool v = ((unsigned)ux < 256u);
        float px = (v ? ux : 0) * SCL;
        int lo = (int)px;
        xloT[tid] = lo;
        xfx[tid] = v ? (px - (float)lo) : -1.0f;   // -1 marks OOB
    }

    float acc[3][2];
    #pragma unroll
    for (int o = 0; o < 3; ++o) { acc[o][0] = 0.f; acc[o][1] = 0.f; }

    for (int c0 = 0; c0 < 64; c0 += CC) {
        __syncthreads();
        for (int i = tid; i < CC * 6 * 130; i += 256) {
            int xx = i % 130; int t = i / 130; int r = t % 6; int cc = t / 6;
            int uy = y0 - 1 + r;
            float v = 0.f;
            float fx = xfx[xx];
            if ((unsigned)uy < 256u && fx >= 0.f) {
                float py = uy * SCL;
                int ylo = (int)py; int yhi = min(ylo + 1, 127); float fy = py - (float)ylo;
                int lo = xloT[xx]; int hi = min(lo + 1, 127);
                const float* hp = hb + (size_t)(c0 + cc) * 16384 + ylo * 128;
                const float* hq = hb + (size_t)(c0 + cc) * 16384 + yhi * 128;
                float a = hp[lo], b2 = hp[hi], c2 = hq[lo], d2 = hq[hi];
                float top = a + (b2 - a) * fx;
                float bot = c2 + (d2 - c2) * fx;
                v = top + (bot - top) * fy;
            }
            ls_u[cc][r][xx] = v;
        }
        __syncthreads();

        for (int cc = 0; cc < CC; ++cc) {
            #pragma unroll
            for (int j = 0; j < 3; ++j) {
                const float* base = &ls_u[cc][row + j][pxl * 2];
                float2 a0 = *reinterpret_cast<const float2*>(base);
                float2 a1 = *reinterpret_cast<const float2*>(base + 2);
                float rv[4] = {a0.x, a0.y, a1.x, a1.y};
                #pragma unroll
                for (int i2 = 0; i2 < 3; ++i2) {
                    const float* wp = &ls_w[((c0 + cc) * 9 + (j * 3 + i2)) * 3];
                    float w0 = wp[0], w1 = wp[1], w2 = wp[2];
                    #pragma unroll
                    for (int p = 0; p < 2; ++p) {
                        float iv = rv[p + i2];
                        acc[0][p] = fmaf(iv, w0, acc[0][p]);
                        acc[1][p] = fmaf(iv, w1, acc[1][p]);
                        acc[2][p] = fmaf(iv, w2, acc[2][p]);
                    }
                }
            }
        }
    }
    int x0 = xbase + pxl * 2;
    #pragma unroll
    for (int o = 0; o < 3; ++o) {
        float2 v;
        v.x = 2.f / (1.f + expf(-acc[o][0])) - 1.f;
        v.y = 2.f / (1.f + expf(-acc[o][1])) - 1.f;
        float* op = out + (((size_t)b * 3 + o) * 256 + y) * 256 + x0;
        *reinterpret_cast<float2*>(op) = v;
    }
}

// ---------------- codebook prep: bf16 hi/lo frag pack + ce2 + zero counts --
__global__ void prep_codebook(const float* __restrict__ cb,
                              unsigned short* __restrict__ cbh,
                              unsigned short* __restrict__ cbl,
                              float* __restrict__ ce2,
                              unsigned int* __restrict__ counts)
{
    int k = blockIdx.x * 256 + threadIdx.x;
    if (k >= 1024) return;
    float s = 0.f;
    for (int d = 0; d < 128; ++d) {
        float v = cb[k * 128 + d];
        s = fmaf(v, v, s);
        unsigned short h = f2bf(v);
        int kk = d >> 4, t = d & 15;
        cbh[(kk * 1024 + k) * 16 + t] = h;
        cbl[(kk * 1024 + k) * 16 + t] = f2bf(v - bf2f(h));
    }
    ce2[k] = s;
    counts[k] = 0u;
}

// ---------------- fused VQ v7: MFMA distance GEMM (bf16 hi/lo 3-product) ---
__global__ __launch_bounds__(512) void vq_fused(
    const float* __restrict__ z, const float* __restrict__ cb,
    const unsigned short* __restrict__ cbh,
    const unsigned short* __restrict__ cbl,
    const float* __restrict__ ce2,
    unsigned int* __restrict__ counts, float* __restrict__ q,
    double* __restrict__ partial)
{
    constexpr int ZP = 136;
    __shared__ unsigned short zh[64 * ZP];
    __shared__ unsigned short zlo[64 * ZP];
    __shared__ float ce2l[1024];
    __shared__ float cmbd[4][2][32];
    __shared__ int   cmbi[4][2][32];
    __shared__ int sidx[64];
    __shared__ float red[8];

    int tid = threadIdx.x;
    int lane = tid & 63;
    int w = tid >> 6;
    int pxg = w & 1;
    int cgrp = w >> 1;
    int ln31 = lane & 31;
    int lhf = lane >> 5;
    int p0g = blockIdx.x * 64;
    int b = p0g >> 12;
    int p0 = p0g & 4095;

    for (int i = tid; i < 8192; i += 512) {
        int d = i >> 6, px = i & 63;
        float v = z[((size_t)b * 128 + d) * 4096 + p0 + px];
        unsigned short h = f2bf(v);
        zh[px * ZP + d]  = h;
        zlo[px * ZP + d] = f2bf(v - bf2f(h));
    }
    for (int i = tid; i < 1024; i += 512) ce2l[i] = ce2[i];
    __syncthreads();

    int pxrow = pxg * 32 + ln31;
    short8v zfh[8], zfl[8];
    #pragma unroll
    for (int kk = 0; kk < 8; ++kk) {
        int off = pxrow * ZP + kk * 16 + lhf * 8;
        zfh[kk] = *reinterpret_cast<const short8v*>(&zh[off]);
        zfl[kk] = *reinterpret_cast<const short8v*>(&zlo[off]);
    }

    float best = 3.4e38f; int bidx = 0;
    #pragma unroll
    for (int ct = 0; ct < 8; ++ct) {
        int c0 = cgrp * 256 + ct * 32;
        f32x16 acc = {};
        #pragma unroll
        for (int kk = 0; kk < 8; ++kk) {
            size_t aoff = ((size_t)(kk * 1024 + c0 + ln31)) * 16 + lhf * 8;
            short8v ah = *reinterpret_cast<const short8v*>(cbh + aoff);
            short8v al = *reinterpret_cast<const short8v*>(cbl + aoff);
            acc = __builtin_amdgcn_mfma_f32_32x32x16_bf16(ah, zfh[kk], acc, 0, 0, 0);
            acc = __builtin_amdgcn_mfma_f32_32x32x16_bf16(ah, zfl[kk], acc, 0, 0, 0);
            acc = __builtin_amdgcn_mfma_f32_32x32x16_bf16(al, zfh[kk], acc, 0, 0, 0);
        }
        #pragma unroll
        for (int r = 0; r < 16; ++r) {
            int code = c0 + (r & 3) + 8 * (r >> 2) + 4 * lhf;
            float dist = ce2l[code] - 2.f * acc[r];
            if (dist < best || (dist == best && code < bidx)) { best = dist; bidx = code; }
        }
    }
    {
        float ob = __shfl_xor(best, 32);
        int   oi = __shfl_xor(bidx, 32);
        if (ob < best || (ob == best && oi < bidx)) { best = ob; bidx = oi; }
    }
    if (lane < 32) { cmbd[cgrp][pxg][lane] = best; cmbi[cgrp][pxg][lane] = bidx; }
    __syncthreads();
    if (tid < 64) {
        int pg = tid >> 5, l = tid & 31;
        float bv = cmbd[0][pg][l]; int bi = cmbi[0][pg][l];
        #pragma unroll
        for (int g = 1; g < 4; ++g) {
            float ov = cmbd[g][pg][l]; int oi = cmbi[g][pg][l];
            if (ov < bv || (ov == bv && oi < bi)) { bv = ov; bi = oi; }
        }
        sidx[pg * 32 + l] = bi;
        atomicAdd(&counts[bi], 1u);
    }
    __syncthreads();

    int pix = tid & 63, dg = tid >> 6;
    int kidx = sidx[pix];
    const float* crow = cb + (size_t)kidx * 128 + dg * 16;
    float sq = 0.f;
    size_t zbase = ((size_t)b * 128 + dg * 16) * 4096 + p0 + pix;
    #pragma unroll
    for (int ii = 0; ii < 4; ++ii) {
        float4 c4 = *reinterpret_cast<const float4*>(crow + 4 * ii);
        float vals[4] = {c4.x, c4.y, c4.z, c4.w};
        #pragma unroll
        for (int jj = 0; jj < 4; ++jj) {
            int dl = ii * 4 + jj;
            float qv = vals[jj];
            float zv = z[zbase + (size_t)dl * 4096];
            float df = qv - zv;
            sq = fmaf(df, df, sq);
            q[zbase + (size_t)dl * 4096] = qv;
        }
    }
    #pragma unroll
    for (int off = 32; off > 0; off >>= 1) sq += __shfl_xor(sq, off);
    if (lane == 0) red[w] = sq;
    __syncthreads();
    if (tid == 0) {
        double s = 0.0;
        #pragma unroll
        for (int ww = 0; ww < 8; ++ww) s += (double)red[ww];
        partial[blockIdx.x] = s;
    }
}

// ---------------- finalize ----------------
__global__ __launch_bounds__(256) void finalize_kernel(
    const double* __restrict__ partial, const unsigned int* __restrict__ counts,
    float* __restrict__ dout)
{
    __shared__ double sd[256];
    __shared__ double lossSh;
    int tid = threadIdx.x;
    double s = 0.0;
    for (int i = tid; i < 512; i += 256) s += partial[i];
    sd[tid] = s; __syncthreads();
    for (int off = 128; off > 0; off >>= 1) {
        if (tid < off) sd[tid] += sd[tid + off];
        __syncthreads();
    }
    if (tid == 0) lossSh = CC_COST * sd[0] / 4194304.0;
    __syncthreads();

    double h = 0.0;
    for (int k = tid; k < 1024; k += 256) {
        double pp = (double)counts[k] / 32768.0;
        h += pp * log(pp + 1e-10);
    }
    sd[tid] = h; __syncthreads();
    for (int off = 128; off > 0; off >>= 1) {
        if (tid < off) sd[tid] += sd[tid + off];
        __syncthreads();
    }
    if (tid == 0) {
        dout[0]       = (float)lossSh;
        dout[1572865] = (float)exp(-sd[0]);
    }
}

// ===========================================================================
extern "C" void kernel_launch(void* const* d_in, const int* in_sizes, int n_in,
                              void* d_out, int out_size, void* d_ws, size_t ws_size,
                              hipStream_t stream)
{
    const float* x        = (const float*)d_in[0];
    const float* enc_c1   = (const float*)d_in[1];
    const float* enc_c2   = (const float*)d_in[2];
    const float* enc_c3   = (const float*)d_in[3];
    const float* enc_r1a  = (const float*)d_in[4];
    const float* enc_r1b  = (const float*)d_in[5];
    const float* enc_r2a  = (const float*)d_in[6];
    const float* enc_r2b  = (const float*)d_in[7];
    const float* pre_vq_w = (const float*)d_in[8];
    const float* codebook = (const float*)d_in[9];
    const float* dec_c1   = (const float*)d_in[10];
    const float* dec_r1a  = (const float*)d_in[11];
    const float* dec_r1b  = (const float*)d_in[12];
    const float* dec_r2a  = (const float*)d_in[13];
    const float* dec_r2b  = (const float*)d_in[14];
    const float* dec_dc   = (const float*)d_in[15];
    const float* dec_c3   = (const float*)d_in[16];
    float* dout = (float*)d_out;

    char* wsp = (char*)d_ws;
    auto alloc = [&](size_t bytes) {
        void* p = (void*)wsp;
        wsp += (bytes + 255) & ~(size_t)255;
        return p;
    };
    float* h1   = (float*)alloc(8ull*64*128*128*4);   // 32MB; also qb alias
    float* bufA = (float*)alloc(8ull*128*64*64*4);    // 16MB; also zb alias
    float* bufB = (float*)alloc(8ull*128*64*64*4);    // 16MB
    float* bufT = (float*)alloc(8ull*32*64*64*4);     // 4MB
    unsigned short* cbh = (unsigned short*)alloc(131072*2);  // [8][1024][16]
    unsigned short* cbl = (unsigned short*)alloc(131072*2);
    float* ce2  = (float*)alloc(1024*4);
    unsigned int* counts = (unsigned int*)alloc(1024*4);
    double* partial = (double*)alloc(512*8);
    float* wt_ec1  = (float*)alloc(3072*4);
    float* wt_er1a = (float*)alloc(36864*4);
    float* wt_er1b = (float*)alloc(4096*4);
    float* wt_er2a = (float*)alloc(36864*4);
    float* wt_er2b = (float*)alloc(4096*4);
    float* wt_pvq  = (float*)alloc(16384*4);
    float* wt_dr1a = (float*)alloc(36864*4);
    float* wt_dr1b = (float*)alloc(4096*4);
    float* wt_dr2a = (float*)alloc(36864*4);
    float* wt_dr2b = (float*)alloc(4096*4);
    float* wt_dc3  = (float*)alloc(1728*4);
    unsigned short* w3hi_e = (unsigned short*)alloc(147456*2);
    unsigned short* w3lo_e = (unsigned short*)alloc(147456*2);
    unsigned short* w3hi_d = (unsigned short*)alloc(147456*2);
    unsigned short* w3lo_d = (unsigned short*)alloc(147456*2);
    unsigned short* w4hi   = (unsigned short*)alloc(131072*2);
    unsigned short* w4lo   = (unsigned short*)alloc(131072*2);
    unsigned short* wdchi  = (unsigned short*)alloc(131072*2);
    unsigned short* wdclo  = (unsigned short*)alloc(131072*2);
    float* zb = bufA;   // alias: pre_vq out, dead before dec_c1 writes bufA
    float* qb = h1;     // alias: dead before deconv overwrites h1

    // VQ prep: bf16 frag pack + ce2 + zero counts
    prep_codebook<<<4, 256, 0, stream>>>(codebook, cbh, cbl, ce2, counts);

    // batched weight transforms (11 jobs; MFMA layers use split kernels)
    WtJobs J;
    const float* srcs[11] = {enc_c1, enc_r1a, enc_r1b, enc_r2a, enc_r2b,
                             pre_vq_w, dec_r1a, dec_r1b, dec_r2a, dec_r2b,
                             dec_c3};
    float* dsts[11] = {wt_ec1, wt_er1a, wt_er1b, wt_er2a, wt_er2b,
                       wt_pvq, wt_dr1a, wt_dr1b, wt_dr2a, wt_dr2b,
                       wt_dc3};
    int couts[11] = {64, 32, 128, 32, 128, 128, 32, 128, 32, 128, 3};
    int cins[11]  = {3, 128, 32, 128, 32, 128, 128, 32, 128, 32, 64};
    int kks[11]   = {16, 9, 1, 9, 1, 1, 9, 1, 9, 1, 9};
    int kinds[11] = {0, 0, 0, 0, 0, 0, 0, 0, 0, 0, 2};
    int off = 0;
    for (int j = 0; j < 11; ++j) {
        J.src[j] = srcs[j]; J.dst[j] = dsts[j];
        J.cout[j] = couts[j]; J.cin[j] = cins[j]; J.kk[j] = kks[j];
        J.kind[j] = kinds[j];
        J.blk0[j] = off;
        off += (couts[j] * cins[j] * kks[j] + 255) / 256;
    }
    J.blk0[11] = off;
    for (int j = 12; j < 16; ++j) J.blk0[j] = off + 1000000;  // sentinels
    wt_batch_k<<<off, 256, 0, stream>>>(J);
    wt_split_k<<<576, 256, 0, stream>>>(enc_c3, w3hi_e, w3lo_e);
    wt_split_k<<<576, 256, 0, stream>>>(dec_c1, w3hi_d, w3lo_d);
    wt_split4_k<<<512, 256, 0, stream>>>(enc_c2, w4hi, w4lo);
    wt_split_dc_k<<<512, 256, 0, stream>>>(dec_dc, wdchi, wdclo);

    // ---- encoder ----
    conv4x4s2_k<3, 64, 128, 3, 4, 64, 1><<<1024, 256, 0, stream>>>(x, wt_ec1, h1);
    conv4x4s2_mfma<<<256, 512, 0, stream>>>(h1, w4hi, w4lo, bufA);
    conv3x3_mfma<<<256, 512, 0, stream>>>(bufA, w3hi_e, w3lo_e, bufB);
    conv3x3_res_k<<<512, 512, 0, stream>>>(bufB, wt_er1a, bufT);
    conv1x1_k<32, 128, 32, true, true><<<512, 256, 0, stream>>>(bufT, wt_er1b, bufB, bufB);
    conv3x3_res_k<<<512, 512, 0, stream>>>(bufB, wt_er2a, bufT);
    conv1x1_k<32, 128, 32, true, true><<<512, 256, 0, stream>>>(bufT, wt_er2b, bufB, bufB);
    conv1x1_k<128, 128, 32, true, false><<<512, 256, 0, stream>>>(bufB, wt_pvq, bufB, zb);

    // ---- VQ (MFMA distances + argmin + gather + loss) ----
    vq_fused<<<512, 512, 0, stream>>>(zb, codebook, cbh, cbl, ce2, counts, qb, partial);

    // ---- decoder ----
    conv3x3_mfma<<<256, 512, 0, stream>>>(qb, w3hi_d, w3lo_d, bufA);
    conv3x3_res_k<<<512, 512, 0, stream>>>(bufA, wt_dr1a, bufT);
    conv1x1_k<32, 128, 32, true, true><<<512, 256, 0, stream>>>(bufT, wt_dr1b, bufA, bufA);
    conv3x3_res_k<<<512, 512, 0, stream>>>(bufA, wt_dr2a, bufT);
    conv1x1_k<32, 128, 32, true, true><<<512, 256, 0, stream>>>(bufT, wt_dr2b, bufA, bufA);
    deconv_mfma<<<512, 512, 0, stream>>>(bufA, wdchi, wdclo, h1);
    upconv_k<8><<<1024, 256, 0, stream>>>(h1, wt_dc3, dout + 1);

    // ---- scalars ----
    finalize_kernel<<<1, 256, 0, stream>>>(partial, counts, dout);
}